// Round 4
// baseline (2882.494 us; speedup 1.0000x reference)
//
#include <hip/hip_runtime.h>
#include <hip/hip_bf16.h>
#include <float.h>

typedef __hip_bfloat16 bf16;
typedef __hip_bfloat162 bf162;

__device__ __forceinline__ float toF(bf16 v) { return __bfloat162float(v); }
__device__ __forceinline__ float2 b2f2(bf162 v) {
    return make_float2(__bfloat162float(v.x), __bfloat162float(v.y));
}

__global__ void fillf_kernel(float* __restrict__ p, float v, int n) {
    int i = blockIdx.x * 256 + threadIdx.x;
    if (i < n) p[i] = v;
}
__global__ void filli_kernel(int* __restrict__ p, int v, int n) {
    int i = blockIdx.x * 256 + threadIdx.x;
    if (i < n) p[i] = v;
}
__global__ void diag_kernel(float* __restrict__ out, float v, int n) {
    int i = blockIdx.x * 256 + threadIdx.x;
    if (i < n) out[i] = v;
}

// Dtype probe: low 16 bits of each 32-bit word, viewed as bf16.
// bf16 inputs -> these are real weights (|w|<0.5). f32 inputs -> random
// mantissa bits -> huge/NaN values -> flag cleared.
__global__ void probe_kernel(const unsigned int* __restrict__ w, int nwords,
                             int* __restrict__ flag) {
    int i = blockIdx.x * 256 + threadIdx.x;
    if (i < nwords) {
        float v = __uint_as_float((w[i] & 0xFFFFu) << 16);
        if (!(v > -1e3f && v < 1e3f)) atomicAnd(flag, 0);
    }
}

// Convert input tensor (dtype per flag) to canonical bf16.
__global__ void convert_kernel(const void* __restrict__ src, bf16* __restrict__ dst,
                               int n, const int* __restrict__ flag) {
    int i = blockIdx.x * 256 + threadIdx.x;
    if (i < n) {
        if (*flag) dst[i] = ((const bf16*)src)[i];
        else       dst[i] = __float2bfloat16(((const float*)src)[i]);
    }
}

__global__ void degcnt_kernel(const int* __restrict__ edges, int E_,
                              int* __restrict__ degd, int* __restrict__ degs) {
    int e = blockIdx.x * 256 + threadIdx.x;
    if (e < E_) {
        atomicAdd(&degs[edges[e]], 1);        // out-degree (src)
        atomicAdd(&degd[edges[E_ + e]], 1);   // in-degree (dst)
    }
}

__global__ void scan_block_kernel(const int* __restrict__ in, int* __restrict__ out,
                                  int* __restrict__ btot, int n) {
    __shared__ int s[256];
    int t = threadIdx.x;
    int i = blockIdx.x * 256 + t;
    s[t] = (i < n) ? in[i] : 0;
    __syncthreads();
    for (int off = 1; off < 256; off <<= 1) {
        int add = (t >= off) ? s[t - off] : 0;
        __syncthreads();
        s[t] += add;
        __syncthreads();
    }
    if (i < n) out[i] = s[t];
    if (t == 255) btot[blockIdx.x] = s[255];
}

__global__ void scan_total_kernel(int* __restrict__ btot, int G) {
    __shared__ int s[256];
    int t = threadIdx.x;
    s[t] = (t < G) ? btot[t] : 0;
    __syncthreads();
    for (int off = 1; off < 256; off <<= 1) {
        int add = (t >= off) ? s[t - off] : 0;
        __syncthreads();
        s[t] += add;
        __syncthreads();
    }
    if (t < G) btot[t] = s[t];
}

__global__ void finalize_kernel(int* __restrict__ indptr, const int* __restrict__ btot, int n) {
    int i = blockIdx.x * 256 + threadIdx.x;
    if (i < n) {
        int b = i >> 8;
        if (b > 0) indptr[i + 1] += btot[b - 1];
    }
    if (i == 0) indptr[0] = 0;
}

__global__ void cur_inv_kernel(const int* __restrict__ indptrd, const int* __restrict__ indptrs,
                               int* __restrict__ curd, int* __restrict__ curs,
                               const int* __restrict__ degd, const int* __restrict__ degs,
                               float* __restrict__ invd, float* __restrict__ invs, int n) {
    int i = blockIdx.x * 256 + threadIdx.x;
    if (i < n) {
        curd[i] = indptrd[i];
        curs[i] = indptrs[i];
        int dd = degd[i]; invd[i] = dd > 0 ? 1.0f / (float)dd : 0.0f;
        int ds = degs[i]; invs[i] = ds > 0 ? 1.0f / (float)ds : 0.0f;
    }
}

__global__ void scatter_kernel(const int* __restrict__ edges, int E_,
                               int* __restrict__ curd, int* __restrict__ curs,
                               int* __restrict__ adjd, int* __restrict__ adjs) {
    int e = blockIdx.x * 256 + threadIdx.x;
    if (e < E_) {
        int s_ = edges[e], d_ = edges[E_ + e];
        adjd[atomicAdd(&curd[d_], 1)] = s_;
        adjs[atomicAdd(&curs[s_], 1)] = d_;
    }
}

__global__ void cnt_kernel(const int* __restrict__ batch, int n, float* __restrict__ cnt) {
    __shared__ float loc[8];
    int tid = threadIdx.x;
    if (tid < 8) loc[tid] = 0.f;
    __syncthreads();
    int i = blockIdx.x * 256 + tid;
    if (i < n) atomicAdd(&loc[batch[i]], 1.0f);
    __syncthreads();
    if (tid < 8 && loc[tid] > 0.f) atomicAdd(&cnt[tid], loc[tid]);
}

// C[M,128] = A[M,K] @ W[K,128] (+bias), all bf16 arrays, f32 accumulate
template<int K>
__global__ void gemm128_kernel(const bf16* __restrict__ A, const bf16* __restrict__ W,
                               const bf16* __restrict__ bias, bf16* __restrict__ C, int M) {
    const int MT = 32, KC = 32;
    __shared__ float As[MT][KC];
    int row0 = blockIdx.x * MT;
    int tid = threadIdx.x;
    int col = tid & 127;
    int rh = tid >> 7;
    float acc[16];
#pragma unroll
    for (int j = 0; j < 16; ++j) acc[j] = 0.f;
    for (int k0 = 0; k0 < K; k0 += KC) {
        int idx = tid;
#pragma unroll
        for (int rep = 0; rep < (MT * KC) / 256; ++rep) {
            int r = idx >> 5, kk = idx & 31;
            int row = row0 + r;
            As[r][kk] = (row < M) ? toF(A[(size_t)row * K + k0 + kk]) : 0.f;
            idx += 256;
        }
        __syncthreads();
        float wreg[KC];
#pragma unroll
        for (int kk = 0; kk < KC; ++kk)
            wreg[kk] = toF(W[(size_t)(k0 + kk) * 128 + col]);
#pragma unroll
        for (int j = 0; j < 16; ++j) {
            const float* ar = As[rh + 2 * j];
            float s = 0.f;
#pragma unroll
            for (int kk = 0; kk < KC; ++kk) s += ar[kk] * wreg[kk];
            acc[j] += s;
        }
        __syncthreads();
    }
    float bv = bias ? toF(bias[col]) : 0.f;
#pragma unroll
    for (int j = 0; j < 16; ++j) {
        int row = row0 + rh + 2 * j;
        if (row < M)
            C[(size_t)row * 128 + col] = __float2bfloat16(acc[j] + bv);
    }
}

// out[i,:] = (Σ_{j∈adj[i]} relu(P[i,:]+Q[j,:]+b1)) @ W2 * inv[i] (+b2 if inv>0)
// 256 thr = 4 nodes (1 wave each) × 64 column-pairs; W2 staged in LDS.
// In-place out==P safe: row i read once by its own wave before write; no other wave reads it.
__global__ void agg_kernel(const int* __restrict__ indptr, const int* __restrict__ adj,
                           const bf16* __restrict__ P, const bf16* __restrict__ Q,
                           const bf16* __restrict__ b1, const bf16* __restrict__ W2,
                           const bf16* __restrict__ b2, const float* __restrict__ inv,
                           bf16* __restrict__ out, int M) {
    __shared__ int4 w2s4[2048];             // 128x128 bf16 = 32 KB
    __shared__ float sh[4][128];
    int tid = threadIdx.x;
    {
        const int4* srcp = (const int4*)W2;
#pragma unroll
        for (int r = 0; r < 8; ++r) w2s4[tid + 256 * r] = srcp[tid + 256 * r];
    }
    int q = tid >> 6;
    int c2 = tid & 63;
    int node = blockIdx.x * 4 + q;
    float2 p2 = make_float2(0.f, 0.f);
    int beg = 0, end = 0;
    if (node < M) {
        float2 pp = b2f2(*(const bf162*)(P + (size_t)node * 128 + 2 * c2));
        float2 bb = b2f2(((const bf162*)b1)[c2]);
        p2.x = pp.x + bb.x;
        p2.y = pp.y + bb.y;
        beg = indptr[node];
        end = indptr[node + 1];
    }
    float2 a2 = make_float2(0.f, 0.f);
    for (int k = beg; k < end; ++k) {
        int j = adj[k];
        float2 qq = b2f2(*(const bf162*)(Q + (size_t)j * 128 + 2 * c2));
        a2.x += fmaxf(p2.x + qq.x, 0.f);
        a2.y += fmaxf(p2.y + qq.y, 0.f);
    }
    sh[q][2 * c2] = a2.x;
    sh[q][2 * c2 + 1] = a2.y;
    __syncthreads();
    const float* srow = sh[q];
    const bf162* w2row = (const bf162*)w2s4;
    float2 o2 = make_float2(0.f, 0.f);
#pragma unroll 4
    for (int k = 0; k < 128; ++k) {
        float2 w = b2f2(w2row[k * 64 + c2]);
        o2.x += srow[k] * w.x;
        o2.y += srow[k] * w.y;
    }
    if (node < M) {
        float sc = inv[node];
        o2.x *= sc;
        o2.y *= sc;
        if (sc > 0.f) {
            float2 bb2 = b2f2(((const bf162*)b2)[c2]);
            o2.x += bb2.x;
            o2.y += bb2.y;
        }
        bf162 r;
        r.x = __float2bfloat16(o2.x);
        r.y = __float2bfloat16(o2.y);
        *(bf162*)(out + (size_t)node * 128 + 2 * c2) = r;
    }
}

// x += relu([x,Fi,Fo]@Wf1+bf1)@Wf2+bf2 for 8 nodes per block
__global__ void final_mlp_kernel(bf16* __restrict__ x,
                                 const bf16* __restrict__ Fi, const bf16* __restrict__ Fo,
                                 const bf16* __restrict__ Wf1, const bf16* __restrict__ bf1_,
                                 const bf16* __restrict__ Wf2, const bf16* __restrict__ bf2_,
                                 int M) {
    const int MT = 8;
    __shared__ float hs[MT][32];
    __shared__ float ts[MT][256];
    int row0 = blockIdx.x * MT;
    int tid = threadIdx.x;
    float acc[MT];
#pragma unroll
    for (int j = 0; j < MT; ++j) acc[j] = 0.f;
    for (int k0 = 0; k0 < 384; k0 += 32) {
        {
            int r = tid >> 5, kk = tid & 31;
            int row = row0 + r;
            int gc = k0 + kk;
            float v = 0.f;
            if (row < M) {
                if (gc < 128) v = toF(x[(size_t)row * 128 + gc]);
                else if (gc < 256) v = toF(Fi[(size_t)row * 128 + gc - 128]);
                else v = toF(Fo[(size_t)row * 128 + gc - 256]);
            }
            hs[r][kk] = v;
        }
        __syncthreads();
        float wreg[32];
#pragma unroll
        for (int kk = 0; kk < 32; ++kk) wreg[kk] = toF(Wf1[(size_t)(k0 + kk) * 256 + tid]);
#pragma unroll
        for (int j = 0; j < MT; ++j) {
            const float* ar = hs[j];
            float s = 0.f;
#pragma unroll
            for (int kk = 0; kk < 32; ++kk) s += ar[kk] * wreg[kk];
            acc[j] += s;
        }
        __syncthreads();
    }
    float b1v = toF(bf1_[tid]);
#pragma unroll
    for (int j = 0; j < MT; ++j) ts[j][tid] = fmaxf(acc[j] + b1v, 0.f);
    __syncthreads();
    int col = tid & 127, rh = tid >> 7;
    float acc2[4] = {0.f, 0.f, 0.f, 0.f};
    for (int k0 = 0; k0 < 256; k0 += 32) {
        float wreg[32];
#pragma unroll
        for (int kk = 0; kk < 32; ++kk) wreg[kk] = toF(Wf2[(size_t)(k0 + kk) * 128 + col]);
#pragma unroll
        for (int j = 0; j < 4; ++j) {
            const float* tr = ts[rh + 2 * j] + k0;
            float s = 0.f;
#pragma unroll
            for (int kk = 0; kk < 32; ++kk) s += tr[kk] * wreg[kk];
            acc2[j] += s;
        }
    }
    float b2v = toF(bf2_[col]);
#pragma unroll
    for (int j = 0; j < 4; ++j) {
        int row = row0 + rh + 2 * j;
        if (row < M) {
            size_t o = (size_t)row * 128 + col;
            x[o] = __float2bfloat16(toF(x[o]) + acc2[j] + b2v);
        }
    }
}

__device__ __forceinline__ void atomicMaxF(float* addr, float val) {
    unsigned int* ua = (unsigned int*)addr;
    unsigned int old = __float_as_uint(*addr);
    while (__uint_as_float(old) < val) {
        unsigned int assumed = old;
        old = atomicCAS(ua, assumed, __float_as_uint(val));
        if (old == assumed) break;
    }
}

__global__ void conv_pool_kernel(const bf16* __restrict__ x,
                                 const bf16* __restrict__ Wconv, const bf16* __restrict__ bconv,
                                 const int* __restrict__ batch, int M,
                                 float* __restrict__ gmax, float* __restrict__ gsum) {
    const int MT = 32;
    __shared__ float xs[MT][128];
    __shared__ int bs[MT];
    int row0 = blockIdx.x * MT;
    int tid = threadIdx.x;
    for (int idx = tid; idx < MT * 128; idx += 256) {
        int r = idx >> 7, c = idx & 127;
        int row = row0 + r;
        xs[r][c] = (row < M) ? toF(x[(size_t)row * 128 + c]) : 0.f;
    }
    if (tid < MT) {
        int row = row0 + tid;
        bs[tid] = (row < M) ? batch[row] : -1;
    }
    __syncthreads();
    float bias = toF(bconv[tid]);
    int cur_b = -1;
    float mx = -FLT_MAX, sm = 0.f;
    for (int r0 = 0; r0 < MT; r0 += 8) {
        float acc[8];
#pragma unroll
        for (int j = 0; j < 8; ++j) acc[j] = bias;
        for (int k = 0; k < 128; ++k) {
            float w = toF(Wconv[(size_t)k * 256 + tid]);
#pragma unroll
            for (int j = 0; j < 8; ++j) acc[j] += xs[r0 + j][k] * w;
        }
#pragma unroll
        for (int j = 0; j < 8; ++j) {
            int b = bs[r0 + j];
            if (b < 0) continue;
            if (b != cur_b) {
                if (cur_b >= 0) {
                    atomicMaxF(&gmax[cur_b * 256 + tid], mx);
                    atomicAdd(&gsum[cur_b * 256 + tid], sm);
                }
                cur_b = b; mx = acc[j]; sm = acc[j];
            } else {
                mx = fmaxf(mx, acc[j]);
                sm += acc[j];
            }
        }
    }
    if (cur_b >= 0) {
        atomicMaxF(&gmax[cur_b * 256 + tid], mx);
        atomicAdd(&gsum[cur_b * 256 + tid], sm);
    }
}

// Output store: dtype per flag; NaN -> sentinel (diagnostic channel).
__global__ void out_kernel(const float* __restrict__ gmax, const float* __restrict__ gsum,
                           const float* __restrict__ cnt, const int* __restrict__ flag,
                           void* __restrict__ out) {
    int i = blockIdx.x * 256 + threadIdx.x;
    if (i < 8 * 512) {
        int b = i >> 9, c = i & 511;
        float v = (c < 256) ? gmax[b * 256 + c] : gsum[b * 256 + (c - 256)] / cnt[b];
        int f = *flag;
        if (!(v == v)) v = 1000.f + 100.f * (float)f;
        if (f) ((bf16*)out)[i] = __float2bfloat16(v);
        else   ((float*)out)[i] = v;
    }
}

extern "C" void kernel_launch(void* const* d_in, const int* in_sizes, int n_in,
                              void* d_out, int out_size, void* d_ws, size_t ws_size,
                              hipStream_t stream) {
    const int* edges = (const int*)d_in[1];
    const int* batch = (const int*)d_in[2];

    const int N_ = in_sizes[2];
    const int E_ = in_sizes[1] / 2;
    const size_t ND = (size_t)N_ * 128;
    auto pad8 = [](int n) { return (size_t)((n + 7) & ~7); };

    // ---- workspace carve (~86 MB for N=50000, E=800000) ----
    char* p = (char*)d_ws;
    bf16* x = (bf16*)p;       p += ND * 2;
    bf16* A = (bf16*)p;       p += ND * 2;   // P / (child) Fo in-place
    bf16* B = (bf16*)p;       p += ND * 2;   // Q
    bf16* C = (bf16*)p;       p += ND * 2;   // Fi
    bf16* nodesb = (bf16*)p;  p += pad8(in_sizes[0]) * 2;
    bf16* wconv_b[16];                       // converted weights/biases d_in[3..18]
    for (int t = 0; t < 16; ++t) { wconv_b[t] = (bf16*)p; p += pad8(in_sizes[3 + t]) * 2; }
    int* degd    = (int*)p;   p += (size_t)N_ * 4;
    int* degs    = (int*)p;   p += (size_t)N_ * 4;
    int* indptrd = (int*)p;   p += (size_t)(N_ + 1) * 4;
    int* indptrs = (int*)p;   p += (size_t)(N_ + 1) * 4;
    int* curd    = (int*)p;   p += (size_t)N_ * 4;
    int* curs    = (int*)p;   p += (size_t)N_ * 4;
    int* adjd    = (int*)p;   p += (size_t)E_ * 4;
    int* adjs    = (int*)p;   p += (size_t)E_ * 4;
    int* btotd   = (int*)p;   p += 256 * 4;
    int* btots   = (int*)p;   p += 256 * 4;
    float* invd  = (float*)p; p += (size_t)N_ * 4;
    float* invs  = (float*)p; p += (size_t)N_ * 4;
    float* cnt   = (float*)p; p += 8 * 4;
    float* gsum  = (float*)p; p += 2048 * 4;
    float* gmax  = (float*)p; p += 2048 * 4;
    int* flag    = (int*)p;   p += 64;
    size_t need = (size_t)(p - (char*)d_ws);

    if (ws_size < need) {
        diag_kernel<<<(out_size + 255) / 256, 256, 0, stream>>>((float*)d_out, (float)(ws_size >> 20), out_size);
        return;
    }

    bf16* Wencb = wconv_b[0],  *bencb = wconv_b[1];
    bf16* Wp1b  = wconv_b[2],  *bp1b  = wconv_b[3];
    bf16* Wp2b  = wconv_b[4],  *bp2b  = wconv_b[5];
    bf16* Wc1b  = wconv_b[6],  *bc1b  = wconv_b[7];
    bf16* Wc2b  = wconv_b[8],  *bc2b  = wconv_b[9];
    bf16* Wf1b  = wconv_b[10], *bf1b  = wconv_b[11];
    bf16* Wf2b  = wconv_b[12], *bf2b  = wconv_b[13];
    bf16* Wconvb = wconv_b[14], *bconvb = wconv_b[15];

    // ---- dtype probe + input conversion ----
    filli_kernel<<<1, 256, 0, stream>>>(flag, 1, 1);
    int nwords = in_sizes[3] / 2;   // safe word count under both dtypes
    probe_kernel<<<(nwords + 255) / 256, 256, 0, stream>>>((const unsigned int*)d_in[3], nwords, flag);
    {
        int n0 = in_sizes[0];
        convert_kernel<<<(n0 + 255) / 256, 256, 0, stream>>>(d_in[0], nodesb, n0, flag);
        for (int t = 0; t < 16; ++t) {
            int n = in_sizes[3 + t];
            convert_kernel<<<(n + 255) / 256, 256, 0, stream>>>(d_in[3 + t], wconv_b[t], n, flag);
        }
    }

    int gN = (N_ + 255) / 256;
    int gE = (E_ + 255) / 256;
    int gb = (N_ + 31) / 32;

    // ---- CSR build + degrees ----
    filli_kernel<<<(2 * N_ + 255) / 256, 256, 0, stream>>>(degd, 0, 2 * N_);   // degd,degs adjacent
    fillf_kernel<<<(8 + 2048 + 255) / 256, 256, 0, stream>>>(cnt, 0.f, 8 + 2048); // cnt,gsum adjacent
    fillf_kernel<<<8, 256, 0, stream>>>(gmax, -FLT_MAX, 2048);
    degcnt_kernel<<<gE, 256, 0, stream>>>(edges, E_, degd, degs);
    scan_block_kernel<<<gN, 256, 0, stream>>>(degd, indptrd + 1, btotd, N_);
    scan_block_kernel<<<gN, 256, 0, stream>>>(degs, indptrs + 1, btots, N_);
    scan_total_kernel<<<1, 256, 0, stream>>>(btotd, gN);
    scan_total_kernel<<<1, 256, 0, stream>>>(btots, gN);
    finalize_kernel<<<gN, 256, 0, stream>>>(indptrd, btotd, N_);
    finalize_kernel<<<gN, 256, 0, stream>>>(indptrs, btots, N_);
    cur_inv_kernel<<<gN, 256, 0, stream>>>(indptrd, indptrs, curd, curs, degd, degs, invd, invs, N_);
    scatter_kernel<<<gE, 256, 0, stream>>>(edges, E_, curd, curs, adjd, adjs);
    cnt_kernel<<<gN, 256, 0, stream>>>(batch, N_, cnt);

    // ---- encoder ----
    gemm128_kernel<256><<<gb, 256, 0, stream>>>(nodesb, Wencb, bencb, x, N_);

    int ga = (N_ + 3) / 4;
    for (int it = 0; it < 2; ++it) {
        // parent: i=dst, j=src
        gemm128_kernel<128><<<gb, 256, 0, stream>>>(x, Wp1b, nullptr, A, N_);
        gemm128_kernel<128><<<gb, 256, 0, stream>>>(x, Wp1b + 128 * 128, nullptr, B, N_);
        agg_kernel<<<ga, 256, 0, stream>>>(indptrd, adjd, A, B, bp1b, Wp2b, bp2b, invd, C, N_);
        // child: i=src, j=dst ; Fo in-place over A
        gemm128_kernel<128><<<gb, 256, 0, stream>>>(x, Wc1b, nullptr, A, N_);
        gemm128_kernel<128><<<gb, 256, 0, stream>>>(x, Wc1b + 128 * 128, nullptr, B, N_);
        agg_kernel<<<ga, 256, 0, stream>>>(indptrs, adjs, A, B, bc1b, Wc2b, bc2b, invs, A, N_);
        final_mlp_kernel<<<(N_ + 7) / 8, 256, 0, stream>>>(x, C, A, Wf1b, bf1b, Wf2b, bf2b, N_);
    }
    conv_pool_kernel<<<gb, 256, 0, stream>>>(x, Wconvb, bconvb, batch, N_, gmax, gsum);
    out_kernel<<<16, 256, 0, stream>>>(gmax, gsum, cnt, flag, d_out);
}

// Round 5
// 1439.327 us; speedup vs baseline: 2.0027x; 2.0027x over previous
//
#include <hip/hip_runtime.h>
#include <hip/hip_bf16.h>
#include <float.h>

typedef __hip_bfloat16 bf16;
typedef __hip_bfloat162 bf162;
typedef short short8 __attribute__((ext_vector_type(8)));   // 8 bf16 in 4 VGPRs (guide §3)
typedef float f32x4 __attribute__((ext_vector_type(4)));

__device__ __forceinline__ float toF(bf16 v) { return __bfloat162float(v); }
__device__ __forceinline__ float2 b2f2(bf162 v) {
    return make_float2(__bfloat162float(v.x), __bfloat162float(v.y));
}

__global__ void fillf_kernel(float* __restrict__ p, float v, int n) {
    int i = blockIdx.x * 256 + threadIdx.x;
    if (i < n) p[i] = v;
}
__global__ void filli_kernel(int* __restrict__ p, int v, int n) {
    int i = blockIdx.x * 256 + threadIdx.x;
    if (i < n) p[i] = v;
}
__global__ void diag_kernel(float* __restrict__ out, float v, int n) {
    int i = blockIdx.x * 256 + threadIdx.x;
    if (i < n) out[i] = v;
}

// Dtype probe: low 16 bits of each word as bf16 — real weights if bf16 input,
// random mantissa garbage (huge/NaN) if f32 input.
__global__ void probe_kernel(const unsigned int* __restrict__ w, int nwords,
                             int* __restrict__ flag) {
    int i = blockIdx.x * 256 + threadIdx.x;
    if (i < nwords) {
        float v = __uint_as_float((w[i] & 0xFFFFu) << 16);
        if (!(v > -1e3f && v < 1e3f)) atomicAnd(flag, 0);
    }
}

__global__ void convert_kernel(const void* __restrict__ src, bf16* __restrict__ dst,
                               int n, const int* __restrict__ flag) {
    int i = blockIdx.x * 256 + threadIdx.x;
    if (i < n) {
        if (*flag) dst[i] = ((const bf16*)src)[i];
        else       dst[i] = __float2bfloat16(((const float*)src)[i]);
    }
}

// dst[n*K + k] = src[k*NCc + n]   (W [K,NCc] -> WT [NCc,K])
__global__ void transpose_kernel(const bf16* __restrict__ src, bf16* __restrict__ dst,
                                 int K, int NCc) {
    int i = blockIdx.x * 256 + threadIdx.x;
    if (i < K * NCc) {
        int k = i / NCc, n = i % NCc;
        dst[n * K + k] = src[i];
    }
}

__global__ void degcnt_kernel(const int* __restrict__ edges, int E_,
                              int* __restrict__ degd, int* __restrict__ degs) {
    int e = blockIdx.x * 256 + threadIdx.x;
    if (e < E_) {
        atomicAdd(&degs[edges[e]], 1);
        atomicAdd(&degd[edges[E_ + e]], 1);
    }
}

__global__ void scan_block_kernel(const int* __restrict__ in, int* __restrict__ out,
                                  int* __restrict__ btot, int n) {
    __shared__ int s[256];
    int t = threadIdx.x;
    int i = blockIdx.x * 256 + t;
    s[t] = (i < n) ? in[i] : 0;
    __syncthreads();
    for (int off = 1; off < 256; off <<= 1) {
        int add = (t >= off) ? s[t - off] : 0;
        __syncthreads();
        s[t] += add;
        __syncthreads();
    }
    if (i < n) out[i] = s[t];
    if (t == 255) btot[blockIdx.x] = s[255];
}

__global__ void scan_total_kernel(int* __restrict__ btot, int G) {
    __shared__ int s[256];
    int t = threadIdx.x;
    s[t] = (t < G) ? btot[t] : 0;
    __syncthreads();
    for (int off = 1; off < 256; off <<= 1) {
        int add = (t >= off) ? s[t - off] : 0;
        __syncthreads();
        s[t] += add;
        __syncthreads();
    }
    if (t < G) btot[t] = s[t];
}

__global__ void finalize_kernel(int* __restrict__ indptr, const int* __restrict__ btot, int n) {
    int i = blockIdx.x * 256 + threadIdx.x;
    if (i < n) {
        int b = i >> 8;
        if (b > 0) indptr[i + 1] += btot[b - 1];
    }
    if (i == 0) indptr[0] = 0;
}

__global__ void cur_inv_kernel(const int* __restrict__ indptrd, const int* __restrict__ indptrs,
                               int* __restrict__ curd, int* __restrict__ curs,
                               const int* __restrict__ degd, const int* __restrict__ degs,
                               float* __restrict__ invd, float* __restrict__ invs, int n) {
    int i = blockIdx.x * 256 + threadIdx.x;
    if (i < n) {
        curd[i] = indptrd[i];
        curs[i] = indptrs[i];
        int dd = degd[i]; invd[i] = dd > 0 ? 1.0f / (float)dd : 0.0f;
        int ds = degs[i]; invs[i] = ds > 0 ? 1.0f / (float)ds : 0.0f;
    }
}

__global__ void scatter_kernel(const int* __restrict__ edges, int E_,
                               int* __restrict__ curd, int* __restrict__ curs,
                               int* __restrict__ adjd, int* __restrict__ adjs) {
    int e = blockIdx.x * 256 + threadIdx.x;
    if (e < E_) {
        int s_ = edges[e], d_ = edges[E_ + e];
        adjd[atomicAdd(&curd[d_], 1)] = s_;
        adjs[atomicAdd(&curs[s_], 1)] = d_;
    }
}

__global__ void cnt_kernel(const int* __restrict__ batch, int n, float* __restrict__ cnt) {
    __shared__ float loc[8];
    int tid = threadIdx.x;
    if (tid < 8) loc[tid] = 0.f;
    __syncthreads();
    int i = blockIdx.x * 256 + tid;
    if (i < n) atomicAdd(&loc[batch[i]], 1.0f);
    __syncthreads();
    if (tid < 8 && loc[tid] > 0.f) atomicAdd(&cnt[tid], loc[tid]);
}

// ---------------- MFMA GEMM ----------------
// C[M,NC] = act(A[M,K] @ WT^T [+bias][*scale]) [+C residual]
// A: NSRC=1 -> A0 [M,K] row-major; NSRC=3 -> concat(A0,A1,A2) each [M,128].
// WT is [NC,K] (pre-transposed). 256 thr = 4 waves; wave = 16 rows, loops NC.
// mfma_f32_16x16x32_bf16: A frag a[j]=A[m=lane&15][k=quad*8+j] (16B load),
// B frag b[j]=W[k=quad*8+j][n=lane&15]=WT[n][k] (16B load),
// D: row=quad*4+reg, col=lane&15 (m89-verified).
// In-place C==A0 safe (wave reads its 16 rows into regs before any store;
// no cross-wave row sharing) — pointers deliberately NOT __restrict__.
template<int K, int NC, int NSRC, bool RELU, bool RES, bool SCALE>
__global__ void gemm_mfma_kernel(const bf16* A0, const bf16* A1, const bf16* A2,
                                 const bf16* WT, const bf16* bias,
                                 const float* scale, bf16* C, int M) {
    int tid = threadIdx.x;
    int wv = tid >> 6, ln = tid & 63;
    int m0 = (blockIdx.x * 4 + wv) * 16;
    if (m0 >= M) return;                       // no barriers below: safe
    int quad = ln >> 4;
    int ncol = ln & 15;
    int lrow = m0 + ncol;
    int rcl = lrow < M ? lrow : M - 1;         // clamp; pad rows never stored
    constexpr int KF = K / 32;
    short8 a[KF];
#pragma unroll
    for (int kb = 0; kb < KF; ++kb) {
        int kg = kb * 32 + quad * 8;
        const bf16* src;
        size_t off;
        if (NSRC == 1) { src = A0; off = (size_t)rcl * K + kg; }
        else {
            src = (kg < 128) ? A0 : (kg < 256 ? A1 : A2);
            off = (size_t)rcl * 128 + (kg & 127);
        }
        a[kb] = *(const short8*)(src + off);
    }
    for (int n0 = 0; n0 < NC; n0 += 16) {
        f32x4 acc = {0.f, 0.f, 0.f, 0.f};
        const bf16* wp = WT + (size_t)(n0 + ncol) * K + quad * 8;
#pragma unroll
        for (int kb = 0; kb < KF; ++kb) {
            short8 b = *(const short8*)(wp + kb * 32);
            acc = __builtin_amdgcn_mfma_f32_16x16x32_bf16(a[kb], b, acc, 0, 0, 0);
        }
        float bv = bias ? toF(bias[n0 + ncol]) : 0.f;
#pragma unroll
        for (int r = 0; r < 4; ++r) {
            int orow = m0 + quad * 4 + r;
            if (orow < M) {
                float v = acc[r];
                if (SCALE) {
                    float sc = scale[orow];
                    v *= sc;
                    if (sc > 0.f) v += bv;
                } else {
                    v += bv;
                }
                if (RELU) v = fmaxf(v, 0.f);
                size_t o = (size_t)orow * NC + n0 + ncol;
                if (RES) v += toF(C[o]);
                C[o] = __float2bfloat16(v);
            }
        }
    }
}

// S[i,:] = sum_{j in adj[i]} relu(P[i,:] + Q[j,:] + b1)
// PQ [M,256]: cols 0-127 = P, 128-255 = Q. 4 nodes/block (1 wave each), 2 cols/lane.
__global__ void agg_kernel(const int* __restrict__ indptr, const int* __restrict__ adj,
                           const bf16* __restrict__ PQ, const bf16* __restrict__ b1,
                           bf16* __restrict__ S, int M) {
    int tid = threadIdx.x;
    int q = tid >> 6, c2 = tid & 63;
    int node = blockIdx.x * 4 + q;
    if (node >= M) return;
    float2 pp = b2f2(*(const bf162*)(PQ + (size_t)node * 256 + 2 * c2));
    float2 bb = b2f2(((const bf162*)b1)[c2]);
    float px = pp.x + bb.x, py = pp.y + bb.y;
    int beg = indptr[node], end = indptr[node + 1];
    float ax = 0.f, ay = 0.f;
    for (int k = beg; k < end; ++k) {
        int j = adj[k];
        float2 qq = b2f2(*(const bf162*)(PQ + (size_t)j * 256 + 128 + 2 * c2));
        ax += fmaxf(px + qq.x, 0.f);
        ay += fmaxf(py + qq.y, 0.f);
    }
    bf162 r;
    r.x = __float2bfloat16(ax);
    r.y = __float2bfloat16(ay);
    *(bf162*)(S + (size_t)node * 128 + 2 * c2) = r;
}

__device__ __forceinline__ void atomicMaxF(float* addr, float val) {
    unsigned int* ua = (unsigned int*)addr;
    unsigned int old = __float_as_uint(*addr);
    while (__uint_as_float(old) < val) {
        unsigned int assumed = old;
        old = atomicCAS(ua, assumed, __float_as_uint(val));
        if (old == assumed) break;
    }
}

// Streamed segment max/sum over sorted batch; y [M,256], thread = col.
__global__ void pool_kernel(const bf16* __restrict__ y, const int* __restrict__ batch,
                            int M, float* __restrict__ gmax, float* __restrict__ gsum) {
    int tid = threadIdx.x;
    int row0 = blockIdx.x * 64;
    int cur_b = -1;
    float mx = -FLT_MAX, sm = 0.f;
    int rend = M - row0; if (rend > 64) rend = 64;
    for (int r = 0; r < rend; ++r) {
        int row = row0 + r;
        float v = toF(y[(size_t)row * 256 + tid]);
        int b = batch[row];
        if (b != cur_b) {
            if (cur_b >= 0) {
                atomicMaxF(&gmax[cur_b * 256 + tid], mx);
                atomicAdd(&gsum[cur_b * 256 + tid], sm);
            }
            cur_b = b; mx = v; sm = v;
        } else {
            mx = fmaxf(mx, v);
            sm += v;
        }
    }
    if (cur_b >= 0) {
        atomicMaxF(&gmax[cur_b * 256 + tid], mx);
        atomicAdd(&gsum[cur_b * 256 + tid], sm);
    }
}

__global__ void out_kernel(const float* __restrict__ gmax, const float* __restrict__ gsum,
                           const float* __restrict__ cnt, const int* __restrict__ flag,
                           void* __restrict__ out) {
    int i = blockIdx.x * 256 + threadIdx.x;
    if (i < 8 * 512) {
        int b = i >> 9, c = i & 511;
        float v = (c < 256) ? gmax[b * 256 + c] : gsum[b * 256 + (c - 256)] / cnt[b];
        int f = *flag;
        if (!(v == v)) v = 1000.f + 100.f * (float)f;
        if (f) ((bf16*)out)[i] = __float2bfloat16(v);
        else   ((float*)out)[i] = v;
    }
}

extern "C" void kernel_launch(void* const* d_in, const int* in_sizes, int n_in,
                              void* d_out, int out_size, void* d_ws, size_t ws_size,
                              hipStream_t stream) {
    const int* edges = (const int*)d_in[1];
    const int* batch = (const int*)d_in[2];

    const int N_ = in_sizes[2];
    const int E_ = in_sizes[1] / 2;
    const size_t ND = (size_t)N_ * 128;
    auto pad8 = [](int n) { return (size_t)((n + 7) & ~7); };

    // ---- workspace carve (~73 MB for N=50000, E=800000) ----
    char* p = (char*)d_ws;
    bf16* x  = (bf16*)p;      p += ND * 2;
    bf16* T  = (bf16*)p;      p += (size_t)N_ * 256 * 2;  // nodesb / PQ / hidden / y
    bf16* S  = (bf16*)p;      p += ND * 2;                // agg sum, then Fo (in-place)
    bf16* Fi = (bf16*)p;      p += ND * 2;
    bf16* wb[16];                                          // converted weights d_in[3..18]
    for (int t = 0; t < 16; ++t) { wb[t] = (bf16*)p; p += pad8(in_sizes[3 + t]) * 2; }
    bf16* WTenc  = (bf16*)p;  p += 256 * 128 * 2;
    bf16* WTpq_p = (bf16*)p;  p += 256 * 128 * 2;
    bf16* WTpq_c = (bf16*)p;  p += 256 * 128 * 2;
    bf16* WT2p   = (bf16*)p;  p += 128 * 128 * 2;
    bf16* WT2c   = (bf16*)p;  p += 128 * 128 * 2;
    bf16* WTf1   = (bf16*)p;  p += 384 * 256 * 2;
    bf16* WTf2   = (bf16*)p;  p += 256 * 128 * 2;
    bf16* WTconv = (bf16*)p;  p += 128 * 256 * 2;
    int* degd    = (int*)p;   p += (size_t)N_ * 4;
    int* degs    = (int*)p;   p += (size_t)N_ * 4;
    int* indptrd = (int*)p;   p += (size_t)(N_ + 1) * 4;
    int* indptrs = (int*)p;   p += (size_t)(N_ + 1) * 4;
    int* curd    = (int*)p;   p += (size_t)N_ * 4;
    int* curs    = (int*)p;   p += (size_t)N_ * 4;
    int* adjd    = (int*)p;   p += (size_t)E_ * 4;
    int* adjs    = (int*)p;   p += (size_t)E_ * 4;
    int* btotd   = (int*)p;   p += 256 * 4;
    int* btots   = (int*)p;   p += 256 * 4;
    float* invd  = (float*)p; p += (size_t)N_ * 4;
    float* invs  = (float*)p; p += (size_t)N_ * 4;
    float* cnt   = (float*)p; p += 8 * 4;
    float* gsum  = (float*)p; p += 2048 * 4;
    float* gmax  = (float*)p; p += 2048 * 4;
    int* flag    = (int*)p;   p += 64;
    size_t need = (size_t)(p - (char*)d_ws);

    if (ws_size < need) {
        diag_kernel<<<(out_size + 255) / 256, 256, 0, stream>>>((float*)d_out, (float)(ws_size >> 20), out_size);
        return;
    }

    bf16* Wencb = wb[0],  *bencb = wb[1];
    bf16* Wp1b  = wb[2],  *bp1b  = wb[3];
    bf16* Wp2b  = wb[4],  *bp2b  = wb[5];
    bf16* Wc1b  = wb[6],  *bc1b  = wb[7];
    bf16* Wc2b  = wb[8],  *bc2b  = wb[9];
    bf16* Wf1b  = wb[10], *bf1b  = wb[11];
    bf16* Wf2b  = wb[12], *bf2b  = wb[13];
    bf16* Wconvb = wb[14], *bconvb = wb[15];

    // ---- dtype probe + conversion (nodes -> T) ----
    filli_kernel<<<1, 256, 0, stream>>>(flag, 1, 1);
    int nwords = in_sizes[3] / 2;
    probe_kernel<<<(nwords + 255) / 256, 256, 0, stream>>>((const unsigned int*)d_in[3], nwords, flag);
    convert_kernel<<<(in_sizes[0] + 255) / 256, 256, 0, stream>>>(d_in[0], T, in_sizes[0], flag);
    for (int t = 0; t < 16; ++t)
        convert_kernel<<<(in_sizes[3 + t] + 255) / 256, 256, 0, stream>>>(d_in[3 + t], wb[t], in_sizes[3 + t], flag);

    // ---- weight transposes (W [K,NC] -> WT [NC,K]) ----
    auto tg = [](int n) { return (n + 255) / 256; };
    transpose_kernel<<<tg(256 * 128), 256, 0, stream>>>(Wencb, WTenc, 256, 128);
    transpose_kernel<<<tg(128 * 128), 256, 0, stream>>>(Wp1b, WTpq_p, 128, 128);                    // P part
    transpose_kernel<<<tg(128 * 128), 256, 0, stream>>>(Wp1b + 128 * 128, WTpq_p + 128 * 128, 128, 128); // Q part
    transpose_kernel<<<tg(128 * 128), 256, 0, stream>>>(Wc1b, WTpq_c, 128, 128);
    transpose_kernel<<<tg(128 * 128), 256, 0, stream>>>(Wc1b + 128 * 128, WTpq_c + 128 * 128, 128, 128);
    transpose_kernel<<<tg(128 * 128), 256, 0, stream>>>(Wp2b, WT2p, 128, 128);
    transpose_kernel<<<tg(128 * 128), 256, 0, stream>>>(Wc2b, WT2c, 128, 128);
    transpose_kernel<<<tg(384 * 256), 256, 0, stream>>>(Wf1b, WTf1, 384, 256);
    transpose_kernel<<<tg(256 * 128), 256, 0, stream>>>(Wf2b, WTf2, 256, 128);
    transpose_kernel<<<tg(128 * 256), 256, 0, stream>>>(Wconvb, WTconv, 128, 256);

    int gN = (N_ + 255) / 256;
    int gE = (E_ + 255) / 256;

    // ---- CSR build + degrees + batch counts ----
    filli_kernel<<<(2 * N_ + 255) / 256, 256, 0, stream>>>(degd, 0, 2 * N_);
    fillf_kernel<<<(8 + 2048 + 255) / 256, 256, 0, stream>>>(cnt, 0.f, 8 + 2048);
    fillf_kernel<<<8, 256, 0, stream>>>(gmax, -FLT_MAX, 2048);
    degcnt_kernel<<<gE, 256, 0, stream>>>(edges, E_, degd, degs);
    scan_block_kernel<<<gN, 256, 0, stream>>>(degd, indptrd + 1, btotd, N_);
    scan_block_kernel<<<gN, 256, 0, stream>>>(degs, indptrs + 1, btots, N_);
    scan_total_kernel<<<1, 256, 0, stream>>>(btotd, gN);
    scan_total_kernel<<<1, 256, 0, stream>>>(btots, gN);
    finalize_kernel<<<gN, 256, 0, stream>>>(indptrd, btotd, N_);
    finalize_kernel<<<gN, 256, 0, stream>>>(indptrs, btots, N_);
    cur_inv_kernel<<<gN, 256, 0, stream>>>(indptrd, indptrs, curd, curs, degd, degs, invd, invs, N_);
    scatter_kernel<<<gE, 256, 0, stream>>>(edges, E_, curd, curs, adjd, adjs);
    cnt_kernel<<<gN, 256, 0, stream>>>(batch, N_, cnt);

    int gb = (N_ + 63) / 64;     // gemm grid (4 waves × 16 rows per block)
    int ga = (N_ + 3) / 4;       // agg grid

    // ---- encoder: x = nodes(T) @ Wenc + benc ----
    gemm_mfma_kernel<256, 128, 1, false, false, false><<<gb, 256, 0, stream>>>(
        T, nullptr, nullptr, WTenc, bencb, nullptr, x, N_);

    for (int it = 0; it < 2; ++it) {
        // parent: PQ = x@[Wp1_i ; Wp1_j] -> T ; S = gather-relu-sum ; Fi = S@Wp2 *invd (+bp2)
        gemm_mfma_kernel<128, 256, 1, false, false, false><<<gb, 256, 0, stream>>>(
            x, nullptr, nullptr, WTpq_p, nullptr, nullptr, T, N_);
        agg_kernel<<<ga, 256, 0, stream>>>(indptrd, adjd, T, bp1b, S, N_);
        gemm_mfma_kernel<128, 128, 1, false, false, true><<<gb, 256, 0, stream>>>(
            S, nullptr, nullptr, WT2p, bp2b, invd, Fi, N_);
        // child: same with src-CSR; Fo = S in-place
        gemm_mfma_kernel<128, 256, 1, false, false, false><<<gb, 256, 0, stream>>>(
            x, nullptr, nullptr, WTpq_c, nullptr, nullptr, T, N_);
        agg_kernel<<<ga, 256, 0, stream>>>(indptrs, adjs, T, bc1b, S, N_);
        gemm_mfma_kernel<128, 128, 1, false, false, true><<<gb, 256, 0, stream>>>(
            S, nullptr, nullptr, WT2c, bc2b, invs, S, N_);
        // final MLP: H = relu([x,Fi,Fo]@Wf1+bf1) -> T ; x += H@Wf2+bf2
        gemm_mfma_kernel<384, 256, 3, true, false, false><<<gb, 256, 0, stream>>>(
            x, Fi, S, WTf1, bf1b, nullptr, T, N_);
        gemm_mfma_kernel<256, 128, 1, false, true, false><<<gb, 256, 0, stream>>>(
            T, nullptr, nullptr, WTf2, bf2b, nullptr, x, N_);
    }

    // conv + pool
    gemm_mfma_kernel<128, 256, 1, false, false, false><<<gb, 256, 0, stream>>>(
        x, nullptr, nullptr, WTconv, bconvb, nullptr, T, N_);
    pool_kernel<<<gb, 256, 0, stream>>>(T, batch, N_, gmax, gsum);
    out_kernel<<<16, 256, 0, stream>>>(gmax, gsum, cnt, flag, d_out);
}

// Round 6
// 1190.737 us; speedup vs baseline: 2.4208x; 1.2088x over previous
//
#include <hip/hip_runtime.h>
#include <hip/hip_bf16.h>
#include <float.h>

typedef __hip_bfloat16 bf16;
typedef __hip_bfloat162 bf162;
typedef short short8 __attribute__((ext_vector_type(8)));   // 8 bf16 in 4 VGPRs
typedef float f32x4 __attribute__((ext_vector_type(4)));

__device__ __forceinline__ float toF(bf16 v) { return __bfloat162float(v); }
__device__ __forceinline__ float2 b2f2(bf162 v) {
    return make_float2(__bfloat162float(v.x), __bfloat162float(v.y));
}

__global__ void diag_kernel(float* __restrict__ out, float v, int n) {
    int i = blockIdx.x * 256 + threadIdx.x;
    if (i < n) out[i] = v;
}
__global__ void filli_kernel(int* __restrict__ p, int v, int n) {
    int i = blockIdx.x * 256 + threadIdx.x;
    if (i < n) p[i] = v;
}

// One fused init: zero degd/degs (2N ints), zero cnt+gsum (2056 f), gmax=-FLT_MAX.
__global__ void init_kernel(int* __restrict__ deg2, float* __restrict__ cnt_gsum,
                            float* __restrict__ gmax, int n2) {
    int i = blockIdx.x * 256 + threadIdx.x;
    if (i < n2) deg2[i] = 0;
    if (i < 8 + 2048) cnt_gsum[i] = 0.f;
    if (i < 2048) gmax[i] = -FLT_MAX;
}

// Dtype probe: low 16 bits of each word as bf16 — real weights if bf16 input,
// random mantissa garbage (huge/NaN) if f32 input.
__global__ void probe_kernel(const unsigned int* __restrict__ w, int nwords,
                             int* __restrict__ flag) {
    int i = blockIdx.x * 256 + threadIdx.x;
    if (i < nwords) {
        float v = __uint_as_float((w[i] & 0xFFFFu) << 16);
        if (!(v > -1e3f && v < 1e3f)) atomicAnd(flag, 0);
    }
}

__global__ void convert_kernel(const void* __restrict__ src, bf16* __restrict__ dst,
                               int n, const int* __restrict__ flag) {
    int i = blockIdx.x * 256 + threadIdx.x;
    if (i < n) {
        if (*flag) dst[i] = ((const bf16*)src)[i];
        else       dst[i] = __float2bfloat16(((const float*)src)[i]);
    }
}

// ---- fused multi-tensor convert (16 weight tensors in one launch) ----
struct ConvSegs {
    const void* src[16];
    bf16* dst[16];
    int n[16];
    int startBlock[17];
};
__global__ void convert_multi_kernel(ConvSegs s, const int* __restrict__ flag) {
    int b = blockIdx.x;
    int seg = 0;
#pragma unroll
    for (int t = 1; t < 16; ++t) if (b >= s.startBlock[t]) seg = t;
    int i = (b - s.startBlock[seg]) * 256 + threadIdx.x;
    if (i < s.n[seg]) {
        if (*flag) s.dst[seg][i] = ((const bf16*)s.src[seg])[i];
        else       s.dst[seg][i] = __float2bfloat16(((const float*)s.src[seg])[i]);
    }
}

// ---- fused multi-transpose (10 weight transposes in one launch) ----
// dst[n*K + k] = src[k*NC + n]
struct TransSegs {
    const bf16* src[10];
    bf16* dst[10];
    int K[10], NC[10];
    int startBlock[11];
};
__global__ void transpose_multi_kernel(TransSegs s) {
    int b = blockIdx.x;
    int seg = 0;
#pragma unroll
    for (int t = 1; t < 10; ++t) if (b >= s.startBlock[t]) seg = t;
    int i = (b - s.startBlock[seg]) * 256 + threadIdx.x;
    int K = s.K[seg], NC = s.NC[seg];
    if (i < K * NC) {
        int k = i / NC, n = i % NC;
        s.dst[seg][n * K + k] = s.src[seg][i];
    }
}

// 4 edges per thread: 4 independent atomic chains in flight (latency hiding).
__global__ void degcnt_kernel(const int* __restrict__ edges, int E_,
                              int* __restrict__ degd, int* __restrict__ degs) {
    int e0 = (blockIdx.x * 256 + threadIdx.x) * 4;
    if (e0 + 4 <= E_) {
        int4 s4 = *(const int4*)(edges + e0);
        int4 d4 = *(const int4*)(edges + E_ + e0);
        atomicAdd(&degs[s4.x], 1); atomicAdd(&degs[s4.y], 1);
        atomicAdd(&degs[s4.z], 1); atomicAdd(&degs[s4.w], 1);
        atomicAdd(&degd[d4.x], 1); atomicAdd(&degd[d4.y], 1);
        atomicAdd(&degd[d4.z], 1); atomicAdd(&degd[d4.w], 1);
    } else {
        for (int e = e0; e < E_; ++e) {
            atomicAdd(&degs[edges[e]], 1);
            atomicAdd(&degd[edges[E_ + e]], 1);
        }
    }
}

__global__ void scan_block_kernel(const int* __restrict__ in, int* __restrict__ out,
                                  int* __restrict__ btot, int n) {
    __shared__ int s[256];
    int t = threadIdx.x;
    int i = blockIdx.x * 256 + t;
    s[t] = (i < n) ? in[i] : 0;
    __syncthreads();
    for (int off = 1; off < 256; off <<= 1) {
        int add = (t >= off) ? s[t - off] : 0;
        __syncthreads();
        s[t] += add;
        __syncthreads();
    }
    if (i < n) out[i] = s[t];
    if (t == 255) btot[blockIdx.x] = s[255];
}

__global__ void scan_total_kernel(int* __restrict__ btot, int G) {
    __shared__ int s[256];
    int t = threadIdx.x;
    s[t] = (t < G) ? btot[t] : 0;
    __syncthreads();
    for (int off = 1; off < 256; off <<= 1) {
        int add = (t >= off) ? s[t - off] : 0;
        __syncthreads();
        s[t] += add;
        __syncthreads();
    }
    if (t < G) btot[t] = s[t];
}

__global__ void finalize_kernel(int* __restrict__ indptr, const int* __restrict__ btot, int n) {
    int i = blockIdx.x * 256 + threadIdx.x;
    if (i < n) {
        int b = i >> 8;
        if (b > 0) indptr[i + 1] += btot[b - 1];
    }
    if (i == 0) indptr[0] = 0;
}

__global__ void cur_inv_kernel(const int* __restrict__ indptrd, const int* __restrict__ indptrs,
                               int* __restrict__ curd, int* __restrict__ curs,
                               const int* __restrict__ degd, const int* __restrict__ degs,
                               float* __restrict__ invd, float* __restrict__ invs, int n) {
    int i = blockIdx.x * 256 + threadIdx.x;
    if (i < n) {
        curd[i] = indptrd[i];
        curs[i] = indptrs[i];
        int dd = degd[i]; invd[i] = dd > 0 ? 1.0f / (float)dd : 0.0f;
        int ds = degs[i]; invs[i] = ds > 0 ? 1.0f / (float)ds : 0.0f;
    }
}

// 4 edges per thread (see degcnt): 8 independent atomic/store chains.
__global__ void scatter_kernel(const int* __restrict__ edges, int E_,
                               int* __restrict__ curd, int* __restrict__ curs,
                               int* __restrict__ adjd, int* __restrict__ adjs) {
    int e0 = (blockIdx.x * 256 + threadIdx.x) * 4;
    if (e0 + 4 <= E_) {
        int4 s4 = *(const int4*)(edges + e0);
        int4 d4 = *(const int4*)(edges + E_ + e0);
        int pd0 = atomicAdd(&curd[d4.x], 1);
        int pd1 = atomicAdd(&curd[d4.y], 1);
        int pd2 = atomicAdd(&curd[d4.z], 1);
        int pd3 = atomicAdd(&curd[d4.w], 1);
        int ps0 = atomicAdd(&curs[s4.x], 1);
        int ps1 = atomicAdd(&curs[s4.y], 1);
        int ps2 = atomicAdd(&curs[s4.z], 1);
        int ps3 = atomicAdd(&curs[s4.w], 1);
        adjd[pd0] = s4.x; adjd[pd1] = s4.y; adjd[pd2] = s4.z; adjd[pd3] = s4.w;
        adjs[ps0] = d4.x; adjs[ps1] = d4.y; adjs[ps2] = d4.z; adjs[ps3] = d4.w;
    } else {
        for (int e = e0; e < E_; ++e) {
            int s_ = edges[e], d_ = edges[E_ + e];
            adjd[atomicAdd(&curd[d_], 1)] = s_;
            adjs[atomicAdd(&curs[s_], 1)] = d_;
        }
    }
}

__global__ void cnt_kernel(const int* __restrict__ batch, int n, float* __restrict__ cnt) {
    __shared__ float loc[8];
    int tid = threadIdx.x;
    if (tid < 8) loc[tid] = 0.f;
    __syncthreads();
    int i = blockIdx.x * 256 + tid;
    if (i < n) atomicAdd(&loc[batch[i]], 1.0f);
    __syncthreads();
    if (tid < 8 && loc[tid] > 0.f) atomicAdd(&cnt[tid], loc[tid]);
}

// ---------------- MFMA GEMM ----------------
// C[M,NC] = act(A[M,K] @ WT^T [+bias][*scale]) [+C residual]
// A: NSRC=1 -> A0 [M,K]; NSRC=3 -> concat(A0,A1,A2) each [M,128]. WT is [NC,K].
// 256 thr = 4 waves; wave = 16 rows. mfma_f32_16x16x32_bf16, m89-verified layouts.
// In-place C==A0 safe (wave holds its rows in regs before store).
template<int K, int NC, int NSRC, bool RELU, bool RES, bool SCALE>
__global__ void gemm_mfma_kernel(const bf16* A0, const bf16* A1, const bf16* A2,
                                 const bf16* WT, const bf16* bias,
                                 const float* scale, bf16* C, int M) {
    int tid = threadIdx.x;
    int wv = tid >> 6, ln = tid & 63;
    int m0 = (blockIdx.x * 4 + wv) * 16;
    if (m0 >= M) return;
    int quad = ln >> 4;
    int ncol = ln & 15;
    int lrow = m0 + ncol;
    int rcl = lrow < M ? lrow : M - 1;
    constexpr int KF = K / 32;
    short8 a[KF];
#pragma unroll
    for (int kb = 0; kb < KF; ++kb) {
        int kg = kb * 32 + quad * 8;
        const bf16* src;
        size_t off;
        if (NSRC == 1) { src = A0; off = (size_t)rcl * K + kg; }
        else {
            src = (kg < 128) ? A0 : (kg < 256 ? A1 : A2);
            off = (size_t)rcl * 128 + (kg & 127);
        }
        a[kb] = *(const short8*)(src + off);
    }
    for (int n0 = 0; n0 < NC; n0 += 16) {
        f32x4 acc = {0.f, 0.f, 0.f, 0.f};
        const bf16* wp = WT + (size_t)(n0 + ncol) * K + quad * 8;
#pragma unroll
        for (int kb = 0; kb < KF; ++kb) {
            short8 b = *(const short8*)(wp + kb * 32);
            acc = __builtin_amdgcn_mfma_f32_16x16x32_bf16(a[kb], b, acc, 0, 0, 0);
        }
        float bv = bias ? toF(bias[n0 + ncol]) : 0.f;
#pragma unroll
        for (int r = 0; r < 4; ++r) {
            int orow = m0 + quad * 4 + r;
            if (orow < M) {
                float v = acc[r];
                if (SCALE) {
                    float sc = scale[orow];
                    v *= sc;
                    if (sc > 0.f) v += bv;
                } else {
                    v += bv;
                }
                if (RELU) v = fmaxf(v, 0.f);
                size_t o = (size_t)orow * NC + n0 + ncol;
                if (RES) v += toF(C[o]);
                C[o] = __float2bfloat16(v);
            }
        }
    }
}

// S[i,:] = sum_{j in adj[i]} relu(P[i,:] + Q[j,:] + b1)
// PQ [M,256]: cols 0-127 = P, 128-255 = Q. 4 nodes/block (1 wave each), 2 cols/lane.
// Neighbor loop unrolled x4: 4 independent 256B gathers in flight per wave.
__global__ void agg_kernel(const int* __restrict__ indptr, const int* __restrict__ adj,
                           const bf16* __restrict__ PQ, const bf16* __restrict__ b1,
                           bf16* __restrict__ S, int M) {
    int tid = threadIdx.x;
    int q = tid >> 6, c2 = tid & 63;
    int node = blockIdx.x * 4 + q;
    if (node >= M) return;
    float2 pp = b2f2(*(const bf162*)(PQ + (size_t)node * 256 + 2 * c2));
    float2 bb = b2f2(((const bf162*)b1)[c2]);
    float px = pp.x + bb.x, py = pp.y + bb.y;
    int beg = indptr[node], end = indptr[node + 1];
    float ax = 0.f, ay = 0.f;
    int k = beg;
    for (; k + 4 <= end; k += 4) {
        int j0 = adj[k], j1 = adj[k + 1], j2 = adj[k + 2], j3 = adj[k + 3];
        float2 q0 = b2f2(*(const bf162*)(PQ + (size_t)j0 * 256 + 128 + 2 * c2));
        float2 q1 = b2f2(*(const bf162*)(PQ + (size_t)j1 * 256 + 128 + 2 * c2));
        float2 q2 = b2f2(*(const bf162*)(PQ + (size_t)j2 * 256 + 128 + 2 * c2));
        float2 q3 = b2f2(*(const bf162*)(PQ + (size_t)j3 * 256 + 128 + 2 * c2));
        ax += fmaxf(px + q0.x, 0.f) + fmaxf(px + q1.x, 0.f)
            + fmaxf(px + q2.x, 0.f) + fmaxf(px + q3.x, 0.f);
        ay += fmaxf(py + q0.y, 0.f) + fmaxf(py + q1.y, 0.f)
            + fmaxf(py + q2.y, 0.f) + fmaxf(py + q3.y, 0.f);
    }
    for (; k < end; ++k) {
        int j = adj[k];
        float2 qq = b2f2(*(const bf162*)(PQ + (size_t)j * 256 + 128 + 2 * c2));
        ax += fmaxf(px + qq.x, 0.f);
        ay += fmaxf(py + qq.y, 0.f);
    }
    bf162 r;
    r.x = __float2bfloat16(ax);
    r.y = __float2bfloat16(ay);
    *(bf162*)(S + (size_t)node * 128 + 2 * c2) = r;
}

__device__ __forceinline__ void atomicMaxF(float* addr, float val) {
    unsigned int* ua = (unsigned int*)addr;
    unsigned int old = __float_as_uint(*addr);
    while (__uint_as_float(old) < val) {
        unsigned int assumed = old;
        old = atomicCAS(ua, assumed, __float_as_uint(val));
        if (old == assumed) break;
    }
}

// Streamed segment max/sum over sorted batch; y [M,256], thread = col.
__global__ void pool_kernel(const bf16* __restrict__ y, const int* __restrict__ batch,
                            int M, float* __restrict__ gmax, float* __restrict__ gsum) {
    int tid = threadIdx.x;
    int row0 = blockIdx.x * 64;
    int cur_b = -1;
    float mx = -FLT_MAX, sm = 0.f;
    int rend = M - row0; if (rend > 64) rend = 64;
    for (int r = 0; r < rend; ++r) {
        int row = row0 + r;
        float v = toF(y[(size_t)row * 256 + tid]);
        int b = batch[row];
        if (b != cur_b) {
            if (cur_b >= 0) {
                atomicMaxF(&gmax[cur_b * 256 + tid], mx);
                atomicAdd(&gsum[cur_b * 256 + tid], sm);
            }
            cur_b = b; mx = v; sm = v;
        } else {
            mx = fmaxf(mx, v);
            sm += v;
        }
    }
    if (cur_b >= 0) {
        atomicMaxF(&gmax[cur_b * 256 + tid], mx);
        atomicAdd(&gsum[cur_b * 256 + tid], sm);
    }
}

__global__ void out_kernel(const float* __restrict__ gmax, const float* __restrict__ gsum,
                           const float* __restrict__ cnt, const int* __restrict__ flag,
                           void* __restrict__ out) {
    int i = blockIdx.x * 256 + threadIdx.x;
    if (i < 8 * 512) {
        int b = i >> 9, c = i & 511;
        float v = (c < 256) ? gmax[b * 256 + c] : gsum[b * 256 + (c - 256)] / cnt[b];
        int f = *flag;
        if (!(v == v)) v = 1000.f + 100.f * (float)f;
        if (f) ((bf16*)out)[i] = __float2bfloat16(v);
        else   ((float*)out)[i] = v;
    }
}

extern "C" void kernel_launch(void* const* d_in, const int* in_sizes, int n_in,
                              void* d_out, int out_size, void* d_ws, size_t ws_size,
                              hipStream_t stream) {
    const int* edges = (const int*)d_in[1];
    const int* batch = (const int*)d_in[2];

    const int N_ = in_sizes[2];
    const int E_ = in_sizes[1] / 2;
    const size_t ND = (size_t)N_ * 128;
    auto pad8 = [](int n) { return (size_t)((n + 7) & ~7); };

    // ---- workspace carve (~73 MB for N=50000, E=800000) ----
    char* p = (char*)d_ws;
    bf16* x  = (bf16*)p;      p += ND * 2;
    bf16* T  = (bf16*)p;      p += (size_t)N_ * 256 * 2;  // nodesb / PQ / hidden / y
    bf16* S  = (bf16*)p;      p += ND * 2;                // agg sum, then Fo (in-place)
    bf16* Fi = (bf16*)p;      p += ND * 2;
    bf16* wb[16];
    for (int t = 0; t < 16; ++t) { wb[t] = (bf16*)p; p += pad8(in_sizes[3 + t]) * 2; }
    bf16* WTenc  = (bf16*)p;  p += 256 * 128 * 2;
    bf16* WTpq_p = (bf16*)p;  p += 256 * 128 * 2;
    bf16* WTpq_c = (bf16*)p;  p += 256 * 128 * 2;
    bf16* WT2p   = (bf16*)p;  p += 128 * 128 * 2;
    bf16* WT2c   = (bf16*)p;  p += 128 * 128 * 2;
    bf16* WTf1   = (bf16*)p;  p += 384 * 256 * 2;
    bf16* WTf2   = (bf16*)p;  p += 256 * 128 * 2;
    bf16* WTconv = (bf16*)p;  p += 128 * 256 * 2;
    int* degd    = (int*)p;   p += (size_t)N_ * 4;
    int* degs    = (int*)p;   p += (size_t)N_ * 4;
    int* indptrd = (int*)p;   p += (size_t)(N_ + 1) * 4;
    int* indptrs = (int*)p;   p += (size_t)(N_ + 1) * 4;
    int* curd    = (int*)p;   p += (size_t)N_ * 4;
    int* curs    = (int*)p;   p += (size_t)N_ * 4;
    int* adjd    = (int*)p;   p += (size_t)E_ * 4;
    int* adjs    = (int*)p;   p += (size_t)E_ * 4;
    int* btotd   = (int*)p;   p += 256 * 4;
    int* btots   = (int*)p;   p += 256 * 4;
    float* invd  = (float*)p; p += (size_t)N_ * 4;
    float* invs  = (float*)p; p += (size_t)N_ * 4;
    float* cnt   = (float*)p; p += 8 * 4;
    float* gsum  = (float*)p; p += 2048 * 4;
    float* gmax  = (float*)p; p += 2048 * 4;
    int* flag    = (int*)p;   p += 64;
    size_t need = (size_t)(p - (char*)d_ws);

    if (ws_size < need) {
        diag_kernel<<<(out_size + 255) / 256, 256, 0, stream>>>((float*)d_out, (float)(ws_size >> 20), out_size);
        return;
    }

    bf16* Wencb = wb[0],  *bencb = wb[1];
    bf16* Wp1b  = wb[2],  *bp1b  = wb[3];
    bf16* Wp2b  = wb[4],  *bp2b  = wb[5];
    bf16* Wc1b  = wb[6],  *bc1b  = wb[7];
    bf16* Wc2b  = wb[8],  *bc2b  = wb[9];
    bf16* Wf1b  = wb[10], *bf1b  = wb[11];
    bf16* Wf2b  = wb[12], *bf2b  = wb[13];
    bf16* Wconvb = wb[14], *bconvb = wb[15];

    // ---- dtype probe + conversions ----
    filli_kernel<<<1, 256, 0, stream>>>(flag, 1, 1);
    int nwords = in_sizes[3] / 2;
    probe_kernel<<<(nwords + 255) / 256, 256, 0, stream>>>((const unsigned int*)d_in[3], nwords, flag);
    convert_kernel<<<(in_sizes[0] + 255) / 256, 256, 0, stream>>>(d_in[0], T, in_sizes[0], flag);
    {
        ConvSegs cs;
        int blk = 0;
        for (int t = 0; t < 16; ++t) {
            cs.src[t] = d_in[3 + t];
            cs.dst[t] = wb[t];
            cs.n[t] = in_sizes[3 + t];
            cs.startBlock[t] = blk;
            blk += (in_sizes[3 + t] + 255) / 256;
        }
        cs.startBlock[16] = blk;
        convert_multi_kernel<<<blk, 256, 0, stream>>>(cs, flag);
    }
    {
        TransSegs ts;
        const bf16* srcs[10] = {Wencb, Wp1b, Wp1b + 128 * 128, Wc1b, Wc1b + 128 * 128,
                                Wp2b, Wc2b, Wf1b, Wf2b, Wconvb};
        bf16* dsts[10] = {WTenc, WTpq_p, WTpq_p + 128 * 128, WTpq_c, WTpq_c + 128 * 128,
                          WT2p, WT2c, WTf1, WTf2, WTconv};
        int Ks[10]  = {256, 128, 128, 128, 128, 128, 128, 384, 256, 128};
        int NCs[10] = {128, 128, 128, 128, 128, 128, 128, 256, 128, 256};
        int blk = 0;
        for (int t = 0; t < 10; ++t) {
            ts.src[t] = srcs[t]; ts.dst[t] = dsts[t];
            ts.K[t] = Ks[t]; ts.NC[t] = NCs[t];
            ts.startBlock[t] = blk;
            blk += (Ks[t] * NCs[t] + 255) / 256;
        }
        ts.startBlock[10] = blk;
        transpose_multi_kernel<<<blk, 256, 0, stream>>>(ts);
    }

    int gN = (N_ + 255) / 256;
    int gE4 = (E_ + 1023) / 1024;

    // ---- CSR build + degrees + batch counts ----
    init_kernel<<<(2 * N_ + 255) / 256, 256, 0, stream>>>(degd, cnt, gmax, 2 * N_);
    degcnt_kernel<<<gE4, 256, 0, stream>>>(edges, E_, degd, degs);
    scan_block_kernel<<<gN, 256, 0, stream>>>(degd, indptrd + 1, btotd, N_);
    scan_block_kernel<<<gN, 256, 0, stream>>>(degs, indptrs + 1, btots, N_);
    scan_total_kernel<<<1, 256, 0, stream>>>(btotd, gN);
    scan_total_kernel<<<1, 256, 0, stream>>>(btots, gN);
    finalize_kernel<<<gN, 256, 0, stream>>>(indptrd, btotd, N_);
    finalize_kernel<<<gN, 256, 0, stream>>>(indptrs, btots, N_);
    cur_inv_kernel<<<gN, 256, 0, stream>>>(indptrd, indptrs, curd, curs, degd, degs, invd, invs, N_);
    scatter_kernel<<<gE4, 256, 0, stream>>>(edges, E_, curd, curs, adjd, adjs);
    cnt_kernel<<<gN, 256, 0, stream>>>(batch, N_, cnt);

    int gb = (N_ + 63) / 64;
    int ga = (N_ + 3) / 4;

    // ---- encoder: x = nodes(T) @ Wenc + benc ----
    gemm_mfma_kernel<256, 128, 1, false, false, false><<<gb, 256, 0, stream>>>(
        T, nullptr, nullptr, WTenc, bencb, nullptr, x, N_);

    for (int it = 0; it < 2; ++it) {
        // parent: PQ = x@[Wp1_i ; Wp1_j] -> T ; S = gather-relu-sum ; Fi = S@Wp2*invd (+bp2)
        gemm_mfma_kernel<128, 256, 1, false, false, false><<<gb, 256, 0, stream>>>(
            x, nullptr, nullptr, WTpq_p, nullptr, nullptr, T, N_);
        agg_kernel<<<ga, 256, 0, stream>>>(indptrd, adjd, T, bp1b, S, N_);
        gemm_mfma_kernel<128, 128, 1, false, false, true><<<gb, 256, 0, stream>>>(
            S, nullptr, nullptr, WT2p, bp2b, invd, Fi, N_);
        // child: src-CSR; Fo = S in-place
        gemm_mfma_kernel<128, 256, 1, false, false, false><<<gb, 256, 0, stream>>>(
            x, nullptr, nullptr, WTpq_c, nullptr, nullptr, T, N_);
        agg_kernel<<<ga, 256, 0, stream>>>(indptrs, adjs, T, bc1b, S, N_);
        gemm_mfma_kernel<128, 128, 1, false, false, true><<<gb, 256, 0, stream>>>(
            S, nullptr, nullptr, WT2c, bc2b, invs, S, N_);
        // final MLP: H = relu([x,Fi,Fo]@Wf1+bf1) -> T ; x += H@Wf2+bf2
        gemm_mfma_kernel<384, 256, 3, true, false, false><<<gb, 256, 0, stream>>>(
            x, Fi, S, WTf1, bf1b, nullptr, T, N_);
        gemm_mfma_kernel<256, 128, 1, false, true, false><<<gb, 256, 0, stream>>>(
            T, nullptr, nullptr, WTf2, bf2b, nullptr, x, N_);
    }

    // conv + pool
    gemm_mfma_kernel<128, 256, 1, false, false, false><<<gb, 256, 0, stream>>>(
        x, nullptr, nullptr, WTconv, bconvb, nullptr, T, N_);
    pool_kernel<<<gb, 256, 0, stream>>>(T, batch, N_, gmax, gsum);
    out_kernel<<<16, 256, 0, stream>>>(gmax, gsum, cnt, flag, d_out);
}

// Round 7
// 1092.359 us; speedup vs baseline: 2.6388x; 1.0901x over previous
//
#include <hip/hip_runtime.h>
#include <hip/hip_bf16.h>
#include <float.h>

typedef __hip_bfloat16 bf16;
typedef __hip_bfloat162 bf162;
typedef short short8 __attribute__((ext_vector_type(8)));   // 8 bf16 in 4 VGPRs
typedef short short4v __attribute__((ext_vector_type(4)));  // 4 bf16 in 2 VGPRs
typedef float f32x4 __attribute__((ext_vector_type(4)));

__device__ __forceinline__ float toF(bf16 v) { return __bfloat162float(v); }
__device__ __forceinline__ float s2f(short s) {
    return __uint_as_float(((unsigned int)(unsigned short)s) << 16);
}
__device__ __forceinline__ short f2s(float f) {
    bf16 h = __float2bfloat16(f);
    return *(short*)&h;
}

__global__ void diag_kernel(float* __restrict__ out, float v, int n) {
    int i = blockIdx.x * 256 + threadIdx.x;
    if (i < n) out[i] = v;
}

// Fused init: zero degd/degs (2N ints), zero cnt+gsum, gmax=-FLT_MAX, flag=1.
__global__ void init_kernel(int* __restrict__ deg2, float* __restrict__ cnt_gsum,
                            float* __restrict__ gmax, int* __restrict__ flag, int n2) {
    int i = blockIdx.x * 256 + threadIdx.x;
    if (i < n2) deg2[i] = 0;
    if (i < 8 + 2048) cnt_gsum[i] = 0.f;
    if (i < 2048) gmax[i] = -FLT_MAX;
    if (i == 0) *flag = 1;
}

// Dtype probe: low 16 bits of each word as bf16 — real weights if bf16 input,
// random mantissa garbage (huge/NaN) if f32 input.
__global__ void probe_kernel(const unsigned int* __restrict__ w, int nwords,
                             int* __restrict__ flag) {
    int i = blockIdx.x * 256 + threadIdx.x;
    if (i < nwords) {
        float v = __uint_as_float((w[i] & 0xFFFFu) << 16);
        if (!(v > -1e3f && v < 1e3f)) atomicAnd(flag, 0);
    }
}

__global__ void convert_kernel(const void* __restrict__ src, bf16* __restrict__ dst,
                               int n, const int* __restrict__ flag) {
    int i = blockIdx.x * 256 + threadIdx.x;
    if (i < n) {
        if (*flag) dst[i] = ((const bf16*)src)[i];
        else       dst[i] = __float2bfloat16(((const float*)src)[i]);
    }
}

// ---- fused multi-tensor convert (16 weight tensors in one launch) ----
struct ConvSegs {
    const void* src[16];
    bf16* dst[16];
    int n[16];
    int startBlock[17];
};
__global__ void convert_multi_kernel(ConvSegs s, const int* __restrict__ flag) {
    int b = blockIdx.x;
    int seg = 0;
#pragma unroll
    for (int t = 1; t < 16; ++t) if (b >= s.startBlock[t]) seg = t;
    int i = (b - s.startBlock[seg]) * 256 + threadIdx.x;
    if (i < s.n[seg]) {
        if (*flag) s.dst[seg][i] = ((const bf16*)s.src[seg])[i];
        else       s.dst[seg][i] = __float2bfloat16(((const float*)s.src[seg])[i]);
    }
}

// ---- fused multi-transpose (10 weight transposes in one launch) ----
struct TransSegs {
    const bf16* src[10];
    bf16* dst[10];
    int K[10], NC[10];
    int startBlock[11];
};
__global__ void transpose_multi_kernel(TransSegs s) {
    int b = blockIdx.x;
    int seg = 0;
#pragma unroll
    for (int t = 1; t < 10; ++t) if (b >= s.startBlock[t]) seg = t;
    int i = (b - s.startBlock[seg]) * 256 + threadIdx.x;
    int K = s.K[seg], NC = s.NC[seg];
    if (i < K * NC) {
        int k = i / NC, n = i % NC;
        s.dst[seg][n * K + k] = s.src[seg][i];
    }
}

// Degrees + per-edge rank (rank = atomicAdd return). Ranks stored coalesced.
__global__ void degcnt_kernel(const int* __restrict__ edges, int E_,
                              int* __restrict__ degd, int* __restrict__ degs,
                              int* __restrict__ rankd, int* __restrict__ ranks) {
    int e0 = (blockIdx.x * 256 + threadIdx.x) * 4;
    if (e0 + 4 <= E_) {
        int4 s4 = *(const int4*)(edges + e0);
        int4 d4 = *(const int4*)(edges + E_ + e0);
        int4 rs, rd;
        rs.x = atomicAdd(&degs[s4.x], 1);
        rs.y = atomicAdd(&degs[s4.y], 1);
        rs.z = atomicAdd(&degs[s4.z], 1);
        rs.w = atomicAdd(&degs[s4.w], 1);
        rd.x = atomicAdd(&degd[d4.x], 1);
        rd.y = atomicAdd(&degd[d4.y], 1);
        rd.z = atomicAdd(&degd[d4.z], 1);
        rd.w = atomicAdd(&degd[d4.w], 1);
        *(int4*)(ranks + e0) = rs;
        *(int4*)(rankd + e0) = rd;
    } else {
        for (int e = e0; e < E_; ++e) {
            ranks[e] = atomicAdd(&degs[edges[e]], 1);
            rankd[e] = atomicAdd(&degd[edges[E_ + e]], 1);
        }
    }
}

// Fused scan of both degree arrays: blocks [0,gN) -> d, [gN,2gN) -> s.
__global__ void scan_block2_kernel(const int* __restrict__ degd, const int* __restrict__ degs,
                                   int* __restrict__ outd, int* __restrict__ outs,
                                   int* __restrict__ btotd, int* __restrict__ btots,
                                   int n, int gN) {
    __shared__ int s[256];
    int bb = blockIdx.x;
    const int* in = (bb < gN) ? degd : degs;
    int* out      = (bb < gN) ? outd : outs;
    int* btot     = (bb < gN) ? btotd : btots;
    int blk       = (bb < gN) ? bb : bb - gN;
    int t = threadIdx.x;
    int i = blk * 256 + t;
    s[t] = (i < n) ? in[i] : 0;
    __syncthreads();
    for (int off = 1; off < 256; off <<= 1) {
        int add = (t >= off) ? s[t - off] : 0;
        __syncthreads();
        s[t] += add;
        __syncthreads();
    }
    if (i < n) out[i] = s[t];
    if (t == 255) btot[blk] = s[255];
}

// 2 blocks: block 0 scans btotd, block 1 scans btots.
__global__ void scan_total2_kernel(int* __restrict__ btotd, int* __restrict__ btots, int G) {
    __shared__ int s[256];
    int* btot = (blockIdx.x == 0) ? btotd : btots;
    int t = threadIdx.x;
    s[t] = (t < G) ? btot[t] : 0;
    __syncthreads();
    for (int off = 1; off < 256; off <<= 1) {
        int add = (t >= off) ? s[t - off] : 0;
        __syncthreads();
        s[t] += add;
        __syncthreads();
    }
    if (t < G) btot[t] = s[t];
}

__global__ void finalize2_kernel(int* __restrict__ indptrd, int* __restrict__ indptrs,
                                 const int* __restrict__ btotd, const int* __restrict__ btots,
                                 int n, int gN) {
    int bb = blockIdx.x;
    int* indptr     = (bb < gN) ? indptrd : indptrs;
    const int* btot = (bb < gN) ? btotd : btots;
    int blk         = (bb < gN) ? bb : bb - gN;
    int i = blk * 256 + threadIdx.x;
    if (i < n) {
        int b = i >> 8;
        if (b > 0) indptr[i + 1] += btot[b - 1];
    }
    if (i == 0) indptr[0] = 0;
}

__global__ void inv_kernel(const int* __restrict__ degd, const int* __restrict__ degs,
                           float* __restrict__ invd, float* __restrict__ invs, int n) {
    int i = blockIdx.x * 256 + threadIdx.x;
    if (i < n) {
        int dd = degd[i]; invd[i] = dd > 0 ? 1.0f / (float)dd : 0.0f;
        int ds = degs[i]; invs[i] = ds > 0 ? 1.0f / (float)ds : 0.0f;
    }
}

// Atomic-free scatter: adj[indptr[node] + rank[e]] = other endpoint.
__global__ void scatter_kernel(const int* __restrict__ edges, int E_,
                               const int* __restrict__ indptrd, const int* __restrict__ indptrs,
                               const int* __restrict__ rankd, const int* __restrict__ ranks,
                               int* __restrict__ adjd, int* __restrict__ adjs) {
    int e0 = (blockIdx.x * 256 + threadIdx.x) * 4;
    if (e0 + 4 <= E_) {
        int4 s4 = *(const int4*)(edges + e0);
        int4 d4 = *(const int4*)(edges + E_ + e0);
        int4 rd = *(const int4*)(rankd + e0);
        int4 rs = *(const int4*)(ranks + e0);
        adjd[indptrd[d4.x] + rd.x] = s4.x;
        adjd[indptrd[d4.y] + rd.y] = s4.y;
        adjd[indptrd[d4.z] + rd.z] = s4.z;
        adjd[indptrd[d4.w] + rd.w] = s4.w;
        adjs[indptrs[s4.x] + rs.x] = d4.x;
        adjs[indptrs[s4.y] + rs.y] = d4.y;
        adjs[indptrs[s4.z] + rs.z] = d4.z;
        adjs[indptrs[s4.w] + rs.w] = d4.w;
    } else {
        for (int e = e0; e < E_; ++e) {
            int s_ = edges[e], d_ = edges[E_ + e];
            adjd[indptrd[d_] + rankd[e]] = s_;
            adjs[indptrs[s_] + ranks[e]] = d_;
        }
    }
}

__global__ void cnt_kernel(const int* __restrict__ batch, int n, float* __restrict__ cnt) {
    __shared__ float loc[8];
    int tid = threadIdx.x;
    if (tid < 8) loc[tid] = 0.f;
    __syncthreads();
    int i = blockIdx.x * 256 + tid;
    if (i < n) atomicAdd(&loc[batch[i]], 1.0f);
    __syncthreads();
    if (tid < 8 && loc[tid] > 0.f) atomicAdd(&cnt[tid], loc[tid]);
}

// ---------------- MFMA GEMM ----------------
// C[M,NC] = act(A[M,K] @ WT^T [+bias][*scale]) [+C residual]
// A: NSRC=1 -> A0 [M,K]; NSRC=3 -> concat(A0,A1,A2) each [M,128]. WT is [NC,K].
// 256 thr = 4 waves; wave = 16 rows. mfma_f32_16x16x32_bf16, m89-verified layouts.
// In-place C==A0 safe (wave holds its rows in regs before store).
template<int K, int NC, int NSRC, bool RELU, bool RES, bool SCALE>
__global__ void gemm_mfma_kernel(const bf16* A0, const bf16* A1, const bf16* A2,
                                 const bf16* WT, const bf16* bias,
                                 const float* scale, bf16* C, int M) {
    int tid = threadIdx.x;
    int wv = tid >> 6, ln = tid & 63;
    int m0 = (blockIdx.x * 4 + wv) * 16;
    if (m0 >= M) return;
    int quad = ln >> 4;
    int ncol = ln & 15;
    int lrow = m0 + ncol;
    int rcl = lrow < M ? lrow : M - 1;
    constexpr int KF = K / 32;
    short8 a[KF];
#pragma unroll
    for (int kb = 0; kb < KF; ++kb) {
        int kg = kb * 32 + quad * 8;
        const bf16* src;
        size_t off;
        if (NSRC == 1) { src = A0; off = (size_t)rcl * K + kg; }
        else {
            src = (kg < 128) ? A0 : (kg < 256 ? A1 : A2);
            off = (size_t)rcl * 128 + (kg & 127);
        }
        a[kb] = *(const short8*)(src + off);
    }
    for (int n0 = 0; n0 < NC; n0 += 16) {
        f32x4 acc = {0.f, 0.f, 0.f, 0.f};
        const bf16* wp = WT + (size_t)(n0 + ncol) * K + quad * 8;
#pragma unroll
        for (int kb = 0; kb < KF; ++kb) {
            short8 b = *(const short8*)(wp + kb * 32);
            acc = __builtin_amdgcn_mfma_f32_16x16x32_bf16(a[kb], b, acc, 0, 0, 0);
        }
        float bv = bias ? toF(bias[n0 + ncol]) : 0.f;
#pragma unroll
        for (int r = 0; r < 4; ++r) {
            int orow = m0 + quad * 4 + r;
            if (orow < M) {
                float v = acc[r];
                if (SCALE) {
                    float sc = scale[orow];
                    v *= sc;
                    if (sc > 0.f) v += bv;
                } else {
                    v += bv;
                }
                if (RELU) v = fmaxf(v, 0.f);
                size_t o = (size_t)orow * NC + n0 + ncol;
                if (RES) v += toF(C[o]);
                C[o] = __float2bfloat16(v);
            }
        }
    }
}

// S[i,:] = sum_{j in adj[i]} relu(P[i,:] + Q[j,:] + b1)
// PQ [M,256]: cols 0-127 = P, 128-255 = Q. 4 nodes/block, 1 wave/node.
// Lane covers 4 cols (8B); half-waves take alternating neighbors; x4 unroll
// -> 8 independent 256B gathers in flight per wave. Halves merge via shfl_xor(32).
__global__ void agg_kernel(const int* __restrict__ indptr, const int* __restrict__ adj,
                           const bf16* __restrict__ PQ, const bf16* __restrict__ b1,
                           bf16* __restrict__ S, int M) {
    int tid = threadIdx.x;
    int wv = tid >> 6, ln = tid & 63;
    int node = blockIdx.x * 4 + wv;
    if (node >= M) return;
    int c4 = ln & 31, half = ln >> 5;
    float p[4];
    {
        short4v pv = *(const short4v*)((const short*)PQ + (size_t)node * 256 + 4 * c4);
        short4v bv = *(const short4v*)((const short*)b1 + 4 * c4);
#pragma unroll
        for (int r = 0; r < 4; ++r) p[r] = s2f(pv[r]) + s2f(bv[r]);
    }
    float a[4] = {0.f, 0.f, 0.f, 0.f};
    int beg = indptr[node], end = indptr[node + 1];
    const short* Qb = (const short*)PQ + 128 + 4 * c4;
    int k = beg + half;
    for (; k + 6 < end; k += 8) {
        int j0 = adj[k], j1 = adj[k + 2], j2 = adj[k + 4], j3 = adj[k + 6];
        short4v q0 = *(const short4v*)(Qb + (size_t)j0 * 256);
        short4v q1 = *(const short4v*)(Qb + (size_t)j1 * 256);
        short4v q2 = *(const short4v*)(Qb + (size_t)j2 * 256);
        short4v q3 = *(const short4v*)(Qb + (size_t)j3 * 256);
#pragma unroll
        for (int r = 0; r < 4; ++r)
            a[r] += fmaxf(p[r] + s2f(q0[r]), 0.f) + fmaxf(p[r] + s2f(q1[r]), 0.f)
                  + fmaxf(p[r] + s2f(q2[r]), 0.f) + fmaxf(p[r] + s2f(q3[r]), 0.f);
    }
    for (; k < end; k += 2) {
        int j = adj[k];
        short4v q = *(const short4v*)(Qb + (size_t)j * 256);
#pragma unroll
        for (int r = 0; r < 4; ++r) a[r] += fmaxf(p[r] + s2f(q[r]), 0.f);
    }
#pragma unroll
    for (int r = 0; r < 4; ++r) a[r] += __shfl_xor(a[r], 32);
    if (half == 0) {
        short4v o;
#pragma unroll
        for (int r = 0; r < 4; ++r) o[r] = f2s(a[r]);
        *(short4v*)((short*)S + (size_t)node * 128 + 4 * c4) = o;
    }
}

__device__ __forceinline__ void atomicMaxF(float* addr, float val) {
    unsigned int* ua = (unsigned int*)addr;
    unsigned int old = __float_as_uint(*addr);
    while (__uint_as_float(old) < val) {
        unsigned int assumed = old;
        old = atomicCAS(ua, assumed, __float_as_uint(val));
        if (old == assumed) break;
    }
}

// Streamed segment max/sum over sorted batch; y [M,256], thread = col.
__global__ void pool_kernel(const bf16* __restrict__ y, const int* __restrict__ batch,
                            int M, float* __restrict__ gmax, float* __restrict__ gsum) {
    int tid = threadIdx.x;
    int row0 = blockIdx.x * 64;
    int cur_b = -1;
    float mx = -FLT_MAX, sm = 0.f;
    int rend = M - row0; if (rend > 64) rend = 64;
    for (int r = 0; r < rend; ++r) {
        int row = row0 + r;
        float v = toF(y[(size_t)row * 256 + tid]);
        int b = batch[row];
        if (b != cur_b) {
            if (cur_b >= 0) {
                atomicMaxF(&gmax[cur_b * 256 + tid], mx);
                atomicAdd(&gsum[cur_b * 256 + tid], sm);
            }
            cur_b = b; mx = v; sm = v;
        } else {
            mx = fmaxf(mx, v);
            sm += v;
        }
    }
    if (cur_b >= 0) {
        atomicMaxF(&gmax[cur_b * 256 + tid], mx);
        atomicAdd(&gsum[cur_b * 256 + tid], sm);
    }
}

__global__ void out_kernel(const float* __restrict__ gmax, const float* __restrict__ gsum,
                           const float* __restrict__ cnt, const int* __restrict__ flag,
                           void* __restrict__ out) {
    int i = blockIdx.x * 256 + threadIdx.x;
    if (i < 8 * 512) {
        int b = i >> 9, c = i & 511;
        float v = (c < 256) ? gmax[b * 256 + c] : gsum[b * 256 + (c - 256)] / cnt[b];
        int f = *flag;
        if (!(v == v)) v = 1000.f + 100.f * (float)f;
        if (f) ((bf16*)out)[i] = __float2bfloat16(v);
        else   ((float*)out)[i] = v;
    }
}

extern "C" void kernel_launch(void* const* d_in, const int* in_sizes, int n_in,
                              void* d_out, int out_size, void* d_ws, size_t ws_size,
                              hipStream_t stream) {
    const int* edges = (const int*)d_in[1];
    const int* batch = (const int*)d_in[2];

    const int N_ = in_sizes[2];
    const int E_ = in_sizes[1] / 2;
    const size_t ND = (size_t)N_ * 128;
    auto pad8 = [](int n) { return (size_t)((n + 7) & ~7); };

    // ---- workspace carve (~79 MB for N=50000, E=800000) ----
    char* p = (char*)d_ws;
    bf16* x  = (bf16*)p;      p += ND * 2;
    bf16* T  = (bf16*)p;      p += (size_t)N_ * 256 * 2;  // nodesb / PQ / hidden / y
    bf16* S  = (bf16*)p;      p += ND * 2;                // agg sum, then Fo (in-place)
    bf16* Fi = (bf16*)p;      p += ND * 2;
    bf16* wb[16];
    for (int t = 0; t < 16; ++t) { wb[t] = (bf16*)p; p += pad8(in_sizes[3 + t]) * 2; }
    bf16* WTenc  = (bf16*)p;  p += 256 * 128 * 2;
    bf16* WTpq_p = (bf16*)p;  p += 256 * 128 * 2;
    bf16* WTpq_c = (bf16*)p;  p += 256 * 128 * 2;
    bf16* WT2p   = (bf16*)p;  p += 128 * 128 * 2;
    bf16* WT2c   = (bf16*)p;  p += 128 * 128 * 2;
    bf16* WTf1   = (bf16*)p;  p += 384 * 256 * 2;
    bf16* WTf2   = (bf16*)p;  p += 256 * 128 * 2;
    bf16* WTconv = (bf16*)p;  p += 128 * 256 * 2;
    int* degd    = (int*)p;   p += (size_t)N_ * 4;
    int* degs    = (int*)p;   p += (size_t)N_ * 4;
    int* indptrd = (int*)p;   p += (size_t)(N_ + 1) * 4;
    int* indptrs = (int*)p;   p += (size_t)(N_ + 1) * 4;
    int* rankd   = (int*)p;   p += (size_t)E_ * 4;
    int* ranks   = (int*)p;   p += (size_t)E_ * 4;
    int* adjd    = (int*)p;   p += (size_t)E_ * 4;
    int* adjs    = (int*)p;   p += (size_t)E_ * 4;
    int* btotd   = (int*)p;   p += 256 * 4;
    int* btots   = (int*)p;   p += 256 * 4;
    float* invd  = (float*)p; p += (size_t)N_ * 4;
    float* invs  = (float*)p; p += (size_t)N_ * 4;
    float* cnt   = (float*)p; p += 8 * 4;
    float* gsum  = (float*)p; p += 2048 * 4;
    float* gmax  = (float*)p; p += 2048 * 4;
    int* flag    = (int*)p;   p += 64;
    size_t need = (size_t)(p - (char*)d_ws);

    if (ws_size < need) {
        diag_kernel<<<(out_size + 255) / 256, 256, 0, stream>>>((float*)d_out, (float)(ws_size >> 20), out_size);
        return;
    }

    bf16* Wencb = wb[0],  *bencb = wb[1];
    bf16* Wp1b  = wb[2],  *bp1b  = wb[3];
    bf16* Wp2b  = wb[4],  *bp2b  = wb[5];
    bf16* Wc1b  = wb[6],  *bc1b  = wb[7];
    bf16* Wc2b  = wb[8],  *bc2b  = wb[9];
    bf16* Wf1b  = wb[10], *bf1b  = wb[11];
    bf16* Wf2b  = wb[12], *bf2b  = wb[13];
    bf16* Wconvb = wb[14], *bconvb = wb[15];

    int gN = (N_ + 255) / 256;
    int gE4 = (E_ + 1023) / 1024;

    // ---- init + dtype probe + conversions ----
    init_kernel<<<(2 * N_ + 255) / 256, 256, 0, stream>>>(degd, cnt, gmax, flag, 2 * N_);
    int nwords = in_sizes[3] / 2;
    probe_kernel<<<(nwords + 255) / 256, 256, 0, stream>>>((const unsigned int*)d_in[3], nwords, flag);
    convert_kernel<<<(in_sizes[0] + 255) / 256, 256, 0, stream>>>(d_in[0], T, in_sizes[0], flag);
    {
        ConvSegs cs;
        int blk = 0;
        for (int t = 0; t < 16; ++t) {
            cs.src[t] = d_in[3 + t];
            cs.dst[t] = wb[t];
            cs.n[t] = in_sizes[3 + t];
            cs.startBlock[t] = blk;
            blk += (in_sizes[3 + t] + 255) / 256;
        }
        cs.startBlock[16] = blk;
        convert_multi_kernel<<<blk, 256, 0, stream>>>(cs, flag);
    }
    {
        TransSegs ts;
        const bf16* srcs[10] = {Wencb, Wp1b, Wp1b + 128 * 128, Wc1b, Wc1b + 128 * 128,
                                Wp2b, Wc2b, Wf1b, Wf2b, Wconvb};
        bf16* dsts[10] = {WTenc, WTpq_p, WTpq_p + 128 * 128, WTpq_c, WTpq_c + 128 * 128,
                          WT2p, WT2c, WTf1, WTf2, WTconv};
        int Ks[10]  = {256, 128, 128, 128, 128, 128, 128, 384, 256, 128};
        int NCs[10] = {128, 128, 128, 128, 128, 128, 128, 256, 128, 256};
        int blk = 0;
        for (int t = 0; t < 10; ++t) {
            ts.src[t] = srcs[t]; ts.dst[t] = dsts[t];
            ts.K[t] = Ks[t]; ts.NC[t] = NCs[t];
            ts.startBlock[t] = blk;
            blk += (Ks[t] * NCs[t] + 255) / 256;
        }
        ts.startBlock[10] = blk;
        transpose_multi_kernel<<<blk, 256, 0, stream>>>(ts);
    }

    // ---- CSR build (rank trick, atomic-free scatter) ----
    degcnt_kernel<<<gE4, 256, 0, stream>>>(edges, E_, degd, degs, rankd, ranks);
    scan_block2_kernel<<<2 * gN, 256, 0, stream>>>(degd, degs, indptrd + 1, indptrs + 1,
                                                   btotd, btots, N_, gN);
    scan_total2_kernel<<<2, 256, 0, stream>>>(btotd, btots, gN);
    finalize2_kernel<<<2 * gN, 256, 0, stream>>>(indptrd, indptrs, btotd, btots, N_, gN);
    inv_kernel<<<gN, 256, 0, stream>>>(degd, degs, invd, invs, N_);
    scatter_kernel<<<gE4, 256, 0, stream>>>(edges, E_, indptrd, indptrs, rankd, ranks, adjd, adjs);
    cnt_kernel<<<gN, 256, 0, stream>>>(batch, N_, cnt);

    int gb = (N_ + 63) / 64;
    int ga = (N_ + 3) / 4;

    // ---- encoder: x = nodes(T) @ Wenc + benc ----
    gemm_mfma_kernel<256, 128, 1, false, false, false><<<gb, 256, 0, stream>>>(
        T, nullptr, nullptr, WTenc, bencb, nullptr, x, N_);

    for (int it = 0; it < 2; ++it) {
        // parent: PQ = x@[Wp1_i ; Wp1_j] -> T ; S = gather-relu-sum ; Fi = S@Wp2*invd (+bp2)
        gemm_mfma_kernel<128, 256, 1, false, false, false><<<gb, 256, 0, stream>>>(
            x, nullptr, nullptr, WTpq_p, nullptr, nullptr, T, N_);
        agg_kernel<<<ga, 256, 0, stream>>>(indptrd, adjd, T, bp1b, S, N_);
        gemm_mfma_kernel<128, 128, 1, false, false, true><<<gb, 256, 0, stream>>>(
            S, nullptr, nullptr, WT2p, bp2b, invd, Fi, N_);
        // child: src-CSR; Fo = S in-place
        gemm_mfma_kernel<128, 256, 1, false, false, false><<<gb, 256, 0, stream>>>(
            x, nullptr, nullptr, WTpq_c, nullptr, nullptr, T, N_);
        agg_kernel<<<ga, 256, 0, stream>>>(indptrs, adjs, T, bc1b, S, N_);
        gemm_mfma_kernel<128, 128, 1, false, false, true><<<gb, 256, 0, stream>>>(
            S, nullptr, nullptr, WT2c, bc2b, invs, S, N_);
        // final MLP: H = relu([x,Fi,Fo]@Wf1+bf1) -> T ; x += H@Wf2+bf2
        gemm_mfma_kernel<384, 256, 3, true, false, false><<<gb, 256, 0, stream>>>(
            x, Fi, S, WTf1, bf1b, nullptr, T, N_);
        gemm_mfma_kernel<256, 128, 1, false, true, false><<<gb, 256, 0, stream>>>(
            T, nullptr, nullptr, WTf2, bf2b, nullptr, x, N_);
    }

    // conv + pool
    gemm_mfma_kernel<128, 256, 1, false, false, false><<<gb, 256, 0, stream>>>(
        x, nullptr, nullptr, WTconv, bconvb, nullptr, T, N_);
    pool_kernel<<<gb, 256, 0, stream>>>(T, batch, N_, gmax, gsum);
    out_kernel<<<16, 256, 0, stream>>>(gmax, gsum, cnt, flag, d_out);
}

// Round 8
// 840.406 us; speedup vs baseline: 3.4299x; 1.2998x over previous
//
#include <hip/hip_runtime.h>
#include <hip/hip_bf16.h>
#include <float.h>

typedef __hip_bfloat16 bf16;
typedef __hip_bfloat162 bf162;
typedef short short8 __attribute__((ext_vector_type(8)));   // 8 bf16 in 4 VGPRs
typedef short short4v __attribute__((ext_vector_type(4)));  // 4 bf16 in 2 VGPRs
typedef float f32x4 __attribute__((ext_vector_type(4)));

__device__ __forceinline__ float toF(bf16 v) { return __bfloat162float(v); }
__device__ __forceinline__ float s2f(short s) {
    return __uint_as_float(((unsigned int)(unsigned short)s) << 16);
}
__device__ __forceinline__ short f2s(float f) {
    bf16 h = __float2bfloat16(f);
    return *(short*)&h;
}

__global__ void diag_kernel(float* __restrict__ out, float v, int n) {
    int i = blockIdx.x * 256 + threadIdx.x;
    if (i < n) out[i] = v;
}

// Fused init: zero degd/degs (2N ints), zero cnt+gsum, gmax=-FLT_MAX, flag=1.
__global__ void init_kernel(int* __restrict__ deg2, float* __restrict__ cnt_gsum,
                            float* __restrict__ gmax, int* __restrict__ flag, int n2) {
    int i = blockIdx.x * 256 + threadIdx.x;
    if (i < n2) deg2[i] = 0;
    if (i < 8 + 2048) cnt_gsum[i] = 0.f;
    if (i < 2048) gmax[i] = -FLT_MAX;
    if (i == 0) *flag = 1;
}

// Dtype probe: low 16 bits of each word as bf16 — real weights if bf16 input,
// random mantissa garbage (huge/NaN) if f32 input.
__global__ void probe_kernel(const unsigned int* __restrict__ w, int nwords,
                             int* __restrict__ flag) {
    int i = blockIdx.x * 256 + threadIdx.x;
    if (i < nwords) {
        float v = __uint_as_float((w[i] & 0xFFFFu) << 16);
        if (!(v > -1e3f && v < 1e3f)) atomicAnd(flag, 0);
    }
}

__global__ void convert_kernel(const void* __restrict__ src, bf16* __restrict__ dst,
                               int n, const int* __restrict__ flag) {
    int i = blockIdx.x * 256 + threadIdx.x;
    if (i < n) {
        if (*flag) dst[i] = ((const bf16*)src)[i];
        else       dst[i] = __float2bfloat16(((const float*)src)[i]);
    }
}

// ---- fused multi-tensor convert (16 weight tensors in one launch) ----
struct ConvSegs {
    const void* src[16];
    bf16* dst[16];
    int n[16];
    int startBlock[17];
};
__global__ void convert_multi_kernel(ConvSegs s, const int* __restrict__ flag) {
    int b = blockIdx.x;
    int seg = 0;
#pragma unroll
    for (int t = 1; t < 16; ++t) if (b >= s.startBlock[t]) seg = t;
    int i = (b - s.startBlock[seg]) * 256 + threadIdx.x;
    if (i < s.n[seg]) {
        if (*flag) s.dst[seg][i] = ((const bf16*)s.src[seg])[i];
        else       s.dst[seg][i] = __float2bfloat16(((const float*)s.src[seg])[i]);
    }
}

// ---- fused multi-swizzle: W [K,NC] row-major -> B-fragment order ----
// dst[((t*KF+kb)*64+ln)*8+j] = W[kb*32+(ln>>4)*8+j][t*16+(ln&15)]
// so a wave's B-frag load for (tile t, kb) is 64 lanes x 16B contiguous.
struct SwizSegs {
    const bf16* src[10];
    bf16* dst[10];
    int K[10], NC[10];
    int startBlock[11];
};
__global__ void swizzle_multi_kernel(SwizSegs s) {
    int b = blockIdx.x;
    int seg = 0;
#pragma unroll
    for (int t = 1; t < 10; ++t) if (b >= s.startBlock[t]) seg = t;
    int i = (b - s.startBlock[seg]) * 256 + threadIdx.x;
    int K = s.K[seg], NC = s.NC[seg];
    if (i < K * NC) {
        int KF = K >> 5;
        int j = i & 7;
        int ln = (i >> 3) & 63;
        int q = i >> 9;
        int kb = q % KF;
        int t = q / KF;
        int k = kb * 32 + (ln >> 4) * 8 + j;
        int n = t * 16 + (ln & 15);
        s.dst[seg][i] = s.src[seg][k * NC + n];
    }
}

// Degrees + per-edge rank (rank = atomicAdd return). Ranks stored coalesced.
__global__ void degcnt_kernel(const int* __restrict__ edges, int E_,
                              int* __restrict__ degd, int* __restrict__ degs,
                              int* __restrict__ rankd, int* __restrict__ ranks) {
    int e0 = (blockIdx.x * 256 + threadIdx.x) * 4;
    if (e0 + 4 <= E_) {
        int4 s4 = *(const int4*)(edges + e0);
        int4 d4 = *(const int4*)(edges + E_ + e0);
        int4 rs, rd;
        rs.x = atomicAdd(&degs[s4.x], 1);
        rs.y = atomicAdd(&degs[s4.y], 1);
        rs.z = atomicAdd(&degs[s4.z], 1);
        rs.w = atomicAdd(&degs[s4.w], 1);
        rd.x = atomicAdd(&degd[d4.x], 1);
        rd.y = atomicAdd(&degd[d4.y], 1);
        rd.z = atomicAdd(&degd[d4.z], 1);
        rd.w = atomicAdd(&degd[d4.w], 1);
        *(int4*)(ranks + e0) = rs;
        *(int4*)(rankd + e0) = rd;
    } else {
        for (int e = e0; e < E_; ++e) {
            ranks[e] = atomicAdd(&degs[edges[e]], 1);
            rankd[e] = atomicAdd(&degd[edges[E_ + e]], 1);
        }
    }
}

// Fused scan of both degree arrays: blocks [0,gN) -> d, [gN,2gN) -> s.
__global__ void scan_block2_kernel(const int* __restrict__ degd, const int* __restrict__ degs,
                                   int* __restrict__ outd, int* __restrict__ outs,
                                   int* __restrict__ btotd, int* __restrict__ btots,
                                   int n, int gN) {
    __shared__ int s[256];
    int bb = blockIdx.x;
    const int* in = (bb < gN) ? degd : degs;
    int* out      = (bb < gN) ? outd : outs;
    int* btot     = (bb < gN) ? btotd : btots;
    int blk       = (bb < gN) ? bb : bb - gN;
    int t = threadIdx.x;
    int i = blk * 256 + t;
    s[t] = (i < n) ? in[i] : 0;
    __syncthreads();
    for (int off = 1; off < 256; off <<= 1) {
        int add = (t >= off) ? s[t - off] : 0;
        __syncthreads();
        s[t] += add;
        __syncthreads();
    }
    if (i < n) out[i] = s[t];
    if (t == 255) btot[blk] = s[255];
}

__global__ void scan_total2_kernel(int* __restrict__ btotd, int* __restrict__ btots, int G) {
    __shared__ int s[256];
    int* btot = (blockIdx.x == 0) ? btotd : btots;
    int t = threadIdx.x;
    s[t] = (t < G) ? btot[t] : 0;
    __syncthreads();
    for (int off = 1; off < 256; off <<= 1) {
        int add = (t >= off) ? s[t - off] : 0;
        __syncthreads();
        s[t] += add;
        __syncthreads();
    }
    if (t < G) btot[t] = s[t];
}

__global__ void finalize2_kernel(int* __restrict__ indptrd, int* __restrict__ indptrs,
                                 const int* __restrict__ btotd, const int* __restrict__ btots,
                                 int n, int gN) {
    int bb = blockIdx.x;
    int* indptr     = (bb < gN) ? indptrd : indptrs;
    const int* btot = (bb < gN) ? btotd : btots;
    int blk         = (bb < gN) ? bb : bb - gN;
    int i = blk * 256 + threadIdx.x;
    if (i < n) {
        int b = i >> 8;
        if (b > 0) indptr[i + 1] += btot[b - 1];
    }
    if (i == 0) indptr[0] = 0;
}

__global__ void inv_kernel(const int* __restrict__ degd, const int* __restrict__ degs,
                           float* __restrict__ invd, float* __restrict__ invs, int n) {
    int i = blockIdx.x * 256 + threadIdx.x;
    if (i < n) {
        int dd = degd[i]; invd[i] = dd > 0 ? 1.0f / (float)dd : 0.0f;
        int ds = degs[i]; invs[i] = ds > 0 ? 1.0f / (float)ds : 0.0f;
    }
}

// Atomic-free scatter: adj[indptr[node] + rank[e]] = other endpoint.
__global__ void scatter_kernel(const int* __restrict__ edges, int E_,
                               const int* __restrict__ indptrd, const int* __restrict__ indptrs,
                               const int* __restrict__ rankd, const int* __restrict__ ranks,
                               int* __restrict__ adjd, int* __restrict__ adjs) {
    int e0 = (blockIdx.x * 256 + threadIdx.x) * 4;
    if (e0 + 4 <= E_) {
        int4 s4 = *(const int4*)(edges + e0);
        int4 d4 = *(const int4*)(edges + E_ + e0);
        int4 rd = *(const int4*)(rankd + e0);
        int4 rs = *(const int4*)(ranks + e0);
        adjd[indptrd[d4.x] + rd.x] = s4.x;
        adjd[indptrd[d4.y] + rd.y] = s4.y;
        adjd[indptrd[d4.z] + rd.z] = s4.z;
        adjd[indptrd[d4.w] + rd.w] = s4.w;
        adjs[indptrs[s4.x] + rs.x] = d4.x;
        adjs[indptrs[s4.y] + rs.y] = d4.y;
        adjs[indptrs[s4.z] + rs.z] = d4.z;
        adjs[indptrs[s4.w] + rs.w] = d4.w;
    } else {
        for (int e = e0; e < E_; ++e) {
            int s_ = edges[e], d_ = edges[E_ + e];
            adjd[indptrd[d_] + rankd[e]] = s_;
            adjs[indptrs[s_] + ranks[e]] = d_;
        }
    }
}

__global__ void cnt_kernel(const int* __restrict__ batch, int n, float* __restrict__ cnt) {
    __shared__ float loc[8];
    int tid = threadIdx.x;
    if (tid < 8) loc[tid] = 0.f;
    __syncthreads();
    int i = blockIdx.x * 256 + tid;
    if (i < n) atomicAdd(&loc[batch[i]], 1.0f);
    __syncthreads();
    if (tid < 8 && loc[tid] > 0.f) atomicAdd(&cnt[tid], loc[tid]);
}

// ---------------- MFMA GEMM (LDS-staged, coalesced) ----------------
// C[M,NC] = act(A[M,K] @ W [+bias][*scale]) [+C residual]
// WS = swizzled weights (see swizzle_multi_kernel). Block = 4 waves x 16 rows.
// Phase 1: stage A tile (64 x K, pad +8) via coalesced 16B loads.
// Phase 2: ds_read A-frags, global 1KB-coalesced B-frags, MFMA.
// Phase 3: epilogue -> LDS C tile -> coalesced 16B stores (RES folded here).
// In-place C==A0 safe at block granularity (A staged before any store).
template<int K, int NC, int NSRC, bool RELU, bool RES, bool SCALE>
__global__ void gemm_mfma_kernel(const bf16* A0, const bf16* A1, const bf16* A2,
                                 const bf16* WS, const bf16* bias,
                                 const float* scale, bf16* C, int M) {
    constexpr int KF = K / 32;
    constexpr int NT = NC / 16;
    constexpr int APAD = K + 8;
    constexpr int CPAD = NC + 8;
    constexpr int ABYTES = 64 * APAD * 2;
    constexpr int CBYTES = 64 * CPAD * 2;
    constexpr int SBYTES = ABYTES > CBYTES ? ABYTES : CBYTES;
    __shared__ __align__(16) char smem[SBYTES];
    short* sA = (short*)smem;

    int tid = threadIdx.x;
    int m0blk = blockIdx.x * 64;

    // ---- phase 1: stage A tile ----
    constexpr int C8 = K / 8;
    for (int idx = tid; idx < 64 * C8; idx += 256) {
        int r = idx / C8, c8 = idx % C8;
        int row = m0blk + r; row = row < M ? row : M - 1;
        const bf16* src;
        int off;
        if (NSRC == 1) { src = A0; off = c8 * 8; }
        else {
            int seg = c8 >> 4;                 // 16 chunks per 128-col source
            src = seg == 0 ? A0 : (seg == 1 ? A1 : A2);
            off = (c8 & 15) * 8;
        }
        const size_t rs = (NSRC == 1) ? (size_t)K : (size_t)128;
        *(short8*)(sA + r * APAD + c8 * 8) = *(const short8*)((const short*)src + (size_t)row * rs + off);
    }
    __syncthreads();

    int wv = tid >> 6, ln = tid & 63;
    int quad = ln >> 4, ncol = ln & 15;
    int mw = wv * 16;

    short8 a[KF];
#pragma unroll
    for (int kb = 0; kb < KF; ++kb)
        a[kb] = *(const short8*)(sA + (mw + ncol) * APAD + kb * 32 + quad * 8);

    f32x4 acc[NT];
#pragma unroll
    for (int t = 0; t < NT; ++t) acc[t] = (f32x4){0.f, 0.f, 0.f, 0.f};

    const short8* wsp = (const short8*)WS;
    for (int t = 0; t < NT; ++t) {
#pragma unroll
        for (int kb = 0; kb < KF; ++kb) {
            short8 b = wsp[(size_t)(t * KF + kb) * 64 + ln];
            acc[t] = __builtin_amdgcn_mfma_f32_16x16x32_bf16(a[kb], b, acc[t], 0, 0, 0);
        }
    }
    __syncthreads();                            // A tile dead; reuse LDS for C

    // ---- phase 2: epilogue into LDS C tile ----
    short* sC = (short*)smem;
    float scl[4];
    if (SCALE) {
#pragma unroll
        for (int r = 0; r < 4; ++r) {
            int orow = m0blk + mw + quad * 4 + r;
            scl[r] = scale[orow < M ? orow : M - 1];
        }
    }
    for (int t = 0; t < NT; ++t) {
        float bv = bias ? toF(bias[t * 16 + ncol]) : 0.f;
#pragma unroll
        for (int r = 0; r < 4; ++r) {
            float v = acc[t][r];
            if (SCALE) { v *= scl[r]; if (scl[r] > 0.f) v += bv; }
            else v += bv;
            if (RELU) v = fmaxf(v, 0.f);
            sC[(mw + quad * 4 + r) * CPAD + t * 16 + ncol] = f2s(v);
        }
    }
    __syncthreads();

    // ---- phase 3: coalesced store (+ residual) ----
    constexpr int OC8 = NC / 8;
    for (int idx = tid; idx < 64 * OC8; idx += 256) {
        int r = idx / OC8, c8 = idx % OC8;
        int row = m0blk + r;
        if (row < M) {
            short8 v = *(short8*)(sC + r * CPAD + c8 * 8);
            size_t o = (size_t)row * NC + c8 * 8;
            if (RES) {
                short8 old = *(const short8*)((const short*)C + o);
#pragma unroll
                for (int j = 0; j < 8; ++j) v[j] = f2s(s2f(v[j]) + s2f(old[j]));
            }
            *(short8*)((short*)C + o) = v;
        }
    }
}

// S[i,:] = sum_{j in adj[i]} relu(P[i,:] + Q[j,:] + b1)
// PQ [M,256]: cols 0-127 = P, 128-255 = Q. 4 nodes/block, 1 wave/node.
// Lane covers 4 cols (8B); half-waves take alternating neighbors; x4 unroll
// -> 8 independent 256B gathers in flight per wave. Halves merge via shfl_xor(32).
__global__ void agg_kernel(const int* __restrict__ indptr, const int* __restrict__ adj,
                           const bf16* __restrict__ PQ, const bf16* __restrict__ b1,
                           bf16* __restrict__ S, int M) {
    int tid = threadIdx.x;
    int wv = tid >> 6, ln = tid & 63;
    int node = blockIdx.x * 4 + wv;
    if (node >= M) return;
    int c4 = ln & 31, half = ln >> 5;
    float p[4];
    {
        short4v pv = *(const short4v*)((const short*)PQ + (size_t)node * 256 + 4 * c4);
        short4v bv = *(const short4v*)((const short*)b1 + 4 * c4);
#pragma unroll
        for (int r = 0; r < 4; ++r) p[r] = s2f(pv[r]) + s2f(bv[r]);
    }
    float a[4] = {0.f, 0.f, 0.f, 0.f};
    int beg = indptr[node], end = indptr[node + 1];
    const short* Qb = (const short*)PQ + 128 + 4 * c4;
    int k = beg + half;
    for (; k + 6 < end; k += 8) {
        int j0 = adj[k], j1 = adj[k + 2], j2 = adj[k + 4], j3 = adj[k + 6];
        short4v q0 = *(const short4v*)(Qb + (size_t)j0 * 256);
        short4v q1 = *(const short4v*)(Qb + (size_t)j1 * 256);
        short4v q2 = *(const short4v*)(Qb + (size_t)j2 * 256);
        short4v q3 = *(const short4v*)(Qb + (size_t)j3 * 256);
#pragma unroll
        for (int r = 0; r < 4; ++r)
            a[r] += fmaxf(p[r] + s2f(q0[r]), 0.f) + fmaxf(p[r] + s2f(q1[r]), 0.f)
                  + fmaxf(p[r] + s2f(q2[r]), 0.f) + fmaxf(p[r] + s2f(q3[r]), 0.f);
    }
    for (; k < end; k += 2) {
        int j = adj[k];
        short4v q = *(const short4v*)(Qb + (size_t)j * 256);
#pragma unroll
        for (int r = 0; r < 4; ++r) a[r] += fmaxf(p[r] + s2f(q[r]), 0.f);
    }
#pragma unroll
    for (int r = 0; r < 4; ++r) a[r] += __shfl_xor(a[r], 32);
    if (half == 0) {
        short4v o;
#pragma unroll
        for (int r = 0; r < 4; ++r) o[r] = f2s(a[r]);
        *(short4v*)((short*)S + (size_t)node * 128 + 4 * c4) = o;
    }
}

__device__ __forceinline__ void atomicMaxF(float* addr, float val) {
    unsigned int* ua = (unsigned int*)addr;
    unsigned int old = __float_as_uint(*addr);
    while (__uint_as_float(old) < val) {
        unsigned int assumed = old;
        old = atomicCAS(ua, assumed, __float_as_uint(val));
        if (old == assumed) break;
    }
}

// Streamed segment max/sum over sorted batch; y [M,256], thread = col.
__global__ void pool_kernel(const bf16* __restrict__ y, const int* __restrict__ batch,
                            int M, float* __restrict__ gmax, float* __restrict__ gsum) {
    int tid = threadIdx.x;
    int row0 = blockIdx.x * 64;
    int cur_b = -1;
    float mx = -FLT_MAX, sm = 0.f;
    int rend = M - row0; if (rend > 64) rend = 64;
    for (int r = 0; r < rend; ++r) {
        int row = row0 + r;
        float v = toF(y[(size_t)row * 256 + tid]);
        int b = batch[row];
        if (b != cur_b) {
            if (cur_b >= 0) {
                atomicMaxF(&gmax[cur_b * 256 + tid], mx);
                atomicAdd(&gsum[cur_b * 256 + tid], sm);
            }
            cur_b = b; mx = v; sm = v;
        } else {
            mx = fmaxf(mx, v);
            sm += v;
        }
    }
    if (cur_b >= 0) {
        atomicMaxF(&gmax[cur_b * 256 + tid], mx);
        atomicAdd(&gsum[cur_b * 256 + tid], sm);
    }
}

__global__ void out_kernel(const float* __restrict__ gmax, const float* __restrict__ gsum,
                           const float* __restrict__ cnt, const int* __restrict__ flag,
                           void* __restrict__ out) {
    int i = blockIdx.x * 256 + threadIdx.x;
    if (i < 8 * 512) {
        int b = i >> 9, c = i & 511;
        float v = (c < 256) ? gmax[b * 256 + c] : gsum[b * 256 + (c - 256)] / cnt[b];
        int f = *flag;
        if (!(v == v)) v = 1000.f + 100.f * (float)f;
        if (f) ((bf16*)out)[i] = __float2bfloat16(v);
        else   ((float*)out)[i] = v;
    }
}

extern "C" void kernel_launch(void* const* d_in, const int* in_sizes, int n_in,
                              void* d_out, int out_size, void* d_ws, size_t ws_size,
                              hipStream_t stream) {
    const int* edges = (const int*)d_in[1];
    const int* batch = (const int*)d_in[2];

    const int N_ = in_sizes[2];
    const int E_ = in_sizes[1] / 2;
    const size_t ND = (size_t)N_ * 128;
    auto pad8 = [](int n) { return (size_t)((n + 7) & ~7); };

    // ---- workspace carve (~79 MB for N=50000, E=800000) ----
    char* p = (char*)d_ws;
    bf16* x  = (bf16*)p;      p += ND * 2;
    bf16* T  = (bf16*)p;      p += (size_t)N_ * 256 * 2;  // nodesb / PQ / hidden / y
    bf16* S  = (bf16*)p;      p += ND * 2;                // agg sum, then Fo (in-place)
    bf16* Fi = (bf16*)p;      p += ND * 2;
    bf16* wb[16];
    for (int t = 0; t < 16; ++t) { wb[t] = (bf16*)p; p += pad8(in_sizes[3 + t]) * 2; }
    bf16* WSenc  = (bf16*)p;  p += 256 * 128 * 2;
    bf16* WSpq_p = (bf16*)p;  p += 256 * 128 * 2;
    bf16* WSpq_c = (bf16*)p;  p += 256 * 128 * 2;
    bf16* WS2p   = (bf16*)p;  p += 128 * 128 * 2;
    bf16* WS2c   = (bf16*)p;  p += 128 * 128 * 2;
    bf16* WSf1   = (bf16*)p;  p += 384 * 256 * 2;
    bf16* WSf2   = (bf16*)p;  p += 256 * 128 * 2;
    bf16* WSconv = (bf16*)p;  p += 128 * 256 * 2;
    int* degd    = (int*)p;   p += (size_t)N_ * 4;
    int* degs    = (int*)p;   p += (size_t)N_ * 4;
    int* indptrd = (int*)p;   p += (size_t)(N_ + 1) * 4;
    int* indptrs = (int*)p;   p += (size_t)(N_ + 1) * 4;
    int* rankd   = (int*)p;   p += (size_t)E_ * 4;
    int* ranks   = (int*)p;   p += (size_t)E_ * 4;
    int* adjd    = (int*)p;   p += (size_t)E_ * 4;
    int* adjs    = (int*)p;   p += (size_t)E_ * 4;
    int* btotd   = (int*)p;   p += 256 * 4;
    int* btots   = (int*)p;   p += 256 * 4;
    float* invd  = (float*)p; p += (size_t)N_ * 4;
    float* invs  = (float*)p; p += (size_t)N_ * 4;
    float* cnt   = (float*)p; p += 8 * 4;
    float* gsum  = (float*)p; p += 2048 * 4;
    float* gmax  = (float*)p; p += 2048 * 4;
    int* flag    = (int*)p;   p += 64;
    size_t need = (size_t)(p - (char*)d_ws);

    if (ws_size < need) {
        diag_kernel<<<(out_size + 255) / 256, 256, 0, stream>>>((float*)d_out, (float)(ws_size >> 20), out_size);
        return;
    }

    bf16* Wencb = wb[0],  *bencb = wb[1];
    bf16* Wp1b  = wb[2],  *bp1b  = wb[3];
    bf16* Wp2b  = wb[4],  *bp2b  = wb[5];
    bf16* Wc1b  = wb[6],  *bc1b  = wb[7];
    bf16* Wc2b  = wb[8],  *bc2b  = wb[9];
    bf16* Wf1b  = wb[10], *bf1b  = wb[11];
    bf16* Wf2b  = wb[12], *bf2b  = wb[13];
    bf16* Wconvb = wb[14], *bconvb = wb[15];

    int gN = (N_ + 255) / 256;
    int gE4 = (E_ + 1023) / 1024;

    // ---- init + dtype probe + conversions ----
    init_kernel<<<(2 * N_ + 255) / 256, 256, 0, stream>>>(degd, cnt, gmax, flag, 2 * N_);
    int nwords = in_sizes[3] / 2;
    probe_kernel<<<(nwords + 255) / 256, 256, 0, stream>>>((const unsigned int*)d_in[3], nwords, flag);
    convert_kernel<<<(in_sizes[0] + 255) / 256, 256, 0, stream>>>(d_in[0], T, in_sizes[0], flag);
    {
        ConvSegs cs;
        int blk = 0;
        for (int t = 0; t < 16; ++t) {
            cs.src[t] = d_in[3 + t];
            cs.dst[t] = wb[t];
            cs.n[t] = in_sizes[3 + t];
            cs.startBlock[t] = blk;
            blk += (in_sizes[3 + t] + 255) / 256;
        }
        cs.startBlock[16] = blk;
        convert_multi_kernel<<<blk, 256, 0, stream>>>(cs, flag);
    }
    {
        SwizSegs ts;
        const bf16* srcs[10] = {Wencb, Wp1b, Wp1b + 128 * 128, Wc1b, Wc1b + 128 * 128,
                                Wp2b, Wc2b, Wf1b, Wf2b, Wconvb};
        bf16* dsts[10] = {WSenc, WSpq_p, WSpq_p + 128 * 128, WSpq_c, WSpq_c + 128 * 128,
                          WS2p, WS2c, WSf1, WSf2, WSconv};
        int Ks[10]  = {256, 128, 128, 128, 128, 128, 128, 384, 256, 128};
        int NCs[10] = {128, 128, 128, 128, 128, 128, 128, 256, 128, 256};
        int blk = 0;
        for (int t = 0; t < 10; ++t) {
            ts.src[t] = srcs[t]; ts.dst[t] = dsts[t];
            ts.K[t] = Ks[t]; ts.NC[t] = NCs[t];
            ts.startBlock[t] = blk;
            blk += (Ks[t] * NCs[t] + 255) / 256;
        }
        ts.startBlock[10] = blk;
        swizzle_multi_kernel<<<blk, 256, 0, stream>>>(ts);
    }

    // ---- CSR build (rank trick, atomic-free scatter) ----
    degcnt_kernel<<<gE4, 256, 0, stream>>>(edges, E_, degd, degs, rankd, ranks);
    scan_block2_kernel<<<2 * gN, 256, 0, stream>>>(degd, degs, indptrd + 1, indptrs + 1,
                                                   btotd, btots, N_, gN);
    scan_total2_kernel<<<2, 256, 0, stream>>>(btotd, btots, gN);
    finalize2_kernel<<<2 * gN, 256, 0, stream>>>(indptrd, indptrs, btotd, btots, N_, gN);
    inv_kernel<<<gN, 256, 0, stream>>>(degd, degs, invd, invs, N_);
    scatter_kernel<<<gE4, 256, 0, stream>>>(edges, E_, indptrd, indptrs, rankd, ranks, adjd, adjs);
    cnt_kernel<<<gN, 256, 0, stream>>>(batch, N_, cnt);

    int gb = (N_ + 63) / 64;
    int ga = (N_ + 3) / 4;

    // ---- encoder: x = nodes(T) @ Wenc + benc ----
    gemm_mfma_kernel<256, 128, 1, false, false, false><<<gb, 256, 0, stream>>>(
        T, nullptr, nullptr, WSenc, bencb, nullptr, x, N_);

    for (int it = 0; it < 2; ++it) {
        // parent: PQ = x@[Wp1_i ; Wp1_j] -> T ; S = gather-relu-sum ; Fi = S@Wp2*invd (+bp2)
        gemm_mfma_kernel<128, 256, 1, false, false, false><<<gb, 256, 0, stream>>>(
            x, nullptr, nullptr, WSpq_p, nullptr, nullptr, T, N_);
        agg_kernel<<<ga, 256, 0, stream>>>(indptrd, adjd, T, bp1b, S, N_);
        gemm_mfma_kernel<128, 128, 1, false, false, true><<<gb, 256, 0, stream>>>(
            S, nullptr, nullptr, WS2p, bp2b, invd, Fi, N_);
        // child: src-CSR; Fo = S in-place
        gemm_mfma_kernel<128, 256, 1, false, false, false><<<gb, 256, 0, stream>>>(
            x, nullptr, nullptr, WSpq_c, nullptr, nullptr, T, N_);
        agg_kernel<<<ga, 256, 0, stream>>>(indptrs, adjs, T, bc1b, S, N_);
        gemm_mfma_kernel<128, 128, 1, false, false, true><<<gb, 256, 0, stream>>>(
            S, nullptr, nullptr, WS2c, bc2b, invs, S, N_);
        // final MLP: H = relu([x,Fi,Fo]@Wf1+bf1) -> T ; x += H@Wf2+bf2
        gemm_mfma_kernel<384, 256, 3, true, false, false><<<gb, 256, 0, stream>>>(
            x, Fi, S, WSf1, bf1b, nullptr, T, N_);
        gemm_mfma_kernel<256, 128, 1, false, true, false><<<gb, 256, 0, stream>>>(
            T, nullptr, nullptr, WSf2, bf2b, nullptr, x, N_);
    }

    // conv + pool
    gemm_mfma_kernel<128, 256, 1, false, false, false><<<gb, 256, 0, stream>>>(
        x, nullptr, nullptr, WSconv, bconvb, nullptr, T, N_);
    pool_kernel<<<gb, 256, 0, stream>>>(T, batch, N_, gmax, gsum);
    out_kernel<<<16, 256, 0, stream>>>(gmax, gsum, cnt, flag, d_out);
}

// Round 9
// 727.033 us; speedup vs baseline: 3.9647x; 1.1559x over previous
//
#include <hip/hip_runtime.h>
#include <hip/hip_bf16.h>
#include <float.h>

typedef __hip_bfloat16 bf16;
typedef short short8 __attribute__((ext_vector_type(8)));   // 8 bf16 in 4 VGPRs
typedef short short4v __attribute__((ext_vector_type(4)));  // 4 bf16 in 2 VGPRs
typedef float f32x4 __attribute__((ext_vector_type(4)));

__device__ __forceinline__ float toF(bf16 v) { return __bfloat162float(v); }
__device__ __forceinline__ float s2f(short s) {
    return __uint_as_float(((unsigned int)(unsigned short)s) << 16);
}
__device__ __forceinline__ short f2s(float f) {
    bf16 h = __float2bfloat16(f);
    return *(short*)&h;
}

__global__ void diag_kernel(float* __restrict__ out, float v, int n) {
    int i = blockIdx.x * 256 + threadIdx.x;
    if (i < n) out[i] = v;
}

// Fused init: zero degd/degs (2N ints), zero cnt+gsum, gmax=-FLT_MAX, flag=1.
__global__ void init_kernel(int* __restrict__ deg2, float* __restrict__ cnt_gsum,
                            float* __restrict__ gmax, int* __restrict__ flag, int n2) {
    int i = blockIdx.x * 256 + threadIdx.x;
    if (i < n2) deg2[i] = 0;
    if (i < 8 + 2048) cnt_gsum[i] = 0.f;
    if (i < 2048) gmax[i] = -FLT_MAX;
    if (i == 0) *flag = 1;
}

// Dtype probe (f32 vs bf16 inputs). Ballot-elect: ONE atomic per wave max
// (round-8 counters: per-thread same-address atomicAnd serialized -> 89us).
__global__ void probe_kernel(const unsigned int* __restrict__ w, int nwords,
                             int* __restrict__ flag) {
    int i = blockIdx.x * 256 + threadIdx.x;
    bool bad = false;
    if (i < nwords) {
        float v = __uint_as_float((w[i] & 0xFFFFu) << 16);
        bad = !(v > -1e3f && v < 1e3f);
    }
    if (__any(bad) && (threadIdx.x & 63) == 0) atomicAnd(flag, 0);
}

__global__ void convert_kernel(const void* __restrict__ src, bf16* __restrict__ dst,
                               int n, const int* __restrict__ flag) {
    int i = blockIdx.x * 256 + threadIdx.x;
    if (i < n) {
        if (*flag) dst[i] = ((const bf16*)src)[i];
        else       dst[i] = __float2bfloat16(((const float*)src)[i]);
    }
}

// ---- fused multi-tensor convert (16 weight tensors in one launch) ----
struct ConvSegs {
    const void* src[16];
    bf16* dst[16];
    int n[16];
    int startBlock[17];
};
__global__ void convert_multi_kernel(ConvSegs s, const int* __restrict__ flag) {
    int b = blockIdx.x;
    int seg = 0;
#pragma unroll
    for (int t = 1; t < 16; ++t) if (b >= s.startBlock[t]) seg = t;
    int i = (b - s.startBlock[seg]) * 256 + threadIdx.x;
    if (i < s.n[seg]) {
        if (*flag) s.dst[seg][i] = ((const bf16*)s.src[seg])[i];
        else       s.dst[seg][i] = __float2bfloat16(((const float*)s.src[seg])[i]);
    }
}

// ---- fused multi-swizzle: W [K,NC] row-major -> B-fragment order ----
// dst[((t*KF+kb)*64+ln)*8+j] = W[kb*32+(ln>>4)*8+j][t*16+(ln&15)]
struct SwizSegs {
    const bf16* src[10];
    bf16* dst[10];
    int K[10], NC[10];
    int startBlock[11];
};
__global__ void swizzle_multi_kernel(SwizSegs s) {
    int b = blockIdx.x;
    int seg = 0;
#pragma unroll
    for (int t = 1; t < 10; ++t) if (b >= s.startBlock[t]) seg = t;
    int i = (b - s.startBlock[seg]) * 256 + threadIdx.x;
    int K = s.K[seg], NC = s.NC[seg];
    if (i < K * NC) {
        int KF = K >> 5;
        int j = i & 7;
        int ln = (i >> 3) & 63;
        int q = i >> 9;
        int kb = q % KF;
        int t = q / KF;
        int k = kb * 32 + (ln >> 4) * 8 + j;
        int n = t * 16 + (ln & 15);
        s.dst[seg][i] = s.src[seg][k * NC + n];
    }
}

// Degrees + per-edge rank (rank = atomicAdd return). Ranks stored coalesced.
__global__ void degcnt_kernel(const int* __restrict__ edges, int E_,
                              int* __restrict__ degd, int* __restrict__ degs,
                              int* __restrict__ rankd, int* __restrict__ ranks) {
    int e0 = (blockIdx.x * 256 + threadIdx.x) * 4;
    if (e0 + 4 <= E_) {
        int4 s4 = *(const int4*)(edges + e0);
        int4 d4 = *(const int4*)(edges + E_ + e0);
        int4 rs, rd;
        rs.x = atomicAdd(&degs[s4.x], 1);
        rs.y = atomicAdd(&degs[s4.y], 1);
        rs.z = atomicAdd(&degs[s4.z], 1);
        rs.w = atomicAdd(&degs[s4.w], 1);
        rd.x = atomicAdd(&degd[d4.x], 1);
        rd.y = atomicAdd(&degd[d4.y], 1);
        rd.z = atomicAdd(&degd[d4.z], 1);
        rd.w = atomicAdd(&degd[d4.w], 1);
        *(int4*)(ranks + e0) = rs;
        *(int4*)(rankd + e0) = rd;
    } else {
        for (int e = e0; e < E_; ++e) {
            ranks[e] = atomicAdd(&degs[edges[e]], 1);
            rankd[e] = atomicAdd(&degd[edges[E_ + e]], 1);
        }
    }
}

// Fused scan of both degree arrays: blocks [0,gN) -> d, [gN,2gN) -> s.
__global__ void scan_block2_kernel(const int* __restrict__ degd, const int* __restrict__ degs,
                                   int* __restrict__ outd, int* __restrict__ outs,
                                   int* __restrict__ btotd, int* __restrict__ btots,
                                   int n, int gN) {
    __shared__ int s[256];
    int bb = blockIdx.x;
    const int* in = (bb < gN) ? degd : degs;
    int* out      = (bb < gN) ? outd : outs;
    int* btot     = (bb < gN) ? btotd : btots;
    int blk       = (bb < gN) ? bb : bb - gN;
    int t = threadIdx.x;
    int i = blk * 256 + t;
    s[t] = (i < n) ? in[i] : 0;
    __syncthreads();
    for (int off = 1; off < 256; off <<= 1) {
        int add = (t >= off) ? s[t - off] : 0;
        __syncthreads();
        s[t] += add;
        __syncthreads();
    }
    if (i < n) out[i] = s[t];
    if (t == 255) btot[blk] = s[255];
}

__global__ void scan_total2_kernel(int* __restrict__ btotd, int* __restrict__ btots, int G) {
    __shared__ int s[256];
    int* btot = (blockIdx.x == 0) ? btotd : btots;
    int t = threadIdx.x;
    s[t] = (t < G) ? btot[t] : 0;
    __syncthreads();
    for (int off = 1; off < 256; off <<= 1) {
        int add = (t >= off) ? s[t - off] : 0;
        __syncthreads();
        s[t] += add;
        __syncthreads();
    }
    if (t < G) btot[t] = s[t];
}

// blocks [0,2gN): finalize indptrs ; blocks [2gN,3gN): inv-degree compute.
__global__ void finalize_inv_kernel(int* __restrict__ indptrd, int* __restrict__ indptrs,
                                    const int* __restrict__ btotd, const int* __restrict__ btots,
                                    const int* __restrict__ degd, const int* __restrict__ degs,
                                    float* __restrict__ invd, float* __restrict__ invs,
                                    int n, int gN) {
    int bb = blockIdx.x;
    if (bb < 2 * gN) {
        int* indptr     = (bb < gN) ? indptrd : indptrs;
        const int* btot = (bb < gN) ? btotd : btots;
        int blk         = (bb < gN) ? bb : bb - gN;
        int i = blk * 256 + threadIdx.x;
        if (i < n) {
            int b = i >> 8;
            if (b > 0) indptr[i + 1] += btot[b - 1];
        }
        if (i == 0) indptr[0] = 0;
    } else {
        int i = (bb - 2 * gN) * 256 + threadIdx.x;
        if (i < n) {
            int dd = degd[i]; invd[i] = dd > 0 ? 1.0f / (float)dd : 0.0f;
            int ds = degs[i]; invs[i] = ds > 0 ? 1.0f / (float)ds : 0.0f;
        }
    }
}

// Atomic-free scatter: adj[indptr[node] + rank[e]] = other endpoint.
__global__ void scatter_kernel(const int* __restrict__ edges, int E_,
                               const int* __restrict__ indptrd, const int* __restrict__ indptrs,
                               const int* __restrict__ rankd, const int* __restrict__ ranks,
                               int* __restrict__ adjd, int* __restrict__ adjs) {
    int e0 = (blockIdx.x * 256 + threadIdx.x) * 4;
    if (e0 + 4 <= E_) {
        int4 s4 = *(const int4*)(edges + e0);
        int4 d4 = *(const int4*)(edges + E_ + e0);
        int4 rd = *(const int4*)(rankd + e0);
        int4 rs = *(const int4*)(ranks + e0);
        adjd[indptrd[d4.x] + rd.x] = s4.x;
        adjd[indptrd[d4.y] + rd.y] = s4.y;
        adjd[indptrd[d4.z] + rd.z] = s4.z;
        adjd[indptrd[d4.w] + rd.w] = s4.w;
        adjs[indptrs[s4.x] + rs.x] = d4.x;
        adjs[indptrs[s4.y] + rs.y] = d4.y;
        adjs[indptrs[s4.z] + rs.z] = d4.z;
        adjs[indptrs[s4.w] + rs.w] = d4.w;
    } else {
        for (int e = e0; e < E_; ++e) {
            int s_ = edges[e], d_ = edges[E_ + e];
            adjd[indptrd[d_] + rankd[e]] = s_;
            adjs[indptrs[s_] + ranks[e]] = d_;
        }
    }
}

__global__ void cnt_kernel(const int* __restrict__ batch, int n, float* __restrict__ cnt) {
    __shared__ float loc[8];
    int tid = threadIdx.x;
    if (tid < 8) loc[tid] = 0.f;
    __syncthreads();
    int i = blockIdx.x * 256 + tid;
    if (i < n) atomicAdd(&loc[batch[i]], 1.0f);
    __syncthreads();
    if (tid < 8 && loc[tid] > 0.f) atomicAdd(&cnt[tid], loc[tid]);
}

__device__ __forceinline__ void atomicMaxF(float* addr, float val) {
    unsigned int* ua = (unsigned int*)addr;
    unsigned int old = __float_as_uint(*addr);
    while (__uint_as_float(old) < val) {
        unsigned int assumed = old;
        old = atomicCAS(ua, assumed, __float_as_uint(val));
        if (old == assumed) break;
    }
}

// ---------------- MFMA GEMM core (LDS-staged, coalesced) ----------------
template<int K, int NC> struct SB {
    static constexpr int APAD = K + 8;
    static constexpr int CPAD = NC + 8;
    static constexpr int AB = 64 * APAD * 2;
    static constexpr int CB = 64 * CPAD * 2;
    static constexpr int S = AB > CB ? AB : CB;
};

// C[M,NC] = act(A[M,K] @ W [+bias][*scale]) [+C res] | POOL: segment max/sum.
template<int K, int NC, int NSRC, bool RELU, bool RES, bool SCALE, bool POOL>
__device__ __forceinline__ void gemm_core(int bx,
    const bf16* A0, const bf16* A1, const bf16* A2,
    const bf16* WS, const bf16* bias, const float* scale, bf16* C, int M,
    const int* batch, float* gmax, float* gsum, char* smem) {
    constexpr int KF = K / 32;
    constexpr int NT = NC / 16;
    constexpr int APAD = SB<K, NC>::APAD;
    constexpr int CPAD = SB<K, NC>::CPAD;
    short* sA = (short*)smem;

    int tid = threadIdx.x;
    int m0blk = bx * 64;

    // phase 1: stage A tile (coalesced 16B)
    constexpr int C8 = K / 8;
    for (int idx = tid; idx < 64 * C8; idx += 256) {
        int r = idx / C8, c8 = idx % C8;
        int row = m0blk + r; row = row < M ? row : M - 1;
        const bf16* src;
        int off;
        if (NSRC == 1) { src = A0; off = c8 * 8; }
        else {
            int seg = c8 >> 4;
            src = seg == 0 ? A0 : (seg == 1 ? A1 : A2);
            off = (c8 & 15) * 8;
        }
        const size_t rs = (NSRC == 1) ? (size_t)K : (size_t)128;
        *(short8*)(sA + r * APAD + c8 * 8) = *(const short8*)((const short*)src + (size_t)row * rs + off);
    }
    __syncthreads();

    int wv = tid >> 6, ln = tid & 63;
    int quad = ln >> 4, ncol = ln & 15;
    int mw = wv * 16;

    short8 a[KF];
#pragma unroll
    for (int kb = 0; kb < KF; ++kb)
        a[kb] = *(const short8*)(sA + (mw + ncol) * APAD + kb * 32 + quad * 8);

    f32x4 acc[NT];
#pragma unroll
    for (int t = 0; t < NT; ++t) acc[t] = (f32x4){0.f, 0.f, 0.f, 0.f};

    const short8* wsp = (const short8*)WS;
    for (int t = 0; t < NT; ++t) {
#pragma unroll
        for (int kb = 0; kb < KF; ++kb) {
            short8 b = wsp[(size_t)(t * KF + kb) * 64 + ln];
            acc[t] = __builtin_amdgcn_mfma_f32_16x16x32_bf16(a[kb], b, acc[t], 0, 0, 0);
        }
    }
    __syncthreads();                            // A tile dead; reuse LDS for C

    // phase 2: epilogue into LDS C tile
    short* sC = (short*)smem;
    float scl[4];
    if (SCALE) {
#pragma unroll
        for (int r = 0; r < 4; ++r) {
            int orow = m0blk + mw + quad * 4 + r;
            scl[r] = scale[orow < M ? orow : M - 1];
        }
    }
    for (int t = 0; t < NT; ++t) {
        float bv = bias ? toF(bias[t * 16 + ncol]) : 0.f;
#pragma unroll
        for (int r = 0; r < 4; ++r) {
            float v = acc[t][r];
            if (SCALE) { v *= scl[r]; if (scl[r] > 0.f) v += bv; }
            else v += bv;
            if (RELU) v = fmaxf(v, 0.f);
            sC[(mw + quad * 4 + r) * CPAD + t * 16 + ncol] = f2s(v);
        }
    }
    __syncthreads();

    if (POOL) {
        // phase 3 (pool): segment max/sum over sorted batch, sourced from LDS.
        int* bs = (int*)(smem + SB<K, NC>::S);
        if (tid < 64) {
            int row = m0blk + tid;
            bs[tid] = (row < M) ? batch[row] : -1;
        }
        __syncthreads();
        int cur_b = -1;
        float mx = -FLT_MAX, sm = 0.f;
        for (int r = 0; r < 64; ++r) {
            int b = bs[r];
            if (b < 0) break;                       // rows sorted; tail only
            float v = s2f(sC[r * CPAD + tid]);      // NC==256, tid==col
            if (b != cur_b) {
                if (cur_b >= 0) {
                    atomicMaxF(&gmax[cur_b * 256 + tid], mx);
                    atomicAdd(&gsum[cur_b * 256 + tid], sm);
                }
                cur_b = b; mx = v; sm = v;
            } else {
                mx = fmaxf(mx, v);
                sm += v;
            }
        }
        if (cur_b >= 0) {
            atomicMaxF(&gmax[cur_b * 256 + tid], mx);
            atomicAdd(&gsum[cur_b * 256 + tid], sm);
        }
    } else {
        // phase 3: coalesced store (+ residual)
        constexpr int OC8 = NC / 8;
        for (int idx = tid; idx < 64 * OC8; idx += 256) {
            int r = idx / OC8, c8 = idx % OC8;
            int row = m0blk + r;
            if (row < M) {
                short8 v = *(short8*)(sC + r * CPAD + c8 * 8);
                size_t o = (size_t)row * NC + c8 * 8;
                if (RES) {
                    short8 old = *(const short8*)((const short*)C + o);
#pragma unroll
                    for (int j = 0; j < 8; ++j) v[j] = f2s(s2f(v[j]) + s2f(old[j]));
                }
                *(short8*)((short*)C + o) = v;
            }
        }
    }
}

template<int K, int NC, int NSRC, bool RELU, bool RES, bool SCALE, bool POOL>
__global__ void gemm_mfma_kernel(const bf16* A0, const bf16* A1, const bf16* A2,
                                 const bf16* WS, const bf16* bias,
                                 const float* scale, bf16* C, int M,
                                 const int* batch, float* gmax, float* gsum) {
    __shared__ __align__(16) char smem[SB<K, NC>::S + (POOL ? 256 : 0)];
    gemm_core<K, NC, NSRC, RELU, RES, SCALE, POOL>(
        blockIdx.x, A0, A1, A2, WS, bias, scale, C, M, batch, gmax, gsum, smem);
}

// Fused: blocks [0,split) = parent S-gemm (Fi = Sp@WS2*inv + b2);
//        blocks [split,..) = child PQ-gemm (T = x@WSpq). Independent.
__global__ void gemm_dual_kernel(const bf16* Sp, const bf16* WS2, const bf16* b2,
                                 const float* inv, bf16* Fi,
                                 const bf16* x, const bf16* WSpq, bf16* T,
                                 int M, int split) {
    __shared__ __align__(16) char smem[SB<128, 256>::S];
    if (blockIdx.x < split)
        gemm_core<128, 128, 1, false, false, true, false>(
            blockIdx.x, Sp, nullptr, nullptr, WS2, b2, inv, Fi, M, nullptr, nullptr, nullptr, smem);
    else
        gemm_core<128, 256, 1, false, false, false, false>(
            blockIdx.x - split, x, nullptr, nullptr, WSpq, nullptr, nullptr, T, M, nullptr, nullptr, nullptr, smem);
}

// S[i,:] = sum_{j in adj[i]} relu(P[i,:] + Q[j,:] + b1)
// PQ [M,256]: cols 0-127 = P, 128-255 = Q. 4 nodes/block, 1 wave/node.
// Half-waves take alternating neighbors, x4 unroll -> 8 gathers in flight.
__global__ void agg_kernel(const int* __restrict__ indptr, const int* __restrict__ adj,
                           const bf16* __restrict__ PQ, const bf16* __restrict__ b1,
                           bf16* __restrict__ S, int M) {
    int tid = threadIdx.x;
    int wv = tid >> 6, ln = tid & 63;
    int node = blockIdx.x * 4 + wv;
    if (node >= M) return;
    int c4 = ln & 31, half = ln >> 5;
    float p[4];
    {
        short4v pv = *(const short4v*)((const short*)PQ + (size_t)node * 256 + 4 * c4);
        short4v bv = *(const short4v*)((const short*)b1 + 4 * c4);
#pragma unroll
        for (int r = 0; r < 4; ++r) p[r] = s2f(pv[r]) + s2f(bv[r]);
    }
    float a[4] = {0.f, 0.f, 0.f, 0.f};
    int beg = indptr[node], end = indptr[node + 1];
    const short* Qb = (const short*)PQ + 128 + 4 * c4;
    int k = beg + half;
    for (; k + 6 < end; k += 8) {
        int j0 = adj[k], j1 = adj[k + 2], j2 = adj[k + 4], j3 = adj[k + 6];
        short4v q0 = *(const short4v*)(Qb + (size_t)j0 * 256);
        short4v q1 = *(const short4v*)(Qb + (size_t)j1 * 256);
        short4v q2 = *(const short4v*)(Qb + (size_t)j2 * 256);
        short4v q3 = *(const short4v*)(Qb + (size_t)j3 * 256);
#pragma unroll
        for (int r = 0; r < 4; ++r)
            a[r] += fmaxf(p[r] + s2f(q0[r]), 0.f) + fmaxf(p[r] + s2f(q1[r]), 0.f)
                  + fmaxf(p[r] + s2f(q2[r]), 0.f) + fmaxf(p[r] + s2f(q3[r]), 0.f);
    }
    for (; k < end; k += 2) {
        int j = adj[k];
        short4v q = *(const short4v*)(Qb + (size_t)j * 256);
#pragma unroll
        for (int r = 0; r < 4; ++r) a[r] += fmaxf(p[r] + s2f(q[r]), 0.f);
    }
#pragma unroll
    for (int r = 0; r < 4; ++r) a[r] += __shfl_xor(a[r], 32);
    if (half == 0) {
        short4v o;
#pragma unroll
        for (int r = 0; r < 4; ++r) o[r] = f2s(a[r]);
        *(short4v*)((short*)S + (size_t)node * 128 + 4 * c4) = o;
    }
}

__global__ void out_kernel(const float* __restrict__ gmax, const float* __restrict__ gsum,
                           const float* __restrict__ cnt, const int* __restrict__ flag,
                           void* __restrict__ out) {
    int i = blockIdx.x * 256 + threadIdx.x;
    if (i < 8 * 512) {
        int b = i >> 9, c = i & 511;
        float v = (c < 256) ? gmax[b * 256 + c] : gsum[b * 256 + (c - 256)] / cnt[b];
        int f = *flag;
        if (!(v == v)) v = 1000.f + 100.f * (float)f;
        if (f) ((bf16*)out)[i] = __float2bfloat16(v);
        else   ((float*)out)[i] = v;
    }
}

extern "C" void kernel_launch(void* const* d_in, const int* in_sizes, int n_in,
                              void* d_out, int out_size, void* d_ws, size_t ws_size,
                              hipStream_t stream) {
    const int* edges = (const int*)d_in[1];
    const int* batch = (const int*)d_in[2];

    const int N_ = in_sizes[2];
    const int E_ = in_sizes[1] / 2;
    const size_t ND = (size_t)N_ * 128;
    auto pad8 = [](int n) { return (size_t)((n + 7) & ~7); };

    // ---- workspace carve (~79 MB for N=50000, E=800000; proven fits) ----
    char* p = (char*)d_ws;
    bf16* x  = (bf16*)p;      p += ND * 2;
    bf16* T  = (bf16*)p;      p += (size_t)N_ * 256 * 2;  // nodesb / PQ / hidden
    bf16* S  = (bf16*)p;      p += ND * 2;                // agg sum / Fo in-place
    bf16* Fi = (bf16*)p;      p += ND * 2;
    bf16* wb[16];
    for (int t = 0; t < 16; ++t) { wb[t] = (bf16*)p; p += pad8(in_sizes[3 + t]) * 2; }
    bf16* WSenc  = (bf16*)p;  p += 256 * 128 * 2;
    bf16* WSpq_p = (bf16*)p;  p += 256 * 128 * 2;
    bf16* WSpq_c = (bf16*)p;  p += 256 * 128 * 2;
    bf16* WS2p   = (bf16*)p;  p += 128 * 128 * 2;
    bf16* WS2c   = (bf16*)p;  p += 128 * 128 * 2;
    bf16* WSf1   = (bf16*)p;  p += 384 * 256 * 2;
    bf16* WSf2   = (bf16*)p;  p += 256 * 128 * 2;
    bf16* WSconv = (bf16*)p;  p += 128 * 256 * 2;
    int* degd    = (int*)p;   p += (size_t)N_ * 4;
    int* degs    = (int*)p;   p += (size_t)N_ * 4;
    int* indptrd = (int*)p;   p += (size_t)(N_ + 1) * 4;
    int* indptrs = (int*)p;   p += (size_t)(N_ + 1) * 4;
    int* rankd   = (int*)p;   p += (size_t)E_ * 4;
    int* ranks   = (int*)p;   p += (size_t)E_ * 4;
    int* adjd    = (int*)p;   p += (size_t)E_ * 4;
    int* adjs    = (int*)p;   p += (size_t)E_ * 4;
    int* btotd   = (int*)p;   p += 256 * 4;
    int* btots   = (int*)p;   p += 256 * 4;
    float* invd  = (float*)p; p += (size_t)N_ * 4;
    float* invs  = (float*)p; p += (size_t)N_ * 4;
    float* cnt   = (float*)p; p += 8 * 4;
    float* gsum  = (float*)p; p += 2048 * 4;
    float* gmax  = (float*)p; p += 2048 * 4;
    int* flag    = (int*)p;   p += 64;
    size_t need = (size_t)(p - (char*)d_ws);

    if (ws_size < need) {
        diag_kernel<<<(out_size + 255) / 256, 256, 0, stream>>>((float*)d_out, (float)(ws_size >> 20), out_size);
        return;
    }

    bf16* Wencb = wb[0],  *bencb = wb[1];
    bf16* Wp1b  = wb[2],  *bp1b  = wb[3];
    bf16* Wp2b  = wb[4],  *bp2b  = wb[5];
    bf16* Wc1b  = wb[6],  *bc1b  = wb[7];
    bf16* Wc2b  = wb[8],  *bc2b  = wb[9];
    bf16* Wf1b  = wb[10], *bf1b  = wb[11];
    bf16* Wf2b  = wb[12], *bf2b  = wb[13];
    bf16* Wconvb = wb[14], *bconvb = wb[15];

    int gN = (N_ + 255) / 256;
    int gE4 = (E_ + 1023) / 1024;

    // ---- init + dtype probe + conversions ----
    init_kernel<<<(2 * N_ + 255) / 256, 256, 0, stream>>>(degd, cnt, gmax, flag, 2 * N_);
    probe_kernel<<<8, 256, 0, stream>>>((const unsigned int*)d_in[3], 2048, flag);
    convert_kernel<<<(in_sizes[0] + 255) / 256, 256, 0, stream>>>(d_in[0], T, in_sizes[0], flag);
    {
        ConvSegs cs;
        int blk = 0;
        for (int t = 0; t < 16; ++t) {
            cs.src[t] = d_in[3 + t];
            cs.dst[t] = wb[t];
            cs.n[t] = in_sizes[3 + t];
            cs.startBlock[t] = blk;
            blk += (in_sizes[3 + t] + 255) / 256;
        }
        cs.startBlock[16] = blk;
        convert_multi_kernel<<<blk, 256, 0, stream>>>(cs, flag);
    }
    {
        SwizSegs ts;
        const bf16* srcs[10] = {Wencb, Wp1b, Wp1b + 128 * 128, Wc1b, Wc1b + 128 * 128,
                                Wp2b, Wc2b, Wf1b, Wf2b, Wconvb};
        bf16* dsts[10] = {WSenc, WSpq_p, WSpq_p + 128 * 128, WSpq_c, WSpq_c + 128 * 128,
                          WS2p, WS2c, WSf1, WSf2, WSconv};
        int Ks[10]  = {256, 128, 128, 128, 128, 128, 128, 384, 256, 128};
        int NCs[10] = {128, 128, 128, 128, 128, 128, 128, 256, 128, 256};
        int blk = 0;
        for (int t = 0; t < 10; ++t) {
            ts.src[t] = srcs[t]; ts.dst[t] = dsts[t];
            ts.K[t] = Ks[t]; ts.NC[t] = NCs[t];
            ts.startBlock[t] = blk;
            blk += (Ks[t] * NCs[t] + 255) / 256;
        }
        ts.startBlock[10] = blk;
        swizzle_multi_kernel<<<blk, 256, 0, stream>>>(ts);
    }

    // ---- CSR build (rank trick, atomic-free scatter) ----
    degcnt_kernel<<<gE4, 256, 0, stream>>>(edges, E_, degd, degs, rankd, ranks);
    scan_block2_kernel<<<2 * gN, 256, 0, stream>>>(degd, degs, indptrd + 1, indptrs + 1,
                                                   btotd, btots, N_, gN);
    scan_total2_kernel<<<2, 256, 0, stream>>>(btotd, btots, gN);
    finalize_inv_kernel<<<3 * gN, 256, 0, stream>>>(indptrd, indptrs, btotd, btots,
                                                    degd, degs, invd, invs, N_, gN);
    scatter_kernel<<<gE4, 256, 0, stream>>>(edges, E_, indptrd, indptrs, rankd, ranks, adjd, adjs);
    cnt_kernel<<<gN, 256, 0, stream>>>(batch, N_, cnt);

    int gb = (N_ + 63) / 64;
    int ga = (N_ + 3) / 4;

    // ---- encoder: x = nodes(T) @ Wenc + benc ----
    gemm_mfma_kernel<256, 128, 1, false, false, false, false><<<gb, 256, 0, stream>>>(
        T, nullptr, nullptr, WSenc, bencb, nullptr, x, N_, nullptr, nullptr, nullptr);

    for (int it = 0; it < 2; ++it) {
        // parent: PQ = x@[Wp1_i;Wp1_j] -> T ; Sp = gather-relu-sum
        gemm_mfma_kernel<128, 256, 1, false, false, false, false><<<gb, 256, 0, stream>>>(
            x, nullptr, nullptr, WSpq_p, nullptr, nullptr, T, N_, nullptr, nullptr, nullptr);
        agg_kernel<<<ga, 256, 0, stream>>>(indptrd, adjd, T, bp1b, S, N_);
        // fused: Fi = Sp@WS2p*invd+bp2  ||  T = x@WSpq_c (child PQ)
        gemm_dual_kernel<<<2 * gb, 256, 0, stream>>>(S, WS2p, bp2b, invd, Fi,
                                                     x, WSpq_c, T, N_, gb);
        agg_kernel<<<ga, 256, 0, stream>>>(indptrs, adjs, T, bc1b, S, N_);
        gemm_mfma_kernel<128, 128, 1, false, false, true, false><<<gb, 256, 0, stream>>>(
            S, nullptr, nullptr, WS2c, bc2b, invs, S, N_, nullptr, nullptr, nullptr);
        // final MLP: H = relu([x,Fi,Fo]@Wf1+bf1) -> T ; x += T@Wf2+bf2
        gemm_mfma_kernel<384, 256, 3, true, false, false, false><<<gb, 256, 0, stream>>>(
            x, Fi, S, WSf1, bf1b, nullptr, T, N_, nullptr, nullptr, nullptr);
        gemm_mfma_kernel<256, 128, 1, false, true, false, false><<<gb, 256, 0, stream>>>(
            T, nullptr, nullptr, WSf2, bf2b, nullptr, x, N_, nullptr, nullptr, nullptr);
    }

    // conv with fused pool epilogue
    gemm_mfma_kernel<128, 256, 1, false, false, false, true><<<gb, 256, 0, stream>>>(
        x, nullptr, nullptr, WSconv, bconvb, nullptr, nullptr, N_, batch, gmax, gsum);
    out_kernel<<<16, 256, 0, stream>>>(gmax, gsum, cnt, flag, d_out);
}

// Round 10
// 722.427 us; speedup vs baseline: 3.9900x; 1.0064x over previous
//
#include <hip/hip_runtime.h>
#include <hip/hip_bf16.h>
#include <float.h>

typedef __hip_bfloat16 bf16;
typedef short short8 __attribute__((ext_vector_type(8)));   // 8 bf16 in 4 VGPRs
typedef short short4v __attribute__((ext_vector_type(4)));  // 4 bf16 in 2 VGPRs
typedef float f32x4 __attribute__((ext_vector_type(4)));

__device__ __forceinline__ float toF(bf16 v) { return __bfloat162float(v); }
__device__ __forceinline__ float s2f(short s) {
    return __uint_as_float(((unsigned int)(unsigned short)s) << 16);
}
__device__ __forceinline__ short f2s(float f) {
    bf16 h = __float2bfloat16(f);
    return *(short*)&h;
}

__global__ void diag_kernel(float* __restrict__ out, float v, int n) {
    int i = blockIdx.x * 256 + threadIdx.x;
    if (i < n) out[i] = v;
}

// Fused init: zero degd/degs (2N ints), zero cnt+gsum, gmax=-FLT_MAX, flag=1.
__global__ void init_kernel(int* __restrict__ deg2, float* __restrict__ cnt_gsum,
                            float* __restrict__ gmax, int* __restrict__ flag, int n2) {
    int i = blockIdx.x * 256 + threadIdx.x;
    if (i < n2) deg2[i] = 0;
    if (i < 8 + 2048) cnt_gsum[i] = 0.f;
    if (i < 2048) gmax[i] = -FLT_MAX;
    if (i == 0) *flag = 1;
}

// Dtype probe (f32 vs bf16 inputs). Ballot-elect: one atomic per wave max.
__global__ void probe_kernel(const unsigned int* __restrict__ w, int nwords,
                             int* __restrict__ flag) {
    int i = blockIdx.x * 256 + threadIdx.x;
    bool bad = false;
    if (i < nwords) {
        float v = __uint_as_float((w[i] & 0xFFFFu) << 16);
        bad = !(v > -1e3f && v < 1e3f);
    }
    if (__any(bad) && (threadIdx.x & 63) == 0) atomicAnd(flag, 0);
}

__global__ void convert_kernel(const void* __restrict__ src, bf16* __restrict__ dst,
                               int n, const int* __restrict__ flag) {
    int i = blockIdx.x * 256 + threadIdx.x;
    if (i < n) {
        if (*flag) dst[i] = ((const bf16*)src)[i];
        else       dst[i] = __float2bfloat16(((const float*)src)[i]);
    }
}

// ---- fused multi-tensor convert (16 weight tensors in one launch) ----
struct ConvSegs {
    const void* src[16];
    bf16* dst[16];
    int n[16];
    int startBlock[17];
};
__global__ void convert_multi_kernel(ConvSegs s, const int* __restrict__ flag) {
    int b = blockIdx.x;
    int seg = 0;
#pragma unroll
    for (int t = 1; t < 16; ++t) if (b >= s.startBlock[t]) seg = t;
    int i = (b - s.startBlock[seg]) * 256 + threadIdx.x;
    if (i < s.n[seg]) {
        if (*flag) s.dst[seg][i] = ((const bf16*)s.src[seg])[i];
        else       s.dst[seg][i] = __float2bfloat16(((const float*)s.src[seg])[i]);
    }
}

// ---- fused multi-swizzle: W [K,NC] row-major -> B-fragment order ----
// dst[((t*KF+kb)*64+ln)*8+j] = W[kb*32+(ln>>4)*8+j][t*16+(ln&15)]
struct SwizSegs {
    const bf16* src[10];
    bf16* dst[10];
    int K[10], NC[10];
    int startBlock[11];
};
__global__ void swizzle_multi_kernel(SwizSegs s) {
    int b = blockIdx.x;
    int seg = 0;
#pragma unroll
    for (int t = 1; t < 10; ++t) if (b >= s.startBlock[t]) seg = t;
    int i = (b - s.startBlock[seg]) * 256 + threadIdx.x;
    int K = s.K[seg], NC = s.NC[seg];
    if (i < K * NC) {
        int KF = K >> 5;
        int j = i & 7;
        int ln = (i >> 3) & 63;
        int q = i >> 9;
        int kb = q % KF;
        int t = q / KF;
        int k = kb * 32 + (ln >> 4) * 8 + j;
        int n = t * 16 + (ln & 15);
        s.dst[seg][i] = s.src[seg][k * NC + n];
    }
}

// Degrees + per-edge rank (rank = atomicAdd return). Ranks stored coalesced.
__global__ void degcnt_kernel(const int* __restrict__ edges, int E_,
                              int* __restrict__ degd, int* __restrict__ degs,
                              int* __restrict__ rankd, int* __restrict__ ranks) {
    int e0 = (blockIdx.x * 256 + threadIdx.x) * 4;
    if (e0 + 4 <= E_) {
        int4 s4 = *(const int4*)(edges + e0);
        int4 d4 = *(const int4*)(edges + E_ + e0);
        int4 rs, rd;
        rs.x = atomicAdd(&degs[s4.x], 1);
        rs.y = atomicAdd(&degs[s4.y], 1);
        rs.z = atomicAdd(&degs[s4.z], 1);
        rs.w = atomicAdd(&degs[s4.w], 1);
        rd.x = atomicAdd(&degd[d4.x], 1);
        rd.y = atomicAdd(&degd[d4.y], 1);
        rd.z = atomicAdd(&degd[d4.z], 1);
        rd.w = atomicAdd(&degd[d4.w], 1);
        *(int4*)(ranks + e0) = rs;
        *(int4*)(rankd + e0) = rd;
    } else {
        for (int e = e0; e < E_; ++e) {
            ranks[e] = atomicAdd(&degs[edges[e]], 1);
            rankd[e] = atomicAdd(&degd[edges[E_ + e]], 1);
        }
    }
}

// Fused scan of both degree arrays: blocks [0,gN) -> d, [gN,2gN) -> s.
__global__ void scan_block2_kernel(const int* __restrict__ degd, const int* __restrict__ degs,
                                   int* __restrict__ outd, int* __restrict__ outs,
                                   int* __restrict__ btotd, int* __restrict__ btots,
                                   int n, int gN) {
    __shared__ int s[256];
    int bb = blockIdx.x;
    const int* in = (bb < gN) ? degd : degs;
    int* out      = (bb < gN) ? outd : outs;
    int* btot     = (bb < gN) ? btotd : btots;
    int blk       = (bb < gN) ? bb : bb - gN;
    int t = threadIdx.x;
    int i = blk * 256 + t;
    s[t] = (i < n) ? in[i] : 0;
    __syncthreads();
    for (int off = 1; off < 256; off <<= 1) {
        int add = (t >= off) ? s[t - off] : 0;
        __syncthreads();
        s[t] += add;
        __syncthreads();
    }
    if (i < n) out[i] = s[t];
    if (t == 255) btot[blk] = s[255];
}

__global__ void scan_total2_kernel(int* __restrict__ btotd, int* __restrict__ btots, int G) {
    __shared__ int s[256];
    int* btot = (blockIdx.x == 0) ? btotd : btots;
    int t = threadIdx.x;
    s[t] = (t < G) ? btot[t] : 0;
    __syncthreads();
    for (int off = 1; off < 256; off <<= 1) {
        int add = (t >= off) ? s[t - off] : 0;
        __syncthreads();
        s[t] += add;
        __syncthreads();
    }
    if (t < G) btot[t] = s[t];
}

// blocks [0,2gN): finalize indptrs ; blocks [2gN,3gN): inv-degree compute.
__global__ void finalize_inv_kernel(int* __restrict__ indptrd, int* __restrict__ indptrs,
                                    const int* __restrict__ btotd, const int* __restrict__ btots,
                                    const int* __restrict__ degd, const int* __restrict__ degs,
                                    float* __restrict__ invd, float* __restrict__ invs,
                                    int n, int gN) {
    int bb = blockIdx.x;
    if (bb < 2 * gN) {
        int* indptr     = (bb < gN) ? indptrd : indptrs;
        const int* btot = (bb < gN) ? btotd : btots;
        int blk         = (bb < gN) ? bb : bb - gN;
        int i = blk * 256 + threadIdx.x;
        if (i < n) {
            int b = i >> 8;
            if (b > 0) indptr[i + 1] += btot[b - 1];
        }
        if (i == 0) indptr[0] = 0;
    } else {
        int i = (bb - 2 * gN) * 256 + threadIdx.x;
        if (i < n) {
            int dd = degd[i]; invd[i] = dd > 0 ? 1.0f / (float)dd : 0.0f;
            int ds = degs[i]; invs[i] = ds > 0 ? 1.0f / (float)ds : 0.0f;
        }
    }
}

// Atomic-free scatter: adj[indptr[node] + rank[e]] = other endpoint.
__global__ void scatter_kernel(const int* __restrict__ edges, int E_,
                               const int* __restrict__ indptrd, const int* __restrict__ indptrs,
                               const int* __restrict__ rankd, const int* __restrict__ ranks,
                               int* __restrict__ adjd, int* __restrict__ adjs) {
    int e0 = (blockIdx.x * 256 + threadIdx.x) * 4;
    if (e0 + 4 <= E_) {
        int4 s4 = *(const int4*)(edges + e0);
        int4 d4 = *(const int4*)(edges + E_ + e0);
        int4 rd = *(const int4*)(rankd + e0);
        int4 rs = *(const int4*)(ranks + e0);
        adjd[indptrd[d4.x] + rd.x] = s4.x;
        adjd[indptrd[d4.y] + rd.y] = s4.y;
        adjd[indptrd[d4.z] + rd.z] = s4.z;
        adjd[indptrd[d4.w] + rd.w] = s4.w;
        adjs[indptrs[s4.x] + rs.x] = d4.x;
        adjs[indptrs[s4.y] + rs.y] = d4.y;
        adjs[indptrs[s4.z] + rs.z] = d4.z;
        adjs[indptrs[s4.w] + rs.w] = d4.w;
    } else {
        for (int e = e0; e < E_; ++e) {
            int s_ = edges[e], d_ = edges[E_ + e];
            adjd[indptrd[d_] + rankd[e]] = s_;
            adjs[indptrs[s_] + ranks[e]] = d_;
        }
    }
}

__global__ void cnt_kernel(const int* __restrict__ batch, int n, float* __restrict__ cnt) {
    __shared__ float loc[8];
    int tid = threadIdx.x;
    if (tid < 8) loc[tid] = 0.f;
    __syncthreads();
    int i = blockIdx.x * 256 + tid;
    if (i < n) atomicAdd(&loc[batch[i]], 1.0f);
    __syncthreads();
    if (tid < 8 && loc[tid] > 0.f) atomicAdd(&cnt[tid], loc[tid]);
}

__device__ __forceinline__ void atomicMaxF(float* addr, float val) {
    unsigned int* ua = (unsigned int*)addr;
    unsigned int old = __float_as_uint(*addr);
    while (__uint_as_float(old) < val) {
        unsigned int assumed = old;
        old = atomicCAS(ua, assumed, __float_as_uint(val));
        if (old == assumed) break;
    }
}

// ---------------- MFMA GEMM core (LDS-staged, ILP-restructured) ----------------
template<int K, int NC> struct SB {
    static constexpr int APAD = K + 8;
    static constexpr int CPAD = NC + 8;
    static constexpr int AB = 64 * APAD * 2;
    static constexpr int CB = 64 * CPAD * 2;
    static constexpr int S = AB > CB ? AB : CB;
};

// C[M,NC] = act(A[M,K] @ W [+bias][*scale]) [+C res] | POOL | STORE=false: leave in sC.
// Compute loop: NC in 128-halves; kb-outer / tile-inner -> 8 INDEPENDENT MFMAs
// per kb (different acc), B-frags for kb+1 register-double-buffered (round-9
// counters: tile-outer serial-chain form was 4.5% MfmaUtil, latency-bound).
template<int K, int NC, int NSRC, bool RELU, bool RES, bool SCALE, bool POOL, bool STORE>
__device__ __forceinline__ void gemm_core(int bx,
    const bf16* A0, const bf16* A1, const bf16* A2,
    const bf16* WS, const bf16* bias, const float* scale, bf16* C, int M,
    const int* batch, float* gmax, float* gsum, char* smem) {
    constexpr int KF = K / 32;
    constexpr int NH = NC / 128;
    constexpr int APAD = SB<K, NC>::APAD;
    constexpr int CPAD = SB<K, NC>::CPAD;
    short* sA = (short*)smem;

    int tid = threadIdx.x;
    int m0blk = bx * 64;

    // phase 1: stage A tile (coalesced 16B)
    constexpr int C8 = K / 8;
    for (int idx = tid; idx < 64 * C8; idx += 256) {
        int r = idx / C8, c8 = idx % C8;
        int row = m0blk + r; row = row < M ? row : M - 1;
        const bf16* src;
        int off;
        if (NSRC == 1) { src = A0; off = c8 * 8; }
        else {
            int seg = c8 >> 4;
            src = seg == 0 ? A0 : (seg == 1 ? A1 : A2);
            off = (c8 & 15) * 8;
        }
        const size_t rs = (NSRC == 1) ? (size_t)K : (size_t)128;
        *(short8*)(sA + r * APAD + c8 * 8) = *(const short8*)((const short*)src + (size_t)row * rs + off);
    }
    __syncthreads();

    int wv = tid >> 6, ln = tid & 63;
    int quad = ln >> 4, ncol = ln & 15;
    int mw = wv * 16;

    short8 a[KF];
#pragma unroll
    for (int kb = 0; kb < KF; ++kb)
        a[kb] = *(const short8*)(sA + (mw + ncol) * APAD + kb * 32 + quad * 8);
    __syncthreads();                      // all a-reads done; sA reusable as sC

    float scl[4];
    if (SCALE) {
#pragma unroll
        for (int r = 0; r < 4; ++r) {
            int orow = m0blk + mw + quad * 4 + r;
            scl[r] = scale[orow < M ? orow : M - 1];
        }
    }

    short* sC = (short*)smem;
    const short8* wsp = (const short8*)WS;
#pragma unroll
    for (int h = 0; h < NH; ++h) {
        f32x4 acc[8];
#pragma unroll
        for (int t = 0; t < 8; ++t) acc[t] = (f32x4){0.f, 0.f, 0.f, 0.f};
        short8 bcur[8], bnxt[8];
#pragma unroll
        for (int t = 0; t < 8; ++t)
            bcur[t] = wsp[(size_t)((h * 8 + t) * KF) * 64 + ln];
#pragma unroll
        for (int kb = 0; kb < KF; ++kb) {
            if (kb + 1 < KF) {
#pragma unroll
                for (int t = 0; t < 8; ++t)
                    bnxt[t] = wsp[(size_t)((h * 8 + t) * KF + kb + 1) * 64 + ln];
            }
#pragma unroll
            for (int t = 0; t < 8; ++t)
                acc[t] = __builtin_amdgcn_mfma_f32_16x16x32_bf16(a[kb], bcur[t], acc[t], 0, 0, 0);
#pragma unroll
            for (int t = 0; t < 8; ++t) bcur[t] = bnxt[t];
        }
        // epilogue for this half into sC
#pragma unroll
        for (int t = 0; t < 8; ++t) {
            float bv = bias ? toF(bias[h * 128 + t * 16 + ncol]) : 0.f;
#pragma unroll
            for (int r = 0; r < 4; ++r) {
                float v = acc[t][r];
                if (SCALE) { v *= scl[r]; if (scl[r] > 0.f) v += bv; }
                else v += bv;
                if (RELU) v = fmaxf(v, 0.f);
                sC[(mw + quad * 4 + r) * CPAD + h * 128 + t * 16 + ncol] = f2s(v);
            }
        }
    }
    __syncthreads();
    if (!STORE && !POOL) return;          // result left in sC (CPAD layout)

    if (POOL) {
        // pool phase: segment max/sum over sorted batch, sourced from LDS.
        int* bs = (int*)(smem + SB<K, NC>::S);
        if (tid < 64) {
            int row = m0blk + tid;
            bs[tid] = (row < M) ? batch[row] : -1;
        }
        __syncthreads();
        int cur_b = -1;
        float mx = -FLT_MAX, sm = 0.f;
        for (int r = 0; r < 64; ++r) {
            int b = bs[r];
            if (b < 0) break;
            float v = s2f(sC[r * CPAD + tid]);
            if (b != cur_b) {
                if (cur_b >= 0) {
                    atomicMaxF(&gmax[cur_b * 256 + tid], mx);
                    atomicAdd(&gsum[cur_b * 256 + tid], sm);
                }
                cur_b = b; mx = v; sm = v;
            } else {
                mx = fmaxf(mx, v);
                sm += v;
            }
        }
        if (cur_b >= 0) {
            atomicMaxF(&gmax[cur_b * 256 + tid], mx);
            atomicAdd(&gsum[cur_b * 256 + tid], sm);
        }
    } else {
        // store phase: coalesced (+ residual)
        constexpr int OC8 = NC / 8;
        for (int idx = tid; idx < 64 * OC8; idx += 256) {
            int r = idx / OC8, c8 = idx % OC8;
            int row = m0blk + r;
            if (row < M) {
                short8 v = *(short8*)(sC + r * CPAD + c8 * 8);
                size_t o = (size_t)row * NC + c8 * 8;
                if (RES) {
                    short8 old = *(const short8*)((const short*)C + o);
#pragma unroll
                    for (int j = 0; j < 8; ++j) v[j] = f2s(s2f(v[j]) + s2f(old[j]));
                }
                *(short8*)((short*)C + o) = v;
            }
        }
    }
}

template<int K, int NC, int NSRC, bool RELU, bool RES, bool SCALE, bool POOL>
__global__ void gemm_mfma_kernel(const bf16* A0, const bf16* A1, const bf16* A2,
                                 const bf16* WS, const bf16* bias,
                                 const float* scale, bf16* C, int M,
                                 const int* batch, float* gmax, float* gsum) {
    __shared__ __align__(16) char smem[SB<K, NC>::S + (POOL ? 256 : 0)];
    gemm_core<K, NC, NSRC, RELU, RES, SCALE, POOL, true>(
        blockIdx.x, A0, A1, A2, WS, bias, scale, C, M, batch, gmax, gsum, smem);
}

// Fused: blocks [0,split) = parent S-gemm (Fi = Sp@WS2*inv + b2);
//        blocks [split,..) = child PQ-gemm (T = x@WSpq). Independent.
__global__ void gemm_dual_kernel(const bf16* Sp, const bf16* WS2, const bf16* b2,
                                 const float* inv, bf16* Fi,
                                 const bf16* x, const bf16* WSpq, bf16* T,
                                 int M, int split) {
    __shared__ __align__(16) char smem[SB<128, 256>::S];
    if (blockIdx.x < split)
        gemm_core<128, 128, 1, false, false, true, false, true>(
            blockIdx.x, Sp, nullptr, nullptr, WS2, b2, inv, Fi, M, nullptr, nullptr, nullptr, smem);
    else
        gemm_core<128, 256, 1, false, false, false, false, true>(
            blockIdx.x - split, x, nullptr, nullptr, WSpq, nullptr, nullptr, T, M, nullptr, nullptr, nullptr, smem);
}

// Fused final MLP: H = relu([x,Fi,Fo]@Wf1+bf1) stays in LDS; x += H@Wf2+bf2.
// Kills the T round-trip (51 MB) + one dispatch per iteration.
__global__ void fused_mlp_kernel(const bf16* x, const bf16* Fi, const bf16* Fo,
                                 const bf16* WSf1, const bf16* bf1_,
                                 const bf16* WSf2, const bf16* bf2_,
                                 bf16* xio, int M) {
    __shared__ __align__(16) char smem[SB<384, 256>::S];
    // f1 -> H in sC (CPAD=264), no store
    gemm_core<384, 256, 3, true, false, false, false, false>(
        blockIdx.x, x, Fi, Fo, WSf1, bf1_, nullptr, nullptr, M,
        nullptr, nullptr, nullptr, smem);

    constexpr int HPAD = 264;    // SB<384,256>::CPAD
    constexpr int CPAD2 = 136;
    short* sH = (short*)smem;
    int tid = threadIdx.x;
    int wv = tid >> 6, ln = tid & 63;
    int quad = ln >> 4, ncol = ln & 15;
    int mw = wv * 16;
    int m0blk = blockIdx.x * 64;

    // f2 A-frags from H (own rows)
    short8 a2[8];
#pragma unroll
    for (int kb = 0; kb < 8; ++kb)
        a2[kb] = *(const short8*)(sH + (mw + ncol) * HPAD + kb * 32 + quad * 8);
    __syncthreads();              // all H reads done before C2 overwrite

    f32x4 acc[8];
#pragma unroll
    for (int t = 0; t < 8; ++t) acc[t] = (f32x4){0.f, 0.f, 0.f, 0.f};
    const short8* wsp = (const short8*)WSf2;   // K=256 -> KF=8
    short8 bcur[8], bnxt[8];
#pragma unroll
    for (int t = 0; t < 8; ++t) bcur[t] = wsp[(size_t)(t * 8) * 64 + ln];
#pragma unroll
    for (int kb = 0; kb < 8; ++kb) {
        if (kb + 1 < 8) {
#pragma unroll
            for (int t = 0; t < 8; ++t)
                bnxt[t] = wsp[(size_t)(t * 8 + kb + 1) * 64 + ln];
        }
#pragma unroll
        for (int t = 0; t < 8; ++t)
            acc[t] = __builtin_amdgcn_mfma_f32_16x16x32_bf16(a2[kb], bcur[t], acc[t], 0, 0, 0);
#pragma unroll
        for (int t = 0; t < 8; ++t) bcur[t] = bnxt[t];
    }
    short* sC2 = (short*)smem;
#pragma unroll
    for (int t = 0; t < 8; ++t) {
        float bv = toF(bf2_[t * 16 + ncol]);
#pragma unroll
        for (int r = 0; r < 4; ++r)
            sC2[(mw + quad * 4 + r) * CPAD2 + t * 16 + ncol] = f2s(acc[t][r] + bv);
    }
    __syncthreads();
    // store with residual x += ...
    for (int idx = tid; idx < 64 * 16; idx += 256) {
        int r = idx >> 4, c8 = idx & 15;
        int row = m0blk + r;
        if (row < M) {
            short8 v = *(short8*)(sC2 + r * CPAD2 + c8 * 8);
            size_t o = (size_t)row * 128 + c8 * 8;
            short8 old = *(const short8*)((const short*)xio + o);
#pragma unroll
            for (int j = 0; j < 8; ++j) v[j] = f2s(s2f(v[j]) + s2f(old[j]));
            *(short8*)((short*)xio + o) = v;
        }
    }
}

// S[i,:] = sum_{j in adj[i]} relu(P[i,:] + Q[j,:] + b1)
// PQ [M,256]: cols 0-127 = P, 128-255 = Q. 4 nodes/block, 1 wave/node.
// Half-waves take alternating neighbors, x8 unroll -> 16 gathers in flight/wave.
__global__ void agg_kernel(const int* __restrict__ indptr, const int* __restrict__ adj,
                           const bf16* __restrict__ PQ, const bf16* __restrict__ b1,
                           bf16* __restrict__ S, int M) {
    int tid = threadIdx.x;
    int wv = tid >> 6, ln = tid & 63;
    int node = blockIdx.x * 4 + wv;
    if (node >= M) return;
    int c4 = ln & 31, half = ln >> 5;
    float p[4];
    {
        short4v pv = *(const short4v*)((const short*)PQ + (size_t)node * 256 + 4 * c4);
        short4v bv = *(const short4v*)((const short*)b1 + 4 * c4);
#pragma unroll
        for (int r = 0; r < 4; ++r) p[r] = s2f(pv[r]) + s2f(bv[r]);
    }
    float a[4] = {0.f, 0.f, 0.f, 0.f};
    int beg = indptr[node], end = indptr[node + 1];
    const short* Qb = (const short*)PQ + 128 + 4 * c4;
    int k = beg + half;
    for (; k + 14 < end; k += 16) {
        int j0 = adj[k],      j1 = adj[k + 2],  j2 = adj[k + 4],  j3 = adj[k + 6];
        int j4 = adj[k + 8],  j5 = adj[k + 10], j6 = adj[k + 12], j7 = adj[k + 14];
        short4v q0 = *(const short4v*)(Qb + (size_t)j0 * 256);
        short4v q1 = *(const short4v*)(Qb + (size_t)j1 * 256);
        short4v q2 = *(const short4v*)(Qb + (size_t)j2 * 256);
        short4v q3 = *(const short4v*)(Qb + (size_t)j3 * 256);
        short4v q4 = *(const short4v*)(Qb + (size_t)j4 * 256);
        short4v q5 = *(const short4v*)(Qb + (size_t)j5 * 256);
        short4v q6 = *(const short4v*)(Qb + (size_t)j6 * 256);
        short4v q7 = *(const short4v*)(Qb + (size_t)j7 * 256);
#pragma unroll
        for (int r = 0; r < 4; ++r)
            a[r] += fmaxf(p[r] + s2f(q0[r]), 0.f) + fmaxf(p[r] + s2f(q1[r]), 0.f)
                  + fmaxf(p[r] + s2f(q2[r]), 0.f) + fmaxf(p[r] + s2f(q3[r]), 0.f)
                  + fmaxf(p[r] + s2f(q4[r]), 0.f) + fmaxf(p[r] + s2f(q5[r]), 0.f)
                  + fmaxf(p[r] + s2f(q6[r]), 0.f) + fmaxf(p[r] + s2f(q7[r]), 0.f);
    }
    for (; k + 6 < end; k += 8) {
        int j0 = adj[k], j1 = adj[k + 2], j2 = adj[k + 4], j3 = adj[k + 6];
        short4v q0 = *(const short4v*)(Qb + (size_t)j0 * 256);
        short4v q1 = *(const short4v*)(Qb + (size_t)j1 * 256);
        short4v q2 = *(const short4v*)(Qb + (size_t)j2 * 256);
        short4v q3 = *(const short4v*)(Qb + (size_t)j3 * 256);
#pragma unroll
        for (int r = 0; r < 4; ++r)
            a[r] += fmaxf(p[r] + s2f(q0[r]), 0.f) + fmaxf(p[r] + s2f(q1[r]), 0.f)
                  + fmaxf(p[r] + s2f(q2[r]), 0.f) + fmaxf(p[r] + s2f(q3[r]), 0.f);
    }
    for (; k < end; k += 2) {
        int j = adj[k];
        short4v q = *(const short4v*)(Qb + (size_t)j * 256);
#pragma unroll
        for (int r = 0; r < 4; ++r) a[r] += fmaxf(p[r] + s2f(q[r]), 0.f);
    }
#pragma unroll
    for (int r = 0; r < 4; ++r) a[r] += __shfl_xor(a[r], 32);
    if (half == 0) {
        short4v o;
#pragma unroll
        for (int r = 0; r < 4; ++r) o[r] = f2s(a[r]);
        *(short4v*)((short*)S + (size_t)node * 128 + 4 * c4) = o;
    }
}

__global__ void out_kernel(const float* __restrict__ gmax, const float* __restrict__ gsum,
                           const float* __restrict__ cnt, const int* __restrict__ flag,
                           void* __restrict__ out) {
    int i = blockIdx.x * 256 + threadIdx.x;
    if (i < 8 * 512) {
        int b = i >> 9, c = i & 511;
        float v = (c < 256) ? gmax[b * 256 + c] : gsum[b * 256 + (c - 256)] / cnt[b];
        int f = *flag;
        if (!(v == v)) v = 1000.f + 100.f * (float)f;
        if (f) ((bf16*)out)[i] = __float2bfloat16(v);
        else   ((float*)out)[i] = v;
    }
}

extern "C" void kernel_launch(void* const* d_in, const int* in_sizes, int n_in,
                              void* d_out, int out_size, void* d_ws, size_t ws_size,
                              hipStream_t stream) {
    const int* edges = (const int*)d_in[1];
    const int* batch = (const int*)d_in[2];

    const int N_ = in_sizes[2];
    const int E_ = in_sizes[1] / 2;
    const size_t ND = (size_t)N_ * 128;
    auto pad8 = [](int n) { return (size_t)((n + 7) & ~7); };

    // ---- workspace carve (~79 MB for N=50000, E=800000; proven fits) ----
    char* p = (char*)d_ws;
    bf16* x  = (bf16*)p;      p += ND * 2;
    bf16* T  = (bf16*)p;      p += (size_t)N_ * 256 * 2;  // nodesb / PQ
    bf16* S  = (bf16*)p;      p += ND * 2;                // agg sum / Fo in-place
    bf16* Fi = (bf16*)p;      p += ND * 2;
    bf16* wb[16];
    for (int t = 0; t < 16; ++t) { wb[t] = (bf16*)p; p += pad8(in_sizes[3 + t]) * 2; }
    bf16* WSenc  = (bf16*)p;  p += 256 * 128 * 2;
    bf16* WSpq_p = (bf16*)p;  p += 256 * 128 * 2;
    bf16* WSpq_c = (bf16*)p;  p += 256 * 128 * 2;
    bf16* WS2p   = (bf16*)p;  p += 128 * 128 * 2;
    bf16* WS2c   = (bf16*)p;  p += 128 * 128 * 2;
    bf16* WSf1   = (bf16*)p;  p += 384 * 256 * 2;
    bf16* WSf2   = (bf16*)p;  p += 256 * 128 * 2;
    bf16* WSconv = (bf16*)p;  p += 128 * 256 * 2;
    int* degd    = (int*)p;   p += (size_t)N_ * 4;
    int* degs    = (int*)p;   p += (size_t)N_ * 4;
    int* indptrd = (int*)p;   p += (size_t)(N_ + 1) * 4;
    int* indptrs = (int*)p;   p += (size_t)(N_ + 1) * 4;
    int* rankd   = (int*)p;   p += (size_t)E_ * 4;
    int* ranks   = (int*)p;   p += (size_t)E_ * 4;
    int* adjd    = (int*)p;   p += (size_t)E_ * 4;
    int* adjs    = (int*)p;   p += (size_t)E_ * 4;
    int* btotd   = (int*)p;   p += 256 * 4;
    int* btots   = (int*)p;   p += 256 * 4;
    float* invd  = (float*)p; p += (size_t)N_ * 4;
    float* invs  = (float*)p; p += (size_t)N_ * 4;
    float* cnt   = (float*)p; p += 8 * 4;
    float* gsum  = (float*)p; p += 2048 * 4;
    float* gmax  = (float*)p; p += 2048 * 4;
    int* flag    = (int*)p;   p += 64;
    size_t need = (size_t)(p - (char*)d_ws);

    if (ws_size < need) {
        diag_kernel<<<(out_size + 255) / 256, 256, 0, stream>>>((float*)d_out, (float)(ws_size >> 20), out_size);
        return;
    }

    bf16* Wencb = wb[0],  *bencb = wb[1];
    bf16* Wp1b  = wb[2],  *bp1b  = wb[3];
    bf16* Wp2b  = wb[4],  *bp2b  = wb[5];
    bf16* Wc1b  = wb[6],  *bc1b  = wb[7];
    bf16* Wc2b  = wb[8],  *bc2b  = wb[9];
    bf16* Wf1b  = wb[10], *bf1b  = wb[11];
    bf16* Wf2b  = wb[12], *bf2b  = wb[13];
    bf16* Wconvb = wb[14], *bconvb = wb[15];

    int gN = (N_ + 255) / 256;
    int gE4 = (E_ + 1023) / 1024;

    // ---- init + dtype probe + conversions ----
    init_kernel<<<(2 * N_ + 255) / 256, 256, 0, stream>>>(degd, cnt, gmax, flag, 2 * N_);
    probe_kernel<<<8, 256, 0, stream>>>((const unsigned int*)d_in[3], 2048, flag);
    convert_kernel<<<(in_sizes[0] + 255) / 256, 256, 0, stream>>>(d_in[0], T, in_sizes[0], flag);
    {
        ConvSegs cs;
        int blk = 0;
        for (int t = 0; t < 16; ++t) {
            cs.src[t] = d_in[3 + t];
            cs.dst[t] = wb[t];
            cs.n[t] = in_sizes[3 + t];
            cs.startBlock[t] = blk;
            blk += (in_sizes[3 + t] + 255) / 256;
        }
        cs.startBlock[16] = blk;
        convert_multi_kernel<<<blk, 256, 0, stream>>>(cs, flag);
    }
    {
        SwizSegs ts;
        const bf16* srcs[10] = {Wencb, Wp1b, Wp1b + 128 * 128, Wc1b, Wc1b + 128 * 128,
                                Wp2b, Wc2b, Wf1b, Wf2b, Wconvb};
        bf16* dsts[10] = {WSenc, WSpq_p, WSpq_p + 128 * 128, WSpq_c, WSpq_c + 128 * 128,
                          WS2p, WS2c, WSf1, WSf2, WSconv};
        int Ks[10]  = {256, 128, 128, 128, 128, 128, 128, 384, 256, 128};
        int NCs[10] = {128, 128, 128, 128, 128, 128, 128, 256, 128, 256};
        int blk = 0;
        for (int t = 0; t < 10; ++t) {
            ts.src[t] = srcs[t]; ts.dst[t] = dsts[t];
            ts.K[t] = Ks[t]; ts.NC[t] = NCs[t];
            ts.startBlock[t] = blk;
            blk += (Ks[t] * NCs[t] + 255) / 256;
        }
        ts.startBlock[10] = blk;
        swizzle_multi_kernel<<<blk, 256, 0, stream>>>(ts);
    }

    // ---- CSR build (rank trick, atomic-free scatter) ----
    degcnt_kernel<<<gE4, 256, 0, stream>>>(edges, E_, degd, degs, rankd, ranks);
    scan_block2_kernel<<<2 * gN, 256, 0, stream>>>(degd, degs, indptrd + 1, indptrs + 1,
                                                   btotd, btots, N_, gN);
    scan_total2_kernel<<<2, 256, 0, stream>>>(btotd, btots, gN);
    finalize_inv_kernel<<<3 * gN, 256, 0, stream>>>(indptrd, indptrs, btotd, btots,
                                                    degd, degs, invd, invs, N_, gN);
    scatter_kernel<<<gE4, 256, 0, stream>>>(edges, E_, indptrd, indptrs, rankd, ranks, adjd, adjs);
    cnt_kernel<<<gN, 256, 0, stream>>>(batch, N_, cnt);

    int gb = (N_ + 63) / 64;
    int ga = (N_ + 3) / 4;

    // ---- encoder: x = nodes(T) @ Wenc + benc ----
    gemm_mfma_kernel<256, 128, 1, false, false, false, false><<<gb, 256, 0, stream>>>(
        T, nullptr, nullptr, WSenc, bencb, nullptr, x, N_, nullptr, nullptr, nullptr);

    for (int it = 0; it < 2; ++it) {
        // parent: PQ = x@[Wp1_i;Wp1_j] -> T ; Sp = gather-relu-sum
        gemm_mfma_kernel<128, 256, 1, false, false, false, false><<<gb, 256, 0, stream>>>(
            x, nullptr, nullptr, WSpq_p, nullptr, nullptr, T, N_, nullptr, nullptr, nullptr);
        agg_kernel<<<ga, 256, 0, stream>>>(indptrd, adjd, T, bp1b, S, N_);
        // fused: Fi = Sp@WS2p*invd+bp2  ||  T = x@WSpq_c (child PQ)
        gemm_dual_kernel<<<2 * gb, 256, 0, stream>>>(S, WS2p, bp2b, invd, Fi,
                                                     x, WSpq_c, T, N_, gb);
        agg_kernel<<<ga, 256, 0, stream>>>(indptrs, adjs, T, bc1b, S, N_);
        gemm_mfma_kernel<128, 128, 1, false, false, true, false><<<gb, 256, 0, stream>>>(
            S, nullptr, nullptr, WS2c, bc2b, invs, S, N_, nullptr, nullptr, nullptr);
        // fused final MLP: x += relu([x,Fi,Fo]@Wf1+bf1)@Wf2+bf2
        fused_mlp_kernel<<<gb, 256, 0, stream>>>(x, Fi, S, WSf1, bf1b, WSf2, bf2b, x, N_);
    }

    // conv with fused pool epilogue
    gemm_mfma_kernel<128, 256, 1, false, false, false, true><<<gb, 256, 0, stream>>>(
        x, nullptr, nullptr, WSconv, bconvb, nullptr, nullptr, N_, batch, gmax, gsum);
    out_kernel<<<16, 256, 0, stream>>>(gmax, gsum, cnt, flag, d_out);
}

// Round 11
// 647.520 us; speedup vs baseline: 4.4516x; 1.1157x over previous
//
#include <hip/hip_runtime.h>
#include <hip/hip_bf16.h>
#include <float.h>

typedef __hip_bfloat16 bf16;
typedef short short8 __attribute__((ext_vector_type(8)));   // 8 bf16 in 4 VGPRs
typedef short short4v __attribute__((ext_vector_type(4)));  // 4 bf16 in 2 VGPRs
typedef float f32x4 __attribute__((ext_vector_type(4)));

__device__ __forceinline__ float toF(bf16 v) { return __bfloat162float(v); }
__device__ __forceinline__ float s2f(short s) {
    return __uint_as_float(((unsigned int)(unsigned short)s) << 16);
}
__device__ __forceinline__ short f2s(float f) {
    bf16 h = __float2bfloat16(f);
    return *(short*)&h;
}

__global__ void diag_kernel(float* __restrict__ out, float v, int n) {
    int i = blockIdx.x * 256 + threadIdx.x;
    if (i < n) out[i] = v;
}

// Fused init: zero degd/degs (2N ints), zero cnt+gsum, gmax=-FLT_MAX, flag=1.
__global__ void init_kernel(int* __restrict__ deg2, float* __restrict__ cnt_gsum,
                            float* __restrict__ gmax, int* __restrict__ flag, int n2) {
    int i = blockIdx.x * 256 + threadIdx.x;
    if (i < n2) deg2[i] = 0;
    if (i < 8 + 2048) cnt_gsum[i] = 0.f;
    if (i < 2048) gmax[i] = -FLT_MAX;
    if (i == 0) *flag = 1;
}

// Dtype probe (f32 vs bf16 inputs). Ballot-elect: one atomic per wave max.
__global__ void probe_kernel(const unsigned int* __restrict__ w, int nwords,
                             int* __restrict__ flag) {
    int i = blockIdx.x * 256 + threadIdx.x;
    bool bad = false;
    if (i < nwords) {
        float v = __uint_as_float((w[i] & 0xFFFFu) << 16);
        bad = !(v > -1e3f && v < 1e3f);
    }
    if (__any(bad) && (threadIdx.x & 63) == 0) atomicAnd(flag, 0);
}

__global__ void convert_kernel(const void* __restrict__ src, bf16* __restrict__ dst,
                               int n, const int* __restrict__ flag) {
    int i = blockIdx.x * 256 + threadIdx.x;
    if (i < n) {
        if (*flag) dst[i] = ((const bf16*)src)[i];
        else       dst[i] = __float2bfloat16(((const float*)src)[i]);
    }
}

// ---- fused multi-tensor convert (16 weight tensors in one launch) ----
struct ConvSegs {
    const void* src[16];
    bf16* dst[16];
    int n[16];
    int startBlock[17];
};
__global__ void convert_multi_kernel(ConvSegs s, const int* __restrict__ flag) {
    int b = blockIdx.x;
    int seg = 0;
#pragma unroll
    for (int t = 1; t < 16; ++t) if (b >= s.startBlock[t]) seg = t;
    int i = (b - s.startBlock[seg]) * 256 + threadIdx.x;
    if (i < s.n[seg]) {
        if (*flag) s.dst[seg][i] = ((const bf16*)s.src[seg])[i];
        else       s.dst[seg][i] = __float2bfloat16(((const float*)s.src[seg])[i]);
    }
}

// ---- fused multi-swizzle: W [K,NC] row-major -> B-fragment order ----
// dst[((t*KF+kb)*64+ln)*8+j] = W[kb*32+(ln>>4)*8+j][t*16+(ln&15)]
struct SwizSegs {
    const bf16* src[10];
    bf16* dst[10];
    int K[10], NC[10];
    int startBlock[11];
};
__global__ void swizzle_multi_kernel(SwizSegs s) {
    int b = blockIdx.x;
    int seg = 0;
#pragma unroll
    for (int t = 1; t < 10; ++t) if (b >= s.startBlock[t]) seg = t;
    int i = (b - s.startBlock[seg]) * 256 + threadIdx.x;
    int K = s.K[seg], NC = s.NC[seg];
    if (i < K * NC) {
        int KF = K >> 5;
        int j = i & 7;
        int ln = (i >> 3) & 63;
        int q = i >> 9;
        int kb = q % KF;
        int t = q / KF;
        int k = kb * 32 + (ln >> 4) * 8 + j;
        int n = t * 16 + (ln & 15);
        s.dst[seg][i] = s.src[seg][k * NC + n];
    }
}

// Degrees + per-edge rank (rank = atomicAdd return). Ranks stored coalesced.
__global__ void degcnt_kernel(const int* __restrict__ edges, int E_,
                              int* __restrict__ degd, int* __restrict__ degs,
                              int* __restrict__ rankd, int* __restrict__ ranks) {
    int e0 = (blockIdx.x * 256 + threadIdx.x) * 4;
    if (e0 + 4 <= E_) {
        int4 s4 = *(const int4*)(edges + e0);
        int4 d4 = *(const int4*)(edges + E_ + e0);
        int4 rs, rd;
        rs.x = atomicAdd(&degs[s4.x], 1);
        rs.y = atomicAdd(&degs[s4.y], 1);
        rs.z = atomicAdd(&degs[s4.z], 1);
        rs.w = atomicAdd(&degs[s4.w], 1);
        rd.x = atomicAdd(&degd[d4.x], 1);
        rd.y = atomicAdd(&degd[d4.y], 1);
        rd.z = atomicAdd(&degd[d4.z], 1);
        rd.w = atomicAdd(&degd[d4.w], 1);
        *(int4*)(ranks + e0) = rs;
        *(int4*)(rankd + e0) = rd;
    } else {
        for (int e = e0; e < E_; ++e) {
            ranks[e] = atomicAdd(&degs[edges[e]], 1);
            rankd[e] = atomicAdd(&degd[edges[E_ + e]], 1);
        }
    }
}

// Fused scan of both degree arrays: blocks [0,gN) -> d, [gN,2gN) -> s.
__global__ void scan_block2_kernel(const int* __restrict__ degd, const int* __restrict__ degs,
                                   int* __restrict__ outd, int* __restrict__ outs,
                                   int* __restrict__ btotd, int* __restrict__ btots,
                                   int n, int gN) {
    __shared__ int s[256];
    int bb = blockIdx.x;
    const int* in = (bb < gN) ? degd : degs;
    int* out      = (bb < gN) ? outd : outs;
    int* btot     = (bb < gN) ? btotd : btots;
    int blk       = (bb < gN) ? bb : bb - gN;
    int t = threadIdx.x;
    int i = blk * 256 + t;
    s[t] = (i < n) ? in[i] : 0;
    __syncthreads();
    for (int off = 1; off < 256; off <<= 1) {
        int add = (t >= off) ? s[t - off] : 0;
        __syncthreads();
        s[t] += add;
        __syncthreads();
    }
    if (i < n) out[i] = s[t];
    if (t == 255) btot[blk] = s[255];
}

__global__ void scan_total2_kernel(int* __restrict__ btotd, int* __restrict__ btots, int G) {
    __shared__ int s[256];
    int* btot = (blockIdx.x == 0) ? btotd : btots;
    int t = threadIdx.x;
    s[t] = (t < G) ? btot[t] : 0;
    __syncthreads();
    for (int off = 1; off < 256; off <<= 1) {
        int add = (t >= off) ? s[t - off] : 0;
        __syncthreads();
        s[t] += add;
        __syncthreads();
    }
    if (t < G) btot[t] = s[t];
}

// blocks [0,2gN): finalize indptrs ; blocks [2gN,3gN): inv-degree compute.
__global__ void finalize_inv_kernel(int* __restrict__ indptrd, int* __restrict__ indptrs,
                                    const int* __restrict__ btotd, const int* __restrict__ btots,
                                    const int* __restrict__ degd, const int* __restrict__ degs,
                                    float* __restrict__ invd, float* __restrict__ invs,
                                    int n, int gN) {
    int bb = blockIdx.x;
    if (bb < 2 * gN) {
        int* indptr     = (bb < gN) ? indptrd : indptrs;
        const int* btot = (bb < gN) ? btotd : btots;
        int blk         = (bb < gN) ? bb : bb - gN;
        int i = blk * 256 + threadIdx.x;
        if (i < n) {
            int b = i >> 8;
            if (b > 0) indptr[i + 1] += btot[b - 1];
        }
        if (i == 0) indptr[0] = 0;
    } else {
        int i = (bb - 2 * gN) * 256 + threadIdx.x;
        if (i < n) {
            int dd = degd[i]; invd[i] = dd > 0 ? 1.0f / (float)dd : 0.0f;
            int ds = degs[i]; invs[i] = ds > 0 ? 1.0f / (float)ds : 0.0f;
        }
    }
}

// Atomic-free scatter: adj[indptr[node] + rank[e]] = other endpoint.
__global__ void scatter_kernel(const int* __restrict__ edges, int E_,
                               const int* __restrict__ indptrd, const int* __restrict__ indptrs,
                               const int* __restrict__ rankd, const int* __restrict__ ranks,
                               int* __restrict__ adjd, int* __restrict__ adjs) {
    int e0 = (blockIdx.x * 256 + threadIdx.x) * 4;
    if (e0 + 4 <= E_) {
        int4 s4 = *(const int4*)(edges + e0);
        int4 d4 = *(const int4*)(edges + E_ + e0);
        int4 rd = *(const int4*)(rankd + e0);
        int4 rs = *(const int4*)(ranks + e0);
        adjd[indptrd[d4.x] + rd.x] = s4.x;
        adjd[indptrd[d4.y] + rd.y] = s4.y;
        adjd[indptrd[d4.z] + rd.z] = s4.z;
        adjd[indptrd[d4.w] + rd.w] = s4.w;
        adjs[indptrs[s4.x] + rs.x] = d4.x;
        adjs[indptrs[s4.y] + rs.y] = d4.y;
        adjs[indptrs[s4.z] + rs.z] = d4.z;
        adjs[indptrs[s4.w] + rs.w] = d4.w;
    } else {
        for (int e = e0; e < E_; ++e) {
            int s_ = edges[e], d_ = edges[E_ + e];
            adjd[indptrd[d_] + rankd[e]] = s_;
            adjs[indptrs[s_] + ranks[e]] = d_;
        }
    }
}

__global__ void cnt_kernel(const int* __restrict__ batch, int n, float* __restrict__ cnt) {
    __shared__ float loc[8];
    int tid = threadIdx.x;
    if (tid < 8) loc[tid] = 0.f;
    __syncthreads();
    int i = blockIdx.x * 256 + tid;
    if (i < n) atomicAdd(&loc[batch[i]], 1.0f);
    __syncthreads();
    if (tid < 8 && loc[tid] > 0.f) atomicAdd(&cnt[tid], loc[tid]);
}

__device__ __forceinline__ void atomicMaxF(float* addr, float val) {
    unsigned int* ua = (unsigned int*)addr;
    unsigned int old = __float_as_uint(*addr);
    while (__uint_as_float(old) < val) {
        unsigned int assumed = old;
        old = atomicCAS(ua, assumed, __float_as_uint(val));
        if (old == assumed) break;
    }
}

// ---------------- MFMA GEMM core (LDS-staged, ILP-restructured) ----------------
template<int K, int NC> struct SB {
    static constexpr int APAD = K + 8;
    static constexpr int CPAD = NC + 8;
    static constexpr int AB = 64 * APAD * 2;
    static constexpr int CB = 64 * CPAD * 2;
    static constexpr int S = AB > CB ? AB : CB;
};

// C[M,NC] = act(A[M,K] @ W [+bias][*scale]) [+C res] | POOL | STORE=false: leave in sC.
// kb-outer / tile-inner: 8 independent MFMAs per kb, B-frags double-buffered.
// NOTE round-10: without __launch_bounds__ the compiler capped VGPRs at 64 and
// spilled ~100 regs to scratch (WRITE_SIZE 41MB vs 13MB expected) — the GEMM
// kernels carry __launch_bounds__(256,2) to allow the ~160-reg working set.
template<int K, int NC, int NSRC, bool RELU, bool RES, bool SCALE, bool POOL, bool STORE>
__device__ __forceinline__ void gemm_core(int bx,
    const bf16* A0, const bf16* A1, const bf16* A2,
    const bf16* WS, const bf16* bias, const float* scale, bf16* C, int M,
    const int* batch, float* gmax, float* gsum, char* smem) {
    constexpr int KF = K / 32;
    constexpr int NH = NC / 128;
    constexpr int APAD = SB<K, NC>::APAD;
    constexpr int CPAD = SB<K, NC>::CPAD;
    short* sA = (short*)smem;

    int tid = threadIdx.x;
    int m0blk = bx * 64;

    // phase 1: stage A tile (coalesced 16B)
    constexpr int C8 = K / 8;
    for (int idx = tid; idx < 64 * C8; idx += 256) {
        int r = idx / C8, c8 = idx % C8;
        int row = m0blk + r; row = row < M ? row : M - 1;
        const bf16* src;
        int off;
        if (NSRC == 1) { src = A0; off = c8 * 8; }
        else {
            int seg = c8 >> 4;
            src = seg == 0 ? A0 : (seg == 1 ? A1 : A2);
            off = (c8 & 15) * 8;
        }
        const size_t rs = (NSRC == 1) ? (size_t)K : (size_t)128;
        *(short8*)(sA + r * APAD + c8 * 8) = *(const short8*)((const short*)src + (size_t)row * rs + off);
    }
    __syncthreads();

    int wv = tid >> 6, ln = tid & 63;
    int quad = ln >> 4, ncol = ln & 15;
    int mw = wv * 16;

    short8 a[KF];
#pragma unroll
    for (int kb = 0; kb < KF; ++kb)
        a[kb] = *(const short8*)(sA + (mw + ncol) * APAD + kb * 32 + quad * 8);
    __syncthreads();                      // all a-reads done; sA reusable as sC

    float scl[4];
    if (SCALE) {
#pragma unroll
        for (int r = 0; r < 4; ++r) {
            int orow = m0blk + mw + quad * 4 + r;
            scl[r] = scale[orow < M ? orow : M - 1];
        }
    }

    short* sC = (short*)smem;
    const short8* wsp = (const short8*)WS;
#pragma unroll
    for (int h = 0; h < NH; ++h) {
        f32x4 acc[8];
#pragma unroll
        for (int t = 0; t < 8; ++t) acc[t] = (f32x4){0.f, 0.f, 0.f, 0.f};
        short8 bcur[8], bnxt[8];
#pragma unroll
        for (int t = 0; t < 8; ++t)
            bcur[t] = wsp[(size_t)((h * 8 + t) * KF) * 64 + ln];
#pragma unroll
        for (int kb = 0; kb < KF; ++kb) {
            if (kb + 1 < KF) {
#pragma unroll
                for (int t = 0; t < 8; ++t)
                    bnxt[t] = wsp[(size_t)((h * 8 + t) * KF + kb + 1) * 64 + ln];
            }
#pragma unroll
            for (int t = 0; t < 8; ++t)
                acc[t] = __builtin_amdgcn_mfma_f32_16x16x32_bf16(a[kb], bcur[t], acc[t], 0, 0, 0);
#pragma unroll
            for (int t = 0; t < 8; ++t) bcur[t] = bnxt[t];
        }
        // epilogue for this half into sC
#pragma unroll
        for (int t = 0; t < 8; ++t) {
            float bv = bias ? toF(bias[h * 128 + t * 16 + ncol]) : 0.f;
#pragma unroll
            for (int r = 0; r < 4; ++r) {
                float v = acc[t][r];
                if (SCALE) { v *= scl[r]; if (scl[r] > 0.f) v += bv; }
                else v += bv;
                if (RELU) v = fmaxf(v, 0.f);
                sC[(mw + quad * 4 + r) * CPAD + h * 128 + t * 16 + ncol] = f2s(v);
            }
        }
    }
    __syncthreads();
    if (!STORE && !POOL) return;          // result left in sC (CPAD layout)

    if (POOL) {
        // pool phase: segment max/sum over sorted batch, sourced from LDS.
        int* bs = (int*)(smem + SB<K, NC>::S);
        if (tid < 64) {
            int row = m0blk + tid;
            bs[tid] = (row < M) ? batch[row] : -1;
        }
        __syncthreads();
        int cur_b = -1;
        float mx = -FLT_MAX, sm = 0.f;
        for (int r = 0; r < 64; ++r) {
            int b = bs[r];
            if (b < 0) break;
            float v = s2f(sC[r * CPAD + tid]);
            if (b != cur_b) {
                if (cur_b >= 0) {
                    atomicMaxF(&gmax[cur_b * 256 + tid], mx);
                    atomicAdd(&gsum[cur_b * 256 + tid], sm);
                }
                cur_b = b; mx = v; sm = v;
            } else {
                mx = fmaxf(mx, v);
                sm += v;
            }
        }
        if (cur_b >= 0) {
            atomicMaxF(&gmax[cur_b * 256 + tid], mx);
            atomicAdd(&gsum[cur_b * 256 + tid], sm);
        }
    } else {
        // store phase: coalesced (+ residual)
        constexpr int OC8 = NC / 8;
        for (int idx = tid; idx < 64 * OC8; idx += 256) {
            int r = idx / OC8, c8 = idx % OC8;
            int row = m0blk + r;
            if (row < M) {
                short8 v = *(short8*)(sC + r * CPAD + c8 * 8);
                size_t o = (size_t)row * NC + c8 * 8;
                if (RES) {
                    short8 old = *(const short8*)((const short*)C + o);
#pragma unroll
                    for (int j = 0; j < 8; ++j) v[j] = f2s(s2f(v[j]) + s2f(old[j]));
                }
                *(short8*)((short*)C + o) = v;
            }
        }
    }
}

template<int K, int NC, int NSRC, bool RELU, bool RES, bool SCALE, bool POOL>
__global__ __launch_bounds__(256, 2)
void gemm_mfma_kernel(const bf16* A0, const bf16* A1, const bf16* A2,
                      const bf16* WS, const bf16* bias,
                      const float* scale, bf16* C, int M,
                      const int* batch, float* gmax, float* gsum) {
    __shared__ __align__(16) char smem[SB<K, NC>::S + (POOL ? 256 : 0)];
    gemm_core<K, NC, NSRC, RELU, RES, SCALE, POOL, true>(
        blockIdx.x, A0, A1, A2, WS, bias, scale, C, M, batch, gmax, gsum, smem);
}

// Fused: blocks [0,split) = parent S-gemm (Fi = Sp@WS2*inv + b2);
//        blocks [split,..) = child PQ-gemm (T = x@WSpq). Independent.
__global__ __launch_bounds__(256, 2)
void gemm_dual_kernel(const bf16* Sp, const bf16* WS2, const bf16* b2,
                      const float* inv, bf16* Fi,
                      const bf16* x, const bf16* WSpq, bf16* T,
                      int M, int split) {
    __shared__ __align__(16) char smem[SB<128, 256>::S];
    if (blockIdx.x < split)
        gemm_core<128, 128, 1, false, false, true, false, true>(
            blockIdx.x, Sp, nullptr, nullptr, WS2, b2, inv, Fi, M, nullptr, nullptr, nullptr, smem);
    else
        gemm_core<128, 256, 1, false, false, false, false, true>(
            blockIdx.x - split, x, nullptr, nullptr, WSpq, nullptr, nullptr, T, M, nullptr, nullptr, nullptr, smem);
}

// Fused final MLP: H = relu([x,Fi,Fo]@Wf1+bf1) stays in LDS; x += H@Wf2+bf2.
__global__ __launch_bounds__(256, 2)
void fused_mlp_kernel(const bf16* x, const bf16* Fi, const bf16* Fo,
                      const bf16* WSf1, const bf16* bf1_,
                      const bf16* WSf2, const bf16* bf2_,
                      bf16* xio, int M) {
    __shared__ __align__(16) char smem[SB<384, 256>::S];
    // f1 -> H in sC (CPAD=264), no store
    gemm_core<384, 256, 3, true, false, false, false, false>(
        blockIdx.x, x, Fi, Fo, WSf1, bf1_, nullptr, nullptr, M,
        nullptr, nullptr, nullptr, smem);

    constexpr int HPAD = 264;    // SB<384,256>::CPAD
    constexpr int CPAD2 = 136;
    short* sH = (short*)smem;
    int tid = threadIdx.x;
    int wv = tid >> 6, ln = tid & 63;
    int quad = ln >> 4, ncol = ln & 15;
    int mw = wv * 16;
    int m0blk = blockIdx.x * 64;

    // f2 A-frags from H (own rows)
    short8 a2[8];
#pragma unroll
    for (int kb = 0; kb < 8; ++kb)
        a2[kb] = *(const short8*)(sH + (mw + ncol) * HPAD + kb * 32 + quad * 8);
    __syncthreads();              // all H reads done before C2 overwrite

    f32x4 acc[8];
#pragma unroll
    for (int t = 0; t < 8; ++t) acc[t] = (f32x4){0.f, 0.f, 0.f, 0.f};
    const short8* wsp = (const short8*)WSf2;   // K=256 -> KF=8
    short8 bcur[8], bnxt[8];
#pragma unroll
    for (int t = 0; t < 8; ++t) bcur[t] = wsp[(size_t)(t * 8) * 64 + ln];
#pragma unroll
    for (int kb = 0; kb < 8; ++kb) {
        if (kb + 1 < 8) {
#pragma unroll
            for (int t = 0; t < 8; ++t)
                bnxt[t] = wsp[(size_t)(t * 8 + kb + 1) * 64 + ln];
        }
#pragma unroll
        for (int t = 0; t < 8; ++t)
            acc[t] = __builtin_amdgcn_mfma_f32_16x16x32_bf16(a2[kb], bcur[t], acc[t], 0, 0, 0);
#pragma unroll
        for (int t = 0; t < 8; ++t) bcur[t] = bnxt[t];
    }
    short* sC2 = (short*)smem;
#pragma unroll
    for (int t = 0; t < 8; ++t) {
        float bv = toF(bf2_[t * 16 + ncol]);
#pragma unroll
        for (int r = 0; r < 4; ++r)
            sC2[(mw + quad * 4 + r) * CPAD2 + t * 16 + ncol] = f2s(acc[t][r] + bv);
    }
    __syncthreads();
    // store with residual x += ...
    for (int idx = tid; idx < 64 * 16; idx += 256) {
        int r = idx >> 4, c8 = idx & 15;
        int row = m0blk + r;
        if (row < M) {
            short8 v = *(short8*)(sC2 + r * CPAD2 + c8 * 8);
            size_t o = (size_t)row * 128 + c8 * 8;
            short8 old = *(const short8*)((const short*)xio + o);
#pragma unroll
            for (int j = 0; j < 8; ++j) v[j] = f2s(s2f(v[j]) + s2f(old[j]));
            *(short8*)((short*)xio + o) = v;
        }
    }
}

// S[i,:] = sum_{j in adj[i]} relu(P[i,:] + Q[j,:] + b1)
// PQ [M,256]: cols 0-127 = P, 128-255 = Q. 4 nodes/block, 1 wave/node.
// Half-waves take alternating neighbors, x8 unroll -> 16 gathers in flight/wave.
__global__ void agg_kernel(const int* __restrict__ indptr, const int* __restrict__ adj,
                           const bf16* __restrict__ PQ, const bf16* __restrict__ b1,
                           bf16* __restrict__ S, int M) {
    int tid = threadIdx.x;
    int wv = tid >> 6, ln = tid & 63;
    int node = blockIdx.x * 4 + wv;
    if (node >= M) return;
    int c4 = ln & 31, half = ln >> 5;
    float p[4];
    {
        short4v pv = *(const short4v*)((const short*)PQ + (size_t)node * 256 + 4 * c4);
        short4v bv = *(const short4v*)((const short*)b1 + 4 * c4);
#pragma unroll
        for (int r = 0; r < 4; ++r) p[r] = s2f(pv[r]) + s2f(bv[r]);
    }
    float a[4] = {0.f, 0.f, 0.f, 0.f};
    int beg = indptr[node], end = indptr[node + 1];
    const short* Qb = (const short*)PQ + 128 + 4 * c4;
    int k = beg + half;
    for (; k + 14 < end; k += 16) {
        int j0 = adj[k],      j1 = adj[k + 2],  j2 = adj[k + 4],  j3 = adj[k + 6];
        int j4 = adj[k + 8],  j5 = adj[k + 10], j6 = adj[k + 12], j7 = adj[k + 14];
        short4v q0 = *(const short4v*)(Qb + (size_t)j0 * 256);
        short4v q1 = *(const short4v*)(Qb + (size_t)j1 * 256);
        short4v q2 = *(const short4v*)(Qb + (size_t)j2 * 256);
        short4v q3 = *(const short4v*)(Qb + (size_t)j3 * 256);
        short4v q4 = *(const short4v*)(Qb + (size_t)j4 * 256);
        short4v q5 = *(const short4v*)(Qb + (size_t)j5 * 256);
        short4v q6 = *(const short4v*)(Qb + (size_t)j6 * 256);
        short4v q7 = *(const short4v*)(Qb + (size_t)j7 * 256);
#pragma unroll
        for (int r = 0; r < 4; ++r)
            a[r] += fmaxf(p[r] + s2f(q0[r]), 0.f) + fmaxf(p[r] + s2f(q1[r]), 0.f)
                  + fmaxf(p[r] + s2f(q2[r]), 0.f) + fmaxf(p[r] + s2f(q3[r]), 0.f)
                  + fmaxf(p[r] + s2f(q4[r]), 0.f) + fmaxf(p[r] + s2f(q5[r]), 0.f)
                  + fmaxf(p[r] + s2f(q6[r]), 0.f) + fmaxf(p[r] + s2f(q7[r]), 0.f);
    }
    for (; k + 6 < end; k += 8) {
        int j0 = adj[k], j1 = adj[k + 2], j2 = adj[k + 4], j3 = adj[k + 6];
        short4v q0 = *(const short4v*)(Qb + (size_t)j0 * 256);
        short4v q1 = *(const short4v*)(Qb + (size_t)j1 * 256);
        short4v q2 = *(const short4v*)(Qb + (size_t)j2 * 256);
        short4v q3 = *(const short4v*)(Qb + (size_t)j3 * 256);
#pragma unroll
        for (int r = 0; r < 4; ++r)
            a[r] += fmaxf(p[r] + s2f(q0[r]), 0.f) + fmaxf(p[r] + s2f(q1[r]), 0.f)
                  + fmaxf(p[r] + s2f(q2[r]), 0.f) + fmaxf(p[r] + s2f(q3[r]), 0.f);
    }
    for (; k < end; k += 2) {
        int j = adj[k];
        short4v q = *(const short4v*)(Qb + (size_t)j * 256);
#pragma unroll
        for (int r = 0; r < 4; ++r) a[r] += fmaxf(p[r] + s2f(q[r]), 0.f);
    }
#pragma unroll
    for (int r = 0; r < 4; ++r) a[r] += __shfl_xor(a[r], 32);
    if (half == 0) {
        short4v o;
#pragma unroll
        for (int r = 0; r < 4; ++r) o[r] = f2s(a[r]);
        *(short4v*)((short*)S + (size_t)node * 128 + 4 * c4) = o;
    }
}

__global__ void out_kernel(const float* __restrict__ gmax, const float* __restrict__ gsum,
                           const float* __restrict__ cnt, const int* __restrict__ flag,
                           void* __restrict__ out) {
    int i = blockIdx.x * 256 + threadIdx.x;
    if (i < 8 * 512) {
        int b = i >> 9, c = i & 511;
        float v = (c < 256) ? gmax[b * 256 + c] : gsum[b * 256 + (c - 256)] / cnt[b];
        int f = *flag;
        if (!(v == v)) v = 1000.f + 100.f * (float)f;
        if (f) ((bf16*)out)[i] = __float2bfloat16(v);
        else   ((float*)out)[i] = v;
    }
}

extern "C" void kernel_launch(void* const* d_in, const int* in_sizes, int n_in,
                              void* d_out, int out_size, void* d_ws, size_t ws_size,
                              hipStream_t stream) {
    const int* edges = (const int*)d_in[1];
    const int* batch = (const int*)d_in[2];

    const int N_ = in_sizes[2];
    const int E_ = in_sizes[1] / 2;
    const size_t ND = (size_t)N_ * 128;
    auto pad8 = [](int n) { return (size_t)((n + 7) & ~7); };

    // ---- workspace carve (~79 MB for N=50000, E=800000; proven fits) ----
    char* p = (char*)d_ws;
    bf16* x  = (bf16*)p;      p += ND * 2;
    bf16* T  = (bf16*)p;      p += (size_t)N_ * 256 * 2;  // nodesb / PQ
    bf16* S  = (bf16*)p;      p += ND * 2;                // agg sum / Fo in-place
    bf16* Fi = (bf16*)p;      p += ND * 2;
    bf16* wb[16];
    for (int t = 0; t < 16; ++t) { wb[t] = (bf16*)p; p += pad8(in_sizes[3 + t]) * 2; }
    bf16* WSenc  = (bf16*)p;  p += 256 * 128 * 2;
    bf16* WSpq_p = (bf16*)p;  p += 256 * 128 * 2;
    bf16* WSpq_c = (bf16*)p;  p += 256 * 128 * 2;
    bf16* WS2p   = (bf16*)p;  p += 128 * 128 * 2;
    bf16* WS2c   = (bf16*)p;  p += 128 * 128 * 2;
    bf16* WSf1   = (bf16*)p;  p += 384 * 256 * 2;
    bf16* WSf2   = (bf16*)p;  p += 256 * 128 * 2;
    bf16* WSconv = (bf16*)p;  p += 128 * 256 * 2;
    int* degd    = (int*)p;   p += (size_t)N_ * 4;
    int* degs    = (int*)p;   p += (size_t)N_ * 4;
    int* indptrd = (int*)p;   p += (size_t)(N_ + 1) * 4;
    int* indptrs = (int*)p;   p += (size_t)(N_ + 1) * 4;
    int* rankd   = (int*)p;   p += (size_t)E_ * 4;
    int* ranks   = (int*)p;   p += (size_t)E_ * 4;
    int* adjd    = (int*)p;   p += (size_t)E_ * 4;
    int* adjs    = (int*)p;   p += (size_t)E_ * 4;
    int* btotd   = (int*)p;   p += 256 * 4;
    int* btots   = (int*)p;   p += 256 * 4;
    float* invd  = (float*)p; p += (size_t)N_ * 4;
    float* invs  = (float*)p; p += (size_t)N_ * 4;
    float* cnt   = (float*)p; p += 8 * 4;
    float* gsum  = (float*)p; p += 2048 * 4;
    float* gmax  = (float*)p; p += 2048 * 4;
    int* flag    = (int*)p;   p += 64;
    size_t need = (size_t)(p - (char*)d_ws);

    if (ws_size < need) {
        diag_kernel<<<(out_size + 255) / 256, 256, 0, stream>>>((float*)d_out, (float)(ws_size >> 20), out_size);
        return;
    }

    bf16* Wencb = wb[0],  *bencb = wb[1];
    bf16* Wp1b  = wb[2],  *bp1b  = wb[3];
    bf16* Wp2b  = wb[4],  *bp2b  = wb[5];
    bf16* Wc1b  = wb[6],  *bc1b  = wb[7];
    bf16* Wc2b  = wb[8],  *bc2b  = wb[9];
    bf16* Wf1b  = wb[10], *bf1b  = wb[11];
    bf16* Wf2b  = wb[12], *bf2b  = wb[13];
    bf16* Wconvb = wb[14], *bconvb = wb[15];

    int gN = (N_ + 255) / 256;
    int gE4 = (E_ + 1023) / 1024;

    // ---- init + dtype probe + conversions ----
    init_kernel<<<(2 * N_ + 255) / 256, 256, 0, stream>>>(degd, cnt, gmax, flag, 2 * N_);
    probe_kernel<<<8, 256, 0, stream>>>((const unsigned int*)d_in[3], 2048, flag);
    convert_kernel<<<(in_sizes[0] + 255) / 256, 256, 0, stream>>>(d_in[0], T, in_sizes[0], flag);
    {
        ConvSegs cs;
        int blk = 0;
        for (int t = 0; t < 16; ++t) {
            cs.src[t] = d_in[3 + t];
            cs.dst[t] = wb[t];
            cs.n[t] = in_sizes[3 + t];
            cs.startBlock[t] = blk;
            blk += (in_sizes[3 + t] + 255) / 256;
        }
        cs.startBlock[16] = blk;
        convert_multi_kernel<<<blk, 256, 0, stream>>>(cs, flag);
    }
    {
        SwizSegs ts;
        const bf16* srcs[10] = {Wencb, Wp1b, Wp1b + 128 * 128, Wc1b, Wc1b + 128 * 128,
                                Wp2b, Wc2b, Wf1b, Wf2b, Wconvb};
        bf16* dsts[10] = {WSenc, WSpq_p, WSpq_p + 128 * 128, WSpq_c, WSpq_c + 128 * 128,
                          WS2p, WS2c, WSf1, WSf2, WSconv};
        int Ks[10]  = {256, 128, 128, 128, 128, 128, 128, 384, 256, 128};
        int NCs[10] = {128, 128, 128, 128, 128, 128, 128, 256, 128, 256};
        int blk = 0;
        for (int t = 0; t < 10; ++t) {
            ts.src[t] = srcs[t]; ts.dst[t] = dsts[t];
            ts.K[t] = Ks[t]; ts.NC[t] = NCs[t];
            ts.startBlock[t] = blk;
            blk += (Ks[t] * NCs[t] + 255) / 256;
        }
        ts.startBlock[10] = blk;
        swizzle_multi_kernel<<<blk, 256, 0, stream>>>(ts);
    }

    // ---- CSR build (rank trick, atomic-free scatter) ----
    degcnt_kernel<<<gE4, 256, 0, stream>>>(edges, E_, degd, degs, rankd, ranks);
    scan_block2_kernel<<<2 * gN, 256, 0, stream>>>(degd, degs, indptrd + 1, indptrs + 1,
                                                   btotd, btots, N_, gN);
    scan_total2_kernel<<<2, 256, 0, stream>>>(btotd, btots, gN);
    finalize_inv_kernel<<<3 * gN, 256, 0, stream>>>(indptrd, indptrs, btotd, btots,
                                                    degd, degs, invd, invs, N_, gN);
    scatter_kernel<<<gE4, 256, 0, stream>>>(edges, E_, indptrd, indptrs, rankd, ranks, adjd, adjs);
    cnt_kernel<<<gN, 256, 0, stream>>>(batch, N_, cnt);

    int gb = (N_ + 63) / 64;
    int ga = (N_ + 3) / 4;

    // ---- encoder: x = nodes(T) @ Wenc + benc ----
    gemm_mfma_kernel<256, 128, 1, false, false, false, false><<<gb, 256, 0, stream>>>(
        T, nullptr, nullptr, WSenc, bencb, nullptr, x, N_, nullptr, nullptr, nullptr);

    for (int it = 0; it < 2; ++it) {
        // parent: PQ = x@[Wp1_i;Wp1_j] -> T ; Sp = gather-relu-sum
        gemm_mfma_kernel<128, 256, 1, false, false, false, false><<<gb, 256, 0, stream>>>(
            x, nullptr, nullptr, WSpq_p, nullptr, nullptr, T, N_, nullptr, nullptr, nullptr);
        agg_kernel<<<ga, 256, 0, stream>>>(indptrd, adjd, T, bp1b, S, N_);
        // fused: Fi = Sp@WS2p*invd+bp2  ||  T = x@WSpq_c (child PQ)
        gemm_dual_kernel<<<2 * gb, 256, 0, stream>>>(S, WS2p, bp2b, invd, Fi,
                                                     x, WSpq_c, T, N_, gb);
        agg_kernel<<<ga, 256, 0, stream>>>(indptrs, adjs, T, bc1b, S, N_);
        gemm_mfma_kernel<128, 128, 1, false, false, true, false><<<gb, 256, 0, stream>>>(
            S, nullptr, nullptr, WS2c, bc2b, invs, S, N_, nullptr, nullptr, nullptr);
        // fused final MLP: x += relu([x,Fi,Fo]@Wf1+bf1)@Wf2+bf2
        fused_mlp_kernel<<<gb, 256, 0, stream>>>(x, Fi, S, WSf1, bf1b, WSf2, bf2b, x, N_);
    }

    // conv with fused pool epilogue
    gemm_mfma_kernel<128, 256, 1, false, false, false, true><<<gb, 256, 0, stream>>>(
        x, nullptr, nullptr, WSconv, bconvb, nullptr, nullptr, N_, batch, gmax, gsum);
    out_kernel<<<16, 256, 0, stream>>>(gmax, gsum, cnt, flag, d_out);
}